// Round 10
// baseline (861.855 us; speedup 1.0000x reference)
//
#include <hip/hip_runtime.h>
#include <stdint.h>

// RWKV6 block: B=1, T=2048, C=2048, H=32, HS=64, FFN=7168, NS=4
// Workspace: 6*16M (f32) + 4*8M (bA) + 6*8M (bO) + 32M (WT) + 4M aux = 212 MiB.

#define TT 2048
#define CC 2048
#define NH 32
#define HSZ 64
#define FFND 7168
#define CHUNK 32
#define NCHUNK 64

typedef __attribute__((ext_vector_type(8))) short short8;
typedef __attribute__((ext_vector_type(4))) float f32x4;

__device__ __forceinline__ float bf2f(short s){
  return __uint_as_float(((uint32_t)(uint16_t)s) << 16);
}
__device__ __forceinline__ short f2bf(float f){
  uint32_t u = __float_as_uint(f);
  u = u + 0x7fffu + ((u >> 16) & 1u);
  return (short)(u >> 16);
}

// ---------------- LayerNorm (row over C) ----------------
__global__ __launch_bounds__(256) void ln_kernel(
    const float* __restrict__ xin, const float* __restrict__ gam,
    const float* __restrict__ bet, float* __restrict__ out, float eps)
{
  int t = blockIdx.x, tid = threadIdx.x;
  const float* row = xin + (size_t)t*CC;
  float4 v0 = *(const float4*)(row + tid*8);
  float4 v1 = *(const float4*)(row + tid*8 + 4);
  float s  = v0.x+v0.y+v0.z+v0.w + v1.x+v1.y+v1.z+v1.w;
  float ss = v0.x*v0.x+v0.y*v0.y+v0.z*v0.z+v0.w*v0.w
           + v1.x*v1.x+v1.y*v1.y+v1.z*v1.z+v1.w*v1.w;
  #pragma unroll
  for(int off=1; off<64; off<<=1){ s += __shfl_xor(s,off); ss += __shfl_xor(ss,off); }
  __shared__ float sm[8];
  int w = tid>>6;
  if((tid&63)==0){ sm[w]=s; sm[4+w]=ss; }
  __syncthreads();
  s = sm[0]+sm[1]+sm[2]+sm[3]; ss = sm[4]+sm[5]+sm[6]+sm[7];
  float mean = s * (1.f/CC);
  float var  = ss * (1.f/CC) - mean*mean;
  float rstd = rsqrtf(var + eps);
  float* orow = out + (size_t)t*CC;
  int c = tid*8;
  float vv[8] = {v0.x,v0.y,v0.z,v0.w,v1.x,v1.y,v1.z,v1.w};
  #pragma unroll
  for(int j=0;j<8;j++) orow[c+j] = (vv[j]-mean)*rstd*gam[c+j] + bet[c+j];
}

// ---------------- fused: xmid = p0+p1+x ; zw = LN(xmid) ----------------
__global__ __launch_bounds__(256) void ln2_fused_kernel(
    const float* __restrict__ p0, const float* __restrict__ p1,
    const float* __restrict__ xres, const float* __restrict__ gam,
    const float* __restrict__ bet, float* __restrict__ xsum,
    float* __restrict__ lnout, float eps)
{
  int t = blockIdx.x, tid = threadIdx.x;
  size_t base = (size_t)t*CC + tid*8;
  float vv[8];
  float s = 0.f, ss = 0.f;
  #pragma unroll
  for(int j=0;j<8;j++){
    float v = p0[base+j] + p1[base+j] + xres[base+j];
    vv[j] = v; s += v; ss += v*v;
    xsum[base+j] = v;
  }
  #pragma unroll
  for(int off=1; off<64; off<<=1){ s += __shfl_xor(s,off); ss += __shfl_xor(ss,off); }
  __shared__ float sm[8];
  int w = tid>>6;
  if((tid&63)==0){ sm[w]=s; sm[4+w]=ss; }
  __syncthreads();
  s = sm[0]+sm[1]+sm[2]+sm[3]; ss = sm[4]+sm[5]+sm[6]+sm[7];
  float mean = s * (1.f/CC);
  float var  = ss * (1.f/CC) - mean*mean;
  float rstd = rsqrtf(var + eps);
  int c = tid*8;
  #pragma unroll
  for(int j=0;j<8;j++) lnout[base+j] = (vv[j]-mean)*rstd*gam[c+j] + bet[c+j];
}

// ---------------- token shift (attention): xx = sh - xa (f32 out) ----------------
__global__ __launch_bounds__(256) void shift1_kernel(
    const float* __restrict__ xa, const float* __restrict__ st,
    const int* __restrict__ sp, float* __restrict__ xxb)
{
  int t = blockIdx.x, tid = threadIdx.x;
  int sp0=sp[0], sp1=sp[1], sp2=sp[2], sp3=sp[3];
  bool is_start = (sp0==t)|(sp1==t)|(sp2==t)|(sp3==t);
  int sid = (sp0<=t)+(sp1<=t)+(sp2<=t)+(sp3<=t) - 1;
  sid = sid<0?0:(sid>3?3:sid);
  int c = tid*8;
  const float* src = is_start ? (st + (size_t)sid*CC + c)
                   : (t>0 ? xa + (size_t)(t-1)*CC + c : nullptr);
  const float* cur = xa + (size_t)t*CC + c;
  float* o = xxb + (size_t)t*CC + c;
  #pragma unroll
  for(int jj=0;jj<8;jj++){
    float sh = src ? src[jj] : 0.f;
    o[jj] = sh - cur[jj];
  }
}

// ---------------- token shift (ffn): xk2/xr2 fused, bf16 out ----------------
__global__ __launch_bounds__(256) void shift2_kernel(
    const float* __restrict__ xf, const float* __restrict__ st,
    const int* __restrict__ sp, const float* __restrict__ cmk,
    const float* __restrict__ cmr, short* __restrict__ xk2, short* __restrict__ xr2)
{
  int t = blockIdx.x, tid = threadIdx.x;
  int sp0=sp[0], sp1=sp[1], sp2=sp[2], sp3=sp[3];
  bool is_start = (sp0==t)|(sp1==t)|(sp2==t)|(sp3==t);
  int sid = (sp0<=t)+(sp1<=t)+(sp2<=t)+(sp3<=t) - 1;
  sid = sid<0?0:(sid>3?3:sid);
  int c = tid*8;
  const float* src = is_start ? (st + (size_t)sid*CC + c)
                   : (t>0 ? xf + (size_t)(t-1)*CC + c : nullptr);
  const float* cur = xf + (size_t)t*CC + c;
  size_t ix = (size_t)t*CC + c;
  #pragma unroll
  for(int jj=0;jj<8;jj++){
    float xfv = cur[jj];
    float sh = src ? src[jj] : 0.f;
    float d = sh - xfv;
    xk2[ix+jj] = f2bf(xfv + d*cmk[c+jj]);
    xr2[ix+jj] = f2bf(xfv + d*cmr[c+jj]);
  }
}

// ---------------- z = xa + xx*maa_x -> bf16 ----------------
__global__ __launch_bounds__(256) void zprep_kernel(const float* __restrict__ xa,
   const float* __restrict__ xx, const float* __restrict__ maa, short* __restrict__ z)
{
  size_t i = ((size_t)blockIdx.x*256 + threadIdx.x)*8;
  int c = (int)(i & (CC-1));
  #pragma unroll
  for(int j=0;j<8;j++) z[i+j] = f2bf(xa[i+j] + xx[i+j]*maa[c+j]);
}

// ---------------- fused 5-way maa mix -> bf16 outputs ----------------
// t0/c derived from blockIdx only => xxxb index is wave-uniform => SMEM loads.
__global__ __launch_bounds__(256) void mix5_kernel(
    const float* __restrict__ xxxb, const float* __restrict__ w2,
    const float* __restrict__ xa, const float* __restrict__ xxv,
    const float* __restrict__ mw, const float* __restrict__ mk,
    const float* __restrict__ mv, const float* __restrict__ mr,
    const float* __restrict__ mg,
    short* __restrict__ ow, short* __restrict__ ok, short* __restrict__ ov,
    short* __restrict__ orr, short* __restrict__ og)
{
  int t0 = (blockIdx.x >> 3) * 8;                  // uniform (no tid)
  int c  = ((blockIdx.x & 7) << 8) + threadIdx.x;  // 0..2047
  float acc[5][8];
  #pragma unroll
  for(int s=0;s<5;s++)
    #pragma unroll
    for(int tt=0;tt<8;tt++) acc[s][tt]=0.f;
  #pragma unroll
  for(int s=0;s<5;s++){
    for(int e=0;e<32;e++){
      float wv = w2[(size_t)(s*32+e)*CC + c];
      #pragma unroll
      for(int tt=0;tt<8;tt++)
        acc[s][tt] += xxxb[(size_t)(t0+tt)*160 + s*32 + e] * wv;
    }
  }
  float vmw=mw[c], vmk=mk[c], vmv=mv[c], vmr=mr[c], vmg=mg[c];
  #pragma unroll
  for(int tt=0;tt<8;tt++){
    size_t ix = (size_t)(t0+tt)*CC + c;
    float av = xa[ix], xv = xxv[ix];
    ow[ix]  = f2bf(av + xv*(vmw + acc[0][tt]));
    ok[ix]  = f2bf(av + xv*(vmk + acc[1][tt]));
    ov[ix]  = f2bf(av + xv*(vmv + acc[2][tt]));
    orr[ix] = f2bf(av + xv*(vmr + acc[3][tt]));
    og[ix]  = f2bf(av + xv*(vmg + acc[4][tt]));
  }
}

// ---------------- dec = exp(-exp(td + h1 @ td_w2)) (f32) ----------------
__global__ __launch_bounds__(256) void dec_kernel(
    const float* __restrict__ h1b, const float* __restrict__ tw2,
    const float* __restrict__ td, float* __restrict__ out)
{
  int t0 = (blockIdx.x >> 3) * 8;
  int c  = ((blockIdx.x & 7) << 8) + threadIdx.x;
  float acc[8] = {0,0,0,0,0,0,0,0};
  for(int e=0;e<64;e++){
    float wv = tw2[(size_t)e*CC + c];
    #pragma unroll
    for(int tt=0;tt<8;tt++) acc[tt] += h1b[(size_t)(t0+tt)*64 + e]*wv;
  }
  float tdc = td[c];
  #pragma unroll
  for(int tt=0;tt<8;tt++)
    out[(size_t)(t0+tt)*CC + c] = expf(-expf(tdc + acc[tt]));
}

// ---------------- tanh split-K reduce ----------------
template<int N, int NK>
__global__ __launch_bounds__(256) void tanh_reduce_kernel(
    const float* __restrict__ part, float* __restrict__ out)
{
  int idx = blockIdx.x*256 + threadIdx.x;
  int col = idx & (N-1);
  int row = idx >> (N==256 ? 8 : 7);
  float s = 0.f;
  #pragma unroll
  for(int z=0;z<8;z++) s += part[(size_t)z*TT*N + idx];
  if(col < NK) out[(size_t)row*NK + col] = tanhf(s);
}

// ---------------- W[K,N] f32 -> Wt[NPAD,K] bf16 ----------------
__global__ __launch_bounds__(256) void transpose_f2bf_kernel(
    const float* __restrict__ W, short* __restrict__ Wt, int K, int N)
{
  __shared__ float tile[64][65];
  int n0 = blockIdx.x*64, k0 = blockIdx.y*64;
  int tid = threadIdx.x;
  #pragma unroll
  for(int q=0;q<16;q++){
    int ix = q*256 + tid;
    int r = ix >> 6, cc2 = ix & 63;
    tile[r][cc2] = (n0 + cc2 < N) ? W[(size_t)(k0+r)*N + n0 + cc2] : 0.f;
  }
  __syncthreads();
  #pragma unroll
  for(int q=0;q<16;q++){
    int ix = q*256 + tid;
    int r = ix >> 6, cc2 = ix & 63;
    Wt[(size_t)(n0+r)*K + k0 + cc2] = f2bf(tile[cc2][r]);
  }
}

struct WPtr4 { const float* w[4]; };
__global__ __launch_bounds__(256) void transpose4_f2bf_kernel(
    WPtr4 ws4, short* __restrict__ Wt)
{
  __shared__ float tile[64][65];
  int z = blockIdx.z;
  const float* W = ws4.w[z];
  short* dst = Wt + (size_t)z*CC*CC;
  int n0 = blockIdx.x*64, k0 = blockIdx.y*64;
  int tid = threadIdx.x;
  #pragma unroll
  for(int q=0;q<16;q++){
    int ix = q*256 + tid;
    int r = ix >> 6, cc2 = ix & 63;
    tile[r][cc2] = W[(size_t)(k0+r)*CC + n0 + cc2];
  }
  __syncthreads();
  #pragma unroll
  for(int q=0;q<16;q++){
    int ix = q*256 + tid;
    int r = ix >> 6, cc2 = ix & 63;
    dst[(size_t)(n0+r)*CC + k0 + cc2] = f2bf(tile[cc2][r]);
  }
}

__device__ __forceinline__ void load_lds16(const void* g, void* l){
  __builtin_amdgcn_global_load_lds(
      (const __attribute__((address_space(1))) uint32_t*)g,
      (__attribute__((address_space(3))) uint32_t*)l, 16, 0, 0);
}

// ---------------- 128^2 MFMA GEMM (m97-structure + swizzle) ----------------
// EPI: 0 bf16; 3 relu^2 bf16; 5 f32 partial slab; 6 rkvg batch
template<int EPI>
__global__ __launch_bounds__(256) void gemm_bt_kernel(
    const short* __restrict__ A, const short* __restrict__ Bt,
    void* __restrict__ Cout, int M, int N, int Kstride, int Klen,
    long zA, long zB, long zC)
{
  __shared__ __align__(16) short As[128*64];
  __shared__ __align__(16) short Bs[128*64];
  int z = blockIdx.z;
  const short* A0 = A + (size_t)z*zA;
  const short* B0 = Bt + (size_t)z*zB;
  int tid = threadIdx.x;
  int w = tid >> 6, lane = tid & 63;
  int l16 = lane & 15, lhi = lane >> 4;
  int wr = w >> 1, wc = w & 1;
  int gx = gridDim.x;
  int nwg = gx*gridDim.y;
  int lin = blockIdx.y*gx + blockIdx.x;
  int wg = (lin & 7)*(nwg >> 3) + (lin >> 3);
  int bn = wg % gx, bm = wg / gx;
  const short* Ab = A0 + (size_t)bm*128*Kstride;
  const short* Bb = B0 + (size_t)bn*128*Kstride;
  int srow = w*8 + (lane>>3);
  int scol = lane & 7;
  f32x4 acc[4][4] = {};
  for(int kt=0; kt<Klen; kt+=64){
    __syncthreads();
    #pragma unroll
    for(int q=0;q<4;q++){
      int row = q*32 + srow;
      int c8 = scol ^ (row & 7);
      int ldsoff = (q*256 + w*64)*8;
      load_lds16(Ab + (size_t)row*Kstride + kt + c8*8, As + ldsoff);
      load_lds16(Bb + (size_t)row*Kstride + kt + c8*8, Bs + ldsoff);
    }
    __syncthreads();
    #pragma unroll
    for(int kk=0;kk<2;kk++){
      short8 af[4], bf[4];
      #pragma unroll
      for(int m=0;m<4;m++){
        int row = wr*64 + m*16 + l16;
        int slot = (kk*4 + lhi) ^ (row & 7);
        af[m] = *(const short8*)(As + row*64 + slot*8);
      }
      #pragma unroll
      for(int n=0;n<4;n++){
        int row = wc*64 + n*16 + l16;
        int slot = (kk*4 + lhi) ^ (row & 7);
        bf[n] = *(const short8*)(Bs + row*64 + slot*8);
      }
      #pragma unroll
      for(int m=0;m<4;m++){
        #pragma unroll
        for(int n=0;n<4;n++)
          acc[m][n] = __builtin_amdgcn_mfma_f32_16x16x32_bf16(af[m], bf[n], acc[m][n], 0, 0, 0);
      }
    }
  }
  int m0 = bm*128 + wr*64;
  int n0 = bn*128 + wc*64;
  #pragma unroll
  for(int m=0;m<4;m++){
    #pragma unroll
    for(int n=0;n<4;n++){
      #pragma unroll
      for(int jj=0;jj<4;jj++){
        int row = m0 + m*16 + lhi*4 + jj;
        int col = n0 + n*16 + l16;
        size_t ix = (size_t)row*N + col;
        float val = acc[m][n][jj];
        if constexpr (EPI==0){ ((short*)Cout)[(size_t)z*zC + ix] = f2bf(val); }
        else if constexpr (EPI==3){ float rv = fmaxf(val, 0.f); ((short*)Cout)[ix] = f2bf(rv*rv); }
        else if constexpr (EPI==5){ ((float*)Cout)[(size_t)z*zC + ix] = val; }
        else {
          short* o = (short*)Cout + (size_t)z*zC;
          o[ix] = (z==3) ? f2bf(val/(1.f+expf(-val))) : f2bf(val);
        }
      }
    }
  }
}

// ---------------- 256^2 MFMA GEMM, 8-phase + pipelined counted-lgkm ---------
// ds_reads for phase p+1 issued during phase p (alternating afrA/afrB,
// bfr0/bfr1), waited with counted lgkmcnt(4)/(12) so LDS latency hides
// under MFMA. vmcnt(4) gates at p4/p8 (steady); last iteration drains
// vmcnt(0) at p4 (fixes latent race: skipped staging shifts the retire
// window off the A-odd halves).
template<int EPI>
__global__ __launch_bounds__(512, 1) void gemm256_kernel(
    const short* __restrict__ A, const short* __restrict__ Bt,
    void* __restrict__ Cout, int M, int N, int Kstride, int Klen,
    long zA, long zB, long zC)
{
  __shared__ __align__(16) short As[2][256*64];
  __shared__ __align__(16) short Bs[2][256*64];
  int z = blockIdx.z;
  const short* A0 = A + (size_t)z*zA;
  const short* B0 = Bt + (size_t)z*zB;
  int tid = threadIdx.x;
  int w = tid >> 6, lane = tid & 63;
  int l16 = lane & 15, lhi = lane >> 4;
  int wr = w >> 2, wc = w & 3;
  int gx = gridDim.x;
  int nwg = gx*gridDim.y;
  int lin = blockIdx.y*gx + blockIdx.x;
  int wg = (lin & 7)*(nwg >> 3) + (lin >> 3);
  int bn = wg % gx, bm = wg / gx;
  const short* Ab = A0 + (size_t)bm*256*Kstride;
  const short* Bb = B0 + (size_t)bn*256*Kstride;
  int srow_w = w*8 + (lane>>3);
  int scol = lane & 7;
  f32x4 acc[8][4] = {};
  short8 bfr0[4][2], bfr1[4][2], afrA[2][2], afrB[2][2];

  auto STG = [&](const short* src, short* dst, int half, int kt){
    #pragma unroll
    for(int q=0;q<2;q++){
      int row = half*128 + q*64 + srow_w;
      int c8 = scol ^ (row & 7);
      load_lds16(src + (size_t)row*Kstride + kt + c8*8,
                 dst + (half*128 + q*64 + w*8)*64);
    }
  };
  auto DSA = [&](const short* Ac, int p, short8 afr[2][2]){
    #pragma unroll
    for(int mm=0;mm<2;mm++)
      #pragma unroll
      for(int kk=0;kk<2;kk++){
        int row = wr*128 + (p*2+mm)*16 + l16;
        int slot = (kk*4 + lhi) ^ (row & 7);
        afr[mm][kk] = *(const short8*)(Ac + row*64 + slot*8);
      }
  };
  auto DSB = [&](const short* Bc, short8 bfr[4][2]){
    #pragma unroll
    for(int n=0;n<4;n++)
      #pragma unroll
      for(int kk=0;kk<2;kk++){
        int row = wc*64 + n*16 + l16;
        int slot = (kk*4 + lhi) ^ (row & 7);
        bfr[n][kk] = *(const short8*)(Bc + row*64 + slot*8);
      }
  };
  auto MM = [&](int p, short8 afr[2][2], short8 bfr[4][2]){
    __builtin_amdgcn_s_setprio(1);
    #pragma unroll
    for(int mm=0;mm<2;mm++)
      #pragma unroll
      for(int n=0;n<4;n++)
        #pragma unroll
        for(int kk=0;kk<2;kk++)
          acc[p*2+mm][n] = __builtin_amdgcn_mfma_f32_16x16x32_bf16(
              afr[mm][kk], bfr[n][kk], acc[p*2+mm][n], 0, 0, 0);
    __builtin_amdgcn_s_setprio(0);
  };
  #define SB()   __builtin_amdgcn_sched_barrier(0)
  #define BAR()  __builtin_amdgcn_s_barrier()
  #define LGKM(n) asm volatile("s_waitcnt lgkmcnt(" #n ")" ::: "memory")
  #define VMC(n)  asm volatile("s_waitcnt vmcnt(" #n ")" ::: "memory")

  int NT = Klen >> 6;        // >= 28, even at all call sites
  int niter = NT >> 1;
  // prologue: tile0 (A0,B0) + tile1 B halves; retire tile0; issue p1 reads
  STG(Ab, &As[0][0], 0, 0); STG(Ab, &As[0][0], 1, 0);
  STG(Bb, &Bs[0][0], 0, 0); STG(Bb, &Bs[0][0], 1, 0);
  STG(Bb, &Bs[1][0], 0, 64); STG(Bb, &Bs[1][0], 1, 64);
  VMC(4); BAR(); SB();
  DSB(&Bs[0][0], bfr0); DSA(&As[0][0], 0, afrA);

  for(int i=0;i<niter;++i){
    int kt_o  = (2*i+1) << 6;
    int kt_e2 = (2*i+2) << 6;
    int kt_o2 = (2*i+3) << 6;
    bool st = (i+1 < niter);
    // ---- P1 ----
    STG(Ab, &As[1][0], 0, kt_o);
    BAR(); SB();
    DSA(&As[0][0], 1, afrB);
    LGKM(4); SB();
    MM(0, afrA, bfr0);
    BAR(); SB();
    // ---- P2 ----
    STG(Ab, &As[1][0], 1, kt_o);
    BAR(); SB();
    DSA(&As[0][0], 2, afrA);
    LGKM(4); SB();
    MM(1, afrB, bfr0);
    BAR(); SB();
    // ---- P3 ----
    if(st) STG(Bb, &Bs[0][0], 0, kt_e2);
    BAR(); SB();
    DSA(&As[0][0], 3, afrB);
    LGKM(4); SB();
    MM(2, afrA, bfr0);
    BAR(); SB();
    // ---- P4 ----
    if(st){ STG(Bb, &Bs[0][0], 1, kt_e2); VMC(4); } else { VMC(0); }
    BAR(); SB();
    DSB(&Bs[1][0], bfr1);
    DSA(&As[1][0], 0, afrA);
    LGKM(12); SB();
    MM(3, afrB, bfr0);
    BAR(); SB();
    // ---- P5 ----
    if(st) STG(Ab, &As[0][0], 0, kt_e2);
    BAR(); SB();
    DSA(&As[1][0], 1, afrB);
    LGKM(4); SB();
    MM(0, afrA, bfr1);
    BAR(); SB();
    // ---- P6 ----
    if(st) STG(Ab, &As[0][0], 1, kt_e2);
    BAR(); SB();
    DSA(&As[1][0], 2, afrA);
    LGKM(4); SB();
    MM(1, afrB, bfr1);
    BAR(); SB();
    // ---- P7 ----
    if(st) STG(Bb, &Bs[1][0], 0, kt_o2);
    BAR(); SB();
    DSA(&As[1][0], 3, afrB);
    LGKM(4); SB();
    MM(2, afrA, bfr1);
    BAR(); SB();
    // ---- P8 ----
    if(st){ STG(Bb, &Bs[1][0], 1, kt_o2); VMC(4); } else { VMC(0); }
    BAR(); SB();
    if(st){
      DSB(&Bs[0][0], bfr0);
      DSA(&As[0][0], 0, afrA);
      LGKM(12); SB();
    } else { LGKM(0); SB(); }
    MM(3, afrB, bfr1);
    BAR(); SB();
  }
  #undef SB
  #undef BAR
  #undef LGKM
  #undef VMC

  int m0 = bm*256 + wr*128;
  int n0 = bn*256 + wc*64;
  #pragma unroll
  for(int m=0;m<8;m++){
    #pragma unroll
    for(int n=0;n<4;n++){
      #pragma unroll
      for(int jj=0;jj<4;jj++){
        int row = m0 + m*16 + lhi*4 + jj;
        int col = n0 + n*16 + l16;
        size_t ix = (size_t)row*N + col;
        float val = acc[m][n][jj];
        if constexpr (EPI==3){ float rv = fmaxf(val, 0.f); ((short*)Cout)[ix] = f2bf(rv*rv); }
        else if constexpr (EPI==5){ ((float*)Cout)[(size_t)z*zC + ix] = val; }
        else {
          short* o = (short*)Cout + (size_t)z*zC;
          o[ix] = (z==3) ? f2bf(val/(1.f+expf(-val))) : f2bf(val);
        }
      }
    }
  }
}

// ---------------- WKV pass A ----------------
__global__ __launch_bounds__(256) void wkv_chunk_kernel(
    const short* __restrict__ rb, const short* __restrict__ kb,
    const short* __restrict__ vb, const float* __restrict__ db,
    const float* __restrict__ wkv_state, const float* __restrict__ u,
    const int* __restrict__ sp,
    float* __restrict__ yb, short* __restrict__ rtb,
    float* __restrict__ Bc, float* __restrict__ Pc)
{
  int blk = blockIdx.x;
  int ch = blk >> 5;
  int h  = blk & 31;
  int tid = threadIdx.x;
  int a = tid & 3, j = tid >> 2;
  int w = tid >> 6, lane = tid & 63;
  __shared__ float sr[2][64], sk[2][64], suk[2][64], sv[2][64], sd[2][64];
  __shared__ float sp_[64];
  float u_reg = (w==1) ? u[h*64 + lane] : 0.f;
  if(tid < 64) sp_[tid] = 1.f;
  float S[16];
  #pragma unroll
  for(int ii=0;ii<16;ii++) S[ii]=0.f;
  int sp0=sp[0], sp1=sp[1], sp2=sp[2], sp3=sp[3];
  int tbase = ch*CHUNK;
  {
    size_t gb = (size_t)tbase*CC + h*64;
    if(w==0)      sr[0][lane] = bf2f(rb[gb+lane]);
    else if(w==1){ float kv_=bf2f(kb[gb+lane]); sk[0][lane]=kv_; suk[0][lane]=u_reg*kv_; }
    else if(w==2) sv[0][lane] = bf2f(vb[gb+lane]);
    else          sd[0][lane] = db[gb+lane];
  }
  __syncthreads();
  for(int tl=0; tl<CHUNK; ++tl){
    int t = tbase + tl;
    int buf = tl & 1;
    if(tl+1 < CHUNK){
      size_t nb = (size_t)(t+1)*CC + h*64;
      int b2_ = buf^1;
      if(w==0)      sr[b2_][lane] = bf2f(rb[nb+lane]);
      else if(w==1){ float kv_=bf2f(kb[nb+lane]); sk[b2_][lane]=kv_; suk[b2_][lane]=u_reg*kv_; }
      else if(w==2) sv[b2_][lane] = bf2f(vb[nb+lane]);
      else          sd[b2_][lane] = db[nb+lane];
    }
    size_t base = (size_t)t*CC + h*64;
    bool is_start = (sp0==t)|(sp1==t)|(sp2==t)|(sp3==t);
    if(is_start){
      int sid = (sp0<=t)+(sp1<=t)+(sp2<=t)+(sp3<=t) - 1;
      sid = sid<0?0:(sid>3?3:sid);
      const float* wsrc = wkv_state + (((size_t)sid*NH + h)*HSZ + a*16)*HSZ + j;
      #pragma unroll
      for(int ii=0;ii<16;ii++) S[ii] = wsrc[(size_t)ii*HSZ];
      if(tid < 64) sp_[tid] = 0.f;
    }
    float vj = sv[buf][j];
    float yp = 0.f, bp = 0.f;
    #pragma unroll
    for(int ii=0;ii<16;ii++){
      int i = a*16 + ii;
      float ri = sr[buf][i];
      yp += ri * S[ii];
      bp += ri * suk[buf][i];
    }
    yp += __shfl_xor(yp, 1); yp += __shfl_xor(yp, 2);
    bp += __shfl_xor(bp, 1); bp += __shfl_xor(bp, 2);
    if(a == 0) yb[base + j] = yp + bp*vj;
    if(tid < 64){
      rtb[base + tid] = f2bf(sr[buf][tid] * sp_[tid]);
      sp_[tid] *= sd[buf][tid];
    }
    #pragma unroll
    for(int ii=0;ii<16;ii++){
      int i = a*16 + ii;
      S[ii] = sd[buf][i]*S[ii] + sk[buf][i]*vj;
    }
    __syncthreads();
  }
  size_t cb = ((size_t)ch*NH + h)*HSZ*HSZ;
  #pragma unroll
  for(int ii=0;ii<16;ii++) Bc[cb + (size_t)(a*16+ii)*HSZ + j] = S[ii];
  if(tid < 64) Pc[((size_t)ch*NH + h)*HSZ + tid] = sp_[tid];
}

// ---------------- WKV pass B ----------------
__global__ __launch_bounds__(256) void wkv_combine_kernel(
    float* __restrict__ BS, const float* __restrict__ Pc)
{
  int idx = blockIdx.x*256 + threadIdx.x;
  int hi = idx >> 6;
  float s = 0.f;
  for(int cc=0; cc<NCHUNK; ++cc){
    size_t ix = (size_t)cc*(NH*HSZ*HSZ) + idx;
    float b = BS[ix];
    BS[ix] = s;
    s = Pc[cc*(NH*HSZ) + hi]*s + b;
  }
}

// ---------------- WKV pass C ----------------
__global__ __launch_bounds__(256) void wkv_corr_kernel(
    const short* __restrict__ rtb, const float* __restrict__ Sin, float* __restrict__ yb)
{
  int blk = blockIdx.x;
  int ch = blk >> 5, h = blk & 31;
  __shared__ float Ssm[64][64];
  __shared__ float Rsm[32][65];
  int tid = threadIdx.x;
  const float* Sp = Sin + (size_t)(ch*NH + h)*HSZ*HSZ;
  #pragma unroll
  for(int q=0;q<16;q++) ((float*)Ssm)[q*256+tid] = Sp[q*256+tid];
  #pragma unroll
  for(int q=0;q<8;q++){
    int ix = q*256 + tid;
    int tl = ix>>6, i = ix&63;
    Rsm[tl][i] = bf2f(rtb[(size_t)(ch*CHUNK+tl)*CC + h*64 + i]);
  }
  __syncthreads();
  int tl = tid >> 3;
  int jq = tid & 7;
  float acc[8];
  #pragma unroll
  for(int jj=0;jj<8;jj++) acc[jj]=0.f;
  for(int i=0;i<64;i++){
    float rv = Rsm[tl][i];
    #pragma unroll
    for(int jj=0;jj<8;jj++) acc[jj] += rv * Ssm[i][jq*8+jj];
  }
  #pragma unroll
  for(int jj=0;jj<8;jj++)
    yb[(size_t)(ch*CHUNK+tl)*CC + h*64 + jq*8+jj] += acc[jj];
}

// ---------------- GroupNorm(H groups) * g -> bf16 ----------------
__global__ __launch_bounds__(256) void gn_mul_kernel(
    const float* __restrict__ yb, const short* __restrict__ gb,
    const float* __restrict__ gam, const float* __restrict__ bet,
    short* __restrict__ yg)
{
  int t = blockIdx.x, tid = threadIdx.x;
  int w = tid >> 6, lane = tid & 63;
  for(int q=0;q<8;q++){
    int h = q*4 + w;
    int cc = h*64 + lane;
    float val = yb[(size_t)t*CC + cc];
    float s = val, ss = val*val;
    #pragma unroll
    for(int off=1;off<64;off<<=1){ s += __shfl_xor(s,off); ss += __shfl_xor(ss,off); }
    float mu = s*(1.f/64.f);
    float var = ss*(1.f/64.f) - mu*mu;
    float rstd = rsqrtf(var + 6.4e-4f);
    float o = (val-mu)*rstd*gam[cc] + bet[cc];
    yg[(size_t)t*CC + cc] = f2bf(o * bf2f(gb[(size_t)t*CC + cc]));
  }
}

// ---------------- final: out += sigmoid(s0+s1)*(kv0+kv1+kv2+kv3) ----------------
__global__ __launch_bounds__(256) void final_kernel(
    const float* __restrict__ s0, const float* __restrict__ s1,
    const float* __restrict__ kv0, const float* __restrict__ kv1,
    const float* __restrict__ kv2, const float* __restrict__ kv3,
    float* __restrict__ out)
{
  size_t i = ((size_t)blockIdx.x*256 + threadIdx.x)*8;
  #pragma unroll
  for(int j=0;j<8;j++){
    float sv = s0[i+j] + s1[i+j];
    float sig = 1.f/(1.f + expf(-sv));
    out[i+j] = out[i+j] + sig*(kv0[i+j] + kv1[i+j] + kv2[i+j] + kv3[i+j]);
  }
}

extern "C" void kernel_launch(void* const* d_in, const int* in_sizes, int n_in,
                              void* d_out, int out_size, void* d_ws, size_t ws_size,
                              hipStream_t stream)
{
  (void)in_sizes; (void)n_in; (void)out_size;
  const float* x         = (const float*)d_in[0];
  const int*   sp        = (const int*)d_in[1];
  const float* att_state = (const float*)d_in[2];
  const float* wkv_state = (const float*)d_in[3];
  const float* ffn_state = (const float*)d_in[4];
  const float* ln1_g=(const float*)d_in[5],  *ln1_b=(const float*)d_in[6];
  const float* ln2_g=(const float*)d_in[7],  *ln2_b=(const float*)d_in[8];
  const float* maa_x=(const float*)d_in[9],  *maa_w=(const float*)d_in[10], *maa_k=(const float*)d_in[11];
  const float* maa_v=(const float*)d_in[12], *maa_r=(const float*)d_in[13], *maa_g=(const float*)d_in[14];
  const float* tm_w1=(const float*)d_in[15], *tm_w2=(const float*)d_in[16];
  const float* td=(const float*)d_in[17],    *td_w1=(const float*)d_in[18], *td_w2=(const float*)d_in[19];
  const float* u = (const float*)d_in[20];
  const float* Wr=(const float*)d_in[21], *Wk=(const float*)d_in[22], *Wv=(const float*)d_in[23];
  const float* Wg=(const float*)d_in[24], *Wo=(const float*)d_in[25];
  const float* lnx_g=(const float*)d_in[26], *lnx_b=(const float*)d_in[27];
  const float* cm_k=(const float*)d_in[28],  *cm_r=(const float*)d_in[29];
  const float* Wck=(const float*)d_in[30], *Wcv=(const float*)d_in[31], *Wcr=(const float*)d_in[32];

  char* ws = (char*)d_ws;
  const size_t SLOT  = (size_t)TT*CC*4;
  const size_t BSLOT = (size_t)TT*CC*2;
  const size_t WT_SZ = (size_t)4*CC*CC*2;
  const size_t NEED  = 6*SLOT + 10*BSLOT + WT_SZ + (4u<<20);
  if(ws_size < NEED) return;

  float* xa   = (float*)(ws + 0*SLOT);
  float* xxb  = (float*)(ws + 1*SLOT);
  float* zw   = (float*)(ws + 2*SLOT);
  float* decb = (float*)(ws + 3*SLOT);
  float* yb   = (float*)(ws + 4*SLOT);
  float* S5   = (float*)(ws + 5*SLOT);
  float* BS   = xa;
  float* xxxPart = zw;
  float* h1Part  = yb;
  short* bA   = (short*)(ws + 6*SLOT);
  short* bO   = (short*)(ws + 6*SLOT + 4*BSLOT);
  short* b1 = bO + 0*(TT*CC);
  short* b2 = bO + 1*(TT*CC);
  short* b3 = bO + 2*(TT*CC);
  short* b4 = bO + 3*(TT*CC);
  short* b5 = bO + 4*(TT*CC);
  short* b6 = bO + 5*(TT*CC);
  short* WT = (short*)(ws + 6*SLOT + 10*BSLOT);
  char*  aux = (char*)WT + WT_SZ;
  float* xxxb = (float*)(aux);
  float* h1b  = (float*)(aux + (2u<<20));
  float* Pc   = (float*)(aux + (5u<<19));
  float* xmid = (float*)d_out;

  dim3 B256(256), B512(512);
  const int NTC8 = TT*CC/8/256;

  // ---- Tmix front ----
  ln_kernel<<<TT, B256, 0, stream>>>(x, ln1_g, ln1_b, xa, 1e-5f);
  shift1_kernel<<<TT, B256, 0, stream>>>(xa, att_state, sp, xxb);
  zprep_kernel<<<NTC8, B256, 0, stream>>>(xa, xxb, maa_x, bA);
  transpose_f2bf_kernel<<<dim3(4, CC/64), B256, 0, stream>>>(tm_w1, WT, CC, 160);
  gemm_bt_kernel<5><<<dim3(2, TT/128, 8), B256, 0, stream>>>(bA, WT, xxxPart, TT, 256, CC, 256,
      256, 256, (long)TT*256);
  tanh_reduce_kernel<256,160><<<TT, B256, 0, stream>>>(xxxPart, xxxb);
  mix5_kernel<<<NTC8, B256, 0, stream>>>(xxxb, tm_w2, xa, xxb,
      maa_w, maa_k, maa_v, maa_r, maa_g,
      b5, bA + 1*(TT*CC), bA + 2*(TT*CC), bA, bA + 3*(TT*CC));
  transpose_f2bf_kernel<<<dim3(2, CC/64), B256, 0, stream>>>(td_w1, WT, CC, 64);
  gemm_bt_kernel<5><<<dim3(1, TT/128, 8), B256, 0, stream>>>(b5, WT, h1Part, TT, 128, CC, 256,
      256, 256, (long)TT*128);
  tanh_reduce_kernel<128,64><<<TT/2, B256, 0, stream>>>(h1Part, h1b);
  dec_kernel<<<NTC8, B256, 0, stream>>>(h1b, td_w2, td, decb);

  // ---- r,k,v,g projections: batched 256^2 8-phase GEMM (256 blocks) ----
  WPtr4 w4; w4.w[0]=Wr; w4.w[1]=Wk; w4.w[2]=Wv; w4.w[3]=Wg;
  transpose4_f2bf_kernel<<<dim3(CC/64, CC/64, 4), B256, 0, stream>>>(w4, WT);
  gemm256_kernel<6><<<dim3(CC/256, TT/256, 4), B512, 0, stream>>>(bA, WT, b1, TT, CC, CC, CC,
      (long)TT*CC, (long)CC*CC, (long)TT*CC);

  // ---- WKV chunked scan ----
  wkv_chunk_kernel<<<NCHUNK*NH, B256, 0, stream>>>(b1, b2, b3, decb, wkv_state, u, sp,
                                                   yb, b5, BS, Pc);
  wkv_combine_kernel<<<NH*HSZ*HSZ/256, B256, 0, stream>>>(BS, Pc);
  wkv_corr_kernel<<<NCHUNK*NH, B256, 0, stream>>>(b5, BS, yb);
  gn_mul_kernel<<<TT, B256, 0, stream>>>(yb, b4, lnx_g, lnx_b, b6);

  // ---- output projection (128^2 split-K=2) + fused residual+LN2 ----
  transpose_f2bf_kernel<<<dim3(CC/64, CC/64), B256, 0, stream>>>(Wo, WT, CC, CC);
  gemm_bt_kernel<5><<<dim3(CC/128, TT/128, 2), B256, 0, stream>>>(b6, WT, yb, TT, CC, CC, 1024,
      1024, 1024, (long)TT*CC);
  ln2_fused_kernel<<<TT, B256, 0, stream>>>(yb, S5, x, ln2_g, ln2_b, xmid, zw, 1e-5f);

  // ---- CMix ----
  shift2_kernel<<<TT, B256, 0, stream>>>(zw, ffn_state, sp, cm_k, cm_r, bA, bA + 1*(TT*CC));
  transpose_f2bf_kernel<<<dim3(FFND/64, CC/64), B256, 0, stream>>>(Wck, WT, CC, FFND);
  gemm256_kernel<3><<<dim3(FFND/256, TT/256, 1), B512, 0, stream>>>(bA, WT, b1, TT, FFND, CC, CC,
      0, 0, 0);
  transpose_f2bf_kernel<<<dim3(CC/64, FFND/64), B256, 0, stream>>>(Wcv, WT, FFND, CC);
  gemm256_kernel<5><<<dim3(CC/256, TT/256, 4), B512, 0, stream>>>(b1, WT, zw, TT, CC, FFND, 1792,
      1792, 1792, (long)TT*CC);
  transpose_f2bf_kernel<<<dim3(CC/64, CC/64), B256, 0, stream>>>(Wcr, WT, CC, CC);
  gemm_bt_kernel<5><<<dim3(CC/128, TT/128, 2), B256, 0, stream>>>(bA + 1*(TT*CC), WT, xa, TT, CC, CC, 1024,
      1024, 1024, (long)TT*CC);
  final_kernel<<<NTC8, B256, 0, stream>>>(xa, xxb, zw, decb, yb, S5, xmid);
}

// Round 11
// 702.926 us; speedup vs baseline: 1.2261x; 1.2261x over previous
//
#include <hip/hip_runtime.h>
#include <stdint.h>

// RWKV6 block: B=1, T=2048, C=2048, H=32, HS=64, FFN=7168, NS=4
// Workspace: 6*16M (f32) + 4*8M (bA) + 6*8M (bO) + 32M (WT) + 4M aux = 212 MiB.

#define TT 2048
#define CC 2048
#define NH 32
#define HSZ 64
#define FFND 7168
#define CHUNK 32
#define NCHUNK 64

typedef __attribute__((ext_vector_type(8))) short short8;
typedef __attribute__((ext_vector_type(4))) float f32x4;

__device__ __forceinline__ float bf2f(short s){
  return __uint_as_float(((uint32_t)(uint16_t)s) << 16);
}
__device__ __forceinline__ short f2bf(float f){
  uint32_t u = __float_as_uint(f);
  u = u + 0x7fffu + ((u >> 16) & 1u);
  return (short)(u >> 16);
}

// ---------------- LayerNorm (row over C) ----------------
__global__ __launch_bounds__(256) void ln_kernel(
    const float* __restrict__ xin, const float* __restrict__ gam,
    const float* __restrict__ bet, float* __restrict__ out, float eps)
{
  int t = blockIdx.x, tid = threadIdx.x;
  const float* row = xin + (size_t)t*CC;
  float4 v0 = *(const float4*)(row + tid*8);
  float4 v1 = *(const float4*)(row + tid*8 + 4);
  float s  = v0.x+v0.y+v0.z+v0.w + v1.x+v1.y+v1.z+v1.w;
  float ss = v0.x*v0.x+v0.y*v0.y+v0.z*v0.z+v0.w*v0.w
           + v1.x*v1.x+v1.y*v1.y+v1.z*v1.z+v1.w*v1.w;
  #pragma unroll
  for(int off=1; off<64; off<<=1){ s += __shfl_xor(s,off); ss += __shfl_xor(ss,off); }
  __shared__ float sm[8];
  int w = tid>>6;
  if((tid&63)==0){ sm[w]=s; sm[4+w]=ss; }
  __syncthreads();
  s = sm[0]+sm[1]+sm[2]+sm[3]; ss = sm[4]+sm[5]+sm[6]+sm[7];
  float mean = s * (1.f/CC);
  float var  = ss * (1.f/CC) - mean*mean;
  float rstd = rsqrtf(var + eps);
  float* orow = out + (size_t)t*CC;
  int c = tid*8;
  float vv[8] = {v0.x,v0.y,v0.z,v0.w,v1.x,v1.y,v1.z,v1.w};
  #pragma unroll
  for(int j=0;j<8;j++) orow[c+j] = (vv[j]-mean)*rstd*gam[c+j] + bet[c+j];
}

// ---------------- fused: xmid = p0+p1+x ; zw = LN(xmid) ----------------
__global__ __launch_bounds__(256) void ln2_fused_kernel(
    const float* __restrict__ p0, const float* __restrict__ p1,
    const float* __restrict__ xres, const float* __restrict__ gam,
    const float* __restrict__ bet, float* __restrict__ xsum,
    float* __restrict__ lnout, float eps)
{
  int t = blockIdx.x, tid = threadIdx.x;
  size_t base = (size_t)t*CC + tid*8;
  float vv[8];
  float s = 0.f, ss = 0.f;
  #pragma unroll
  for(int j=0;j<8;j++){
    float v = p0[base+j] + p1[base+j] + xres[base+j];
    vv[j] = v; s += v; ss += v*v;
    xsum[base+j] = v;
  }
  #pragma unroll
  for(int off=1; off<64; off<<=1){ s += __shfl_xor(s,off); ss += __shfl_xor(ss,off); }
  __shared__ float sm[8];
  int w = tid>>6;
  if((tid&63)==0){ sm[w]=s; sm[4+w]=ss; }
  __syncthreads();
  s = sm[0]+sm[1]+sm[2]+sm[3]; ss = sm[4]+sm[5]+sm[6]+sm[7];
  float mean = s * (1.f/CC);
  float var  = ss * (1.f/CC) - mean*mean;
  float rstd = rsqrtf(var + eps);
  int c = tid*8;
  #pragma unroll
  for(int j=0;j<8;j++) lnout[base+j] = (vv[j]-mean)*rstd*gam[c+j] + bet[c+j];
}

// ---------------- token shift (attention): xx = sh - xa (f32 out) ----------------
__global__ __launch_bounds__(256) void shift1_kernel(
    const float* __restrict__ xa, const float* __restrict__ st,
    const int* __restrict__ sp, float* __restrict__ xxb)
{
  int t = blockIdx.x, tid = threadIdx.x;
  int sp0=sp[0], sp1=sp[1], sp2=sp[2], sp3=sp[3];
  bool is_start = (sp0==t)|(sp1==t)|(sp2==t)|(sp3==t);
  int sid = (sp0<=t)+(sp1<=t)+(sp2<=t)+(sp3<=t) - 1;
  sid = sid<0?0:(sid>3?3:sid);
  int c = tid*8;
  const float* src = is_start ? (st + (size_t)sid*CC + c)
                   : (t>0 ? xa + (size_t)(t-1)*CC + c : nullptr);
  const float* cur = xa + (size_t)t*CC + c;
  float* o = xxb + (size_t)t*CC + c;
  #pragma unroll
  for(int jj=0;jj<8;jj++){
    float sh = src ? src[jj] : 0.f;
    o[jj] = sh - cur[jj];
  }
}

// ---------------- token shift (ffn): xk2/xr2 fused, bf16 out ----------------
__global__ __launch_bounds__(256) void shift2_kernel(
    const float* __restrict__ xf, const float* __restrict__ st,
    const int* __restrict__ sp, const float* __restrict__ cmk,
    const float* __restrict__ cmr, short* __restrict__ xk2, short* __restrict__ xr2)
{
  int t = blockIdx.x, tid = threadIdx.x;
  int sp0=sp[0], sp1=sp[1], sp2=sp[2], sp3=sp[3];
  bool is_start = (sp0==t)|(sp1==t)|(sp2==t)|(sp3==t);
  int sid = (sp0<=t)+(sp1<=t)+(sp2<=t)+(sp3<=t) - 1;
  sid = sid<0?0:(sid>3?3:sid);
  int c = tid*8;
  const float* src = is_start ? (st + (size_t)sid*CC + c)
                   : (t>0 ? xf + (size_t)(t-1)*CC + c : nullptr);
  const float* cur = xf + (size_t)t*CC + c;
  size_t ix = (size_t)t*CC + c;
  #pragma unroll
  for(int jj=0;jj<8;jj++){
    float xfv = cur[jj];
    float sh = src ? src[jj] : 0.f;
    float d = sh - xfv;
    xk2[ix+jj] = f2bf(xfv + d*cmk[c+jj]);
    xr2[ix+jj] = f2bf(xfv + d*cmr[c+jj]);
  }
}

// ---------------- z = xa + xx*maa_x -> bf16 ----------------
__global__ __launch_bounds__(256) void zprep_kernel(const float* __restrict__ xa,
   const float* __restrict__ xx, const float* __restrict__ maa, short* __restrict__ z)
{
  size_t i = ((size_t)blockIdx.x*256 + threadIdx.x)*8;
  int c = (int)(i & (CC-1));
  #pragma unroll
  for(int j=0;j<8;j++) z[i+j] = f2bf(xa[i+j] + xx[i+j]*maa[c+j]);
}

// ---------------- fused 5-way maa mix -> bf16 outputs ----------------
// t0/c derived from blockIdx only => xxxb index is wave-uniform => SMEM loads.
__global__ __launch_bounds__(256) void mix5_kernel(
    const float* __restrict__ xxxb, const float* __restrict__ w2,
    const float* __restrict__ xa, const float* __restrict__ xxv,
    const float* __restrict__ mw, const float* __restrict__ mk,
    const float* __restrict__ mv, const float* __restrict__ mr,
    const float* __restrict__ mg,
    short* __restrict__ ow, short* __restrict__ ok, short* __restrict__ ov,
    short* __restrict__ orr, short* __restrict__ og)
{
  int t0 = (blockIdx.x >> 3) * 8;                  // uniform (no tid)
  int c  = ((blockIdx.x & 7) << 8) + threadIdx.x;  // 0..2047
  float acc[5][8];
  #pragma unroll
  for(int s=0;s<5;s++)
    #pragma unroll
    for(int tt=0;tt<8;tt++) acc[s][tt]=0.f;
  #pragma unroll
  for(int s=0;s<5;s++){
    for(int e=0;e<32;e++){
      float wv = w2[(size_t)(s*32+e)*CC + c];
      #pragma unroll
      for(int tt=0;tt<8;tt++)
        acc[s][tt] += xxxb[(size_t)(t0+tt)*160 + s*32 + e] * wv;
    }
  }
  float vmw=mw[c], vmk=mk[c], vmv=mv[c], vmr=mr[c], vmg=mg[c];
  #pragma unroll
  for(int tt=0;tt<8;tt++){
    size_t ix = (size_t)(t0+tt)*CC + c;
    float av = xa[ix], xv = xxv[ix];
    ow[ix]  = f2bf(av + xv*(vmw + acc[0][tt]));
    ok[ix]  = f2bf(av + xv*(vmk + acc[1][tt]));
    ov[ix]  = f2bf(av + xv*(vmv + acc[2][tt]));
    orr[ix] = f2bf(av + xv*(vmr + acc[3][tt]));
    og[ix]  = f2bf(av + xv*(vmg + acc[4][tt]));
  }
}

// ---------------- dec = exp(-exp(td + h1 @ td_w2)) (f32) ----------------
__global__ __launch_bounds__(256) void dec_kernel(
    const float* __restrict__ h1b, const float* __restrict__ tw2,
    const float* __restrict__ td, float* __restrict__ out)
{
  int t0 = (blockIdx.x >> 3) * 8;
  int c  = ((blockIdx.x & 7) << 8) + threadIdx.x;
  float acc[8] = {0,0,0,0,0,0,0,0};
  for(int e=0;e<64;e++){
    float wv = tw2[(size_t)e*CC + c];
    #pragma unroll
    for(int tt=0;tt<8;tt++) acc[tt] += h1b[(size_t)(t0+tt)*64 + e]*wv;
  }
  float tdc = td[c];
  #pragma unroll
  for(int tt=0;tt<8;tt++)
    out[(size_t)(t0+tt)*CC + c] = expf(-expf(tdc + acc[tt]));
}

// ---------------- tanh split-K reduce ----------------
template<int N, int NK>
__global__ __launch_bounds__(256) void tanh_reduce_kernel(
    const float* __restrict__ part, float* __restrict__ out)
{
  int idx = blockIdx.x*256 + threadIdx.x;
  int col = idx & (N-1);
  int row = idx >> (N==256 ? 8 : 7);
  float s = 0.f;
  #pragma unroll
  for(int z=0;z<8;z++) s += part[(size_t)z*TT*N + idx];
  if(col < NK) out[(size_t)row*NK + col] = tanhf(s);
}

// ---------------- W[K,N] f32 -> Wt[NPAD,K] bf16 ----------------
__global__ __launch_bounds__(256) void transpose_f2bf_kernel(
    const float* __restrict__ W, short* __restrict__ Wt, int K, int N)
{
  __shared__ float tile[64][65];
  int n0 = blockIdx.x*64, k0 = blockIdx.y*64;
  int tid = threadIdx.x;
  #pragma unroll
  for(int q=0;q<16;q++){
    int ix = q*256 + tid;
    int r = ix >> 6, cc2 = ix & 63;
    tile[r][cc2] = (n0 + cc2 < N) ? W[(size_t)(k0+r)*N + n0 + cc2] : 0.f;
  }
  __syncthreads();
  #pragma unroll
  for(int q=0;q<16;q++){
    int ix = q*256 + tid;
    int r = ix >> 6, cc2 = ix & 63;
    Wt[(size_t)(n0+r)*K + k0 + cc2] = f2bf(tile[cc2][r]);
  }
}

struct WPtr4 { const float* w[4]; };
__global__ __launch_bounds__(256) void transpose4_f2bf_kernel(
    WPtr4 ws4, short* __restrict__ Wt)
{
  __shared__ float tile[64][65];
  int z = blockIdx.z;
  const float* W = ws4.w[z];
  short* dst = Wt + (size_t)z*CC*CC;
  int n0 = blockIdx.x*64, k0 = blockIdx.y*64;
  int tid = threadIdx.x;
  #pragma unroll
  for(int q=0;q<16;q++){
    int ix = q*256 + tid;
    int r = ix >> 6, cc2 = ix & 63;
    tile[r][cc2] = W[(size_t)(k0+r)*CC + n0 + cc2];
  }
  __syncthreads();
  #pragma unroll
  for(int q=0;q<16;q++){
    int ix = q*256 + tid;
    int r = ix >> 6, cc2 = ix & 63;
    dst[(size_t)(n0+r)*CC + k0 + cc2] = f2bf(tile[cc2][r]);
  }
}

__device__ __forceinline__ void load_lds16(const void* g, void* l){
  __builtin_amdgcn_global_load_lds(
      (const __attribute__((address_space(1))) uint32_t*)g,
      (__attribute__((address_space(3))) uint32_t*)l, 16, 0, 0);
}

// ---------------- 128^2 MFMA GEMM (m97-structure + swizzle) ----------------
// EPI: 0 bf16; 3 relu^2 bf16; 5 f32 partial slab; 6 rkvg batch
template<int EPI>
__global__ __launch_bounds__(256) void gemm_bt_kernel(
    const short* __restrict__ A, const short* __restrict__ Bt,
    void* __restrict__ Cout, int M, int N, int Kstride, int Klen,
    long zA, long zB, long zC)
{
  __shared__ __align__(16) short As[128*64];
  __shared__ __align__(16) short Bs[128*64];
  int z = blockIdx.z;
  const short* A0 = A + (size_t)z*zA;
  const short* B0 = Bt + (size_t)z*zB;
  int tid = threadIdx.x;
  int w = tid >> 6, lane = tid & 63;
  int l16 = lane & 15, lhi = lane >> 4;
  int wr = w >> 1, wc = w & 1;
  int gx = gridDim.x;
  int nwg = gx*gridDim.y;
  int lin = blockIdx.y*gx + blockIdx.x;
  int wg = (lin & 7)*(nwg >> 3) + (lin >> 3);
  int bn = wg % gx, bm = wg / gx;
  const short* Ab = A0 + (size_t)bm*128*Kstride;
  const short* Bb = B0 + (size_t)bn*128*Kstride;
  int srow = w*8 + (lane>>3);
  int scol = lane & 7;
  f32x4 acc[4][4] = {};
  for(int kt=0; kt<Klen; kt+=64){
    __syncthreads();
    #pragma unroll
    for(int q=0;q<4;q++){
      int row = q*32 + srow;
      int c8 = scol ^ (row & 7);
      int ldsoff = (q*256 + w*64)*8;
      load_lds16(Ab + (size_t)row*Kstride + kt + c8*8, As + ldsoff);
      load_lds16(Bb + (size_t)row*Kstride + kt + c8*8, Bs + ldsoff);
    }
    __syncthreads();
    #pragma unroll
    for(int kk=0;kk<2;kk++){
      short8 af[4], bf[4];
      #pragma unroll
      for(int m=0;m<4;m++){
        int row = wr*64 + m*16 + l16;
        int slot = (kk*4 + lhi) ^ (row & 7);
        af[m] = *(const short8*)(As + row*64 + slot*8);
      }
      #pragma unroll
      for(int n=0;n<4;n++){
        int row = wc*64 + n*16 + l16;
        int slot = (kk*4 + lhi) ^ (row & 7);
        bf[n] = *(const short8*)(Bs + row*64 + slot*8);
      }
      #pragma unroll
      for(int m=0;m<4;m++){
        #pragma unroll
        for(int n=0;n<4;n++)
          acc[m][n] = __builtin_amdgcn_mfma_f32_16x16x32_bf16(af[m], bf[n], acc[m][n], 0, 0, 0);
      }
    }
  }
  int m0 = bm*128 + wr*64;
  int n0 = bn*128 + wc*64;
  #pragma unroll
  for(int m=0;m<4;m++){
    #pragma unroll
    for(int n=0;n<4;n++){
      #pragma unroll
      for(int jj=0;jj<4;jj++){
        int row = m0 + m*16 + lhi*4 + jj;
        int col = n0 + n*16 + l16;
        size_t ix = (size_t)row*N + col;
        float val = acc[m][n][jj];
        if constexpr (EPI==0){ ((short*)Cout)[(size_t)z*zC + ix] = f2bf(val); }
        else if constexpr (EPI==3){ float rv = fmaxf(val, 0.f); ((short*)Cout)[ix] = f2bf(rv*rv); }
        else if constexpr (EPI==5){ ((float*)Cout)[(size_t)z*zC + ix] = val; }
        else {
          short* o = (short*)Cout + (size_t)z*zC;
          o[ix] = (z==3) ? f2bf(val/(1.f+expf(-val))) : f2bf(val);
        }
      }
    }
  }
}

// ---------------- 256^2 MFMA GEMM, fine 8-phase counted-vmcnt schedule ------
// (round-9 structure: per-phase lgkmcnt(0); counted vmcnt(4) at P4/P8 in
// steady state, vmcnt(0) on the LAST iteration where staging is skipped.)
template<int EPI>
__global__ __launch_bounds__(512, 1) void gemm256_kernel(
    const short* __restrict__ A, const short* __restrict__ Bt,
    void* __restrict__ Cout, int M, int N, int Kstride, int Klen,
    long zA, long zB, long zC)
{
  __shared__ __align__(16) short As[2][256*64];
  __shared__ __align__(16) short Bs[2][256*64];
  int z = blockIdx.z;
  const short* A0 = A + (size_t)z*zA;
  const short* B0 = Bt + (size_t)z*zB;
  int tid = threadIdx.x;
  int w = tid >> 6, lane = tid & 63;
  int l16 = lane & 15, lhi = lane >> 4;
  int wr = w >> 2, wc = w & 3;
  int gx = gridDim.x;
  int nwg = gx*gridDim.y;
  int lin = blockIdx.y*gx + blockIdx.x;
  int wg = (lin & 7)*(nwg >> 3) + (lin >> 3);
  int bn = wg % gx, bm = wg / gx;
  const short* Ab = A0 + (size_t)bm*256*Kstride;
  const short* Bb = B0 + (size_t)bn*256*Kstride;
  int srow_w = w*8 + (lane>>3);
  int scol = lane & 7;
  f32x4 acc[8][4] = {};

  auto STG = [&](const short* src, short* dst, int half, int kt){
    #pragma unroll
    for(int q=0;q<2;q++){
      int row = half*128 + q*64 + srow_w;
      int c8 = scol ^ (row & 7);
      load_lds16(src + (size_t)row*Kstride + kt + c8*8,
                 dst + (half*128 + q*64 + w*8)*64);
    }
  };
  auto DSA = [&](const short* Ac, int p, short8 afr[2][2]){
    #pragma unroll
    for(int mm=0;mm<2;mm++)
      #pragma unroll
      for(int kk=0;kk<2;kk++){
        int row = wr*128 + (p*2+mm)*16 + l16;
        int slot = (kk*4 + lhi) ^ (row & 7);
        afr[mm][kk] = *(const short8*)(Ac + row*64 + slot*8);
      }
  };
  auto DSB = [&](const short* Bc, short8 bfr[4][2]){
    #pragma unroll
    for(int n=0;n<4;n++)
      #pragma unroll
      for(int kk=0;kk<2;kk++){
        int row = wc*64 + n*16 + l16;
        int slot = (kk*4 + lhi) ^ (row & 7);
        bfr[n][kk] = *(const short8*)(Bc + row*64 + slot*8);
      }
  };
  auto MM = [&](int p, short8 afr[2][2], short8 bfr[4][2]){
    __builtin_amdgcn_s_setprio(1);
    #pragma unroll
    for(int mm=0;mm<2;mm++)
      #pragma unroll
      for(int n=0;n<4;n++)
        #pragma unroll
        for(int kk=0;kk<2;kk++)
          acc[p*2+mm][n] = __builtin_amdgcn_mfma_f32_16x16x32_bf16(
              afr[mm][kk], bfr[n][kk], acc[p*2+mm][n], 0, 0, 0);
    __builtin_amdgcn_s_setprio(0);
  };
  #define PH_SYNC() do{ __builtin_amdgcn_s_barrier(); \
      asm volatile("s_waitcnt lgkmcnt(0)" ::: "memory"); \
      __builtin_amdgcn_sched_barrier(0); }while(0)
  #define PH_END() do{ __builtin_amdgcn_s_barrier(); \
      __builtin_amdgcn_sched_barrier(0); }while(0)

  int NT = Klen >> 6;
  int niter = NT >> 1;
  STG(Ab, &As[0][0], 0, 0); STG(Ab, &As[0][0], 1, 0);
  STG(Bb, &Bs[0][0], 0, 0); STG(Bb, &Bs[0][0], 1, 0);
  STG(Bb, &Bs[1][0], 0, 64); STG(Bb, &Bs[1][0], 1, 64);
  asm volatile("s_waitcnt vmcnt(4)" ::: "memory");
  __builtin_amdgcn_s_barrier();
  __builtin_amdgcn_sched_barrier(0);

  for(int i=0;i<niter;++i){
    int kt_o  = (2*i+1) << 6;
    int kt_e2 = (2*i+2) << 6;
    int kt_o2 = (2*i+3) << 6;
    bool st = (i+1 < niter);
    short8 bfr[4][2], afr[2][2];
    DSB(&Bs[0][0], bfr);
    DSA(&As[0][0], 0, afr);
    STG(Ab, &As[1][0], 0, kt_o);
    PH_SYNC(); MM(0, afr, bfr); PH_END();
    DSA(&As[0][0], 1, afr);
    STG(Ab, &As[1][0], 1, kt_o);
    PH_SYNC(); MM(1, afr, bfr); PH_END();
    DSA(&As[0][0], 2, afr);
    if(st) STG(Bb, &Bs[0][0], 0, kt_e2);
    PH_SYNC(); MM(2, afr, bfr); PH_END();
    DSA(&As[0][0], 3, afr);
    if(st){ STG(Bb, &Bs[0][0], 1, kt_e2);
            asm volatile("s_waitcnt vmcnt(4)" ::: "memory"); }
    else  { asm volatile("s_waitcnt vmcnt(0)" ::: "memory"); }
    PH_SYNC(); MM(3, afr, bfr); PH_END();
    DSB(&Bs[1][0], bfr);
    DSA(&As[1][0], 0, afr);
    if(st) STG(Ab, &As[0][0], 0, kt_e2);
    PH_SYNC(); MM(0, afr, bfr); PH_END();
    DSA(&As[1][0], 1, afr);
    if(st) STG(Ab, &As[0][0], 1, kt_e2);
    PH_SYNC(); MM(1, afr, bfr); PH_END();
    DSA(&As[1][0], 2, afr);
    if(st) STG(Bb, &Bs[1][0], 0, kt_o2);
    PH_SYNC(); MM(2, afr, bfr); PH_END();
    DSA(&As[1][0], 3, afr);
    if(st){ STG(Bb, &Bs[1][0], 1, kt_o2);
            asm volatile("s_waitcnt vmcnt(4)" ::: "memory"); }
    else  { asm volatile("s_waitcnt vmcnt(0)" ::: "memory"); }
    PH_SYNC(); MM(3, afr, bfr); PH_END();
  }
  #undef PH_SYNC
  #undef PH_END

  int m0 = bm*256 + wr*128;
  int n0 = bn*256 + wc*64;
  #pragma unroll
  for(int m=0;m<8;m++){
    #pragma unroll
    for(int n=0;n<4;n++){
      #pragma unroll
      for(int jj=0;jj<4;jj++){
        int row = m0 + m*16 + lhi*4 + jj;
        int col = n0 + n*16 + l16;
        size_t ix = (size_t)row*N + col;
        float val = acc[m][n][jj];
        if constexpr (EPI==3){ float rv = fmaxf(val, 0.f); ((short*)Cout)[ix] = f2bf(rv*rv); }
        else if constexpr (EPI==5){ ((float*)Cout)[(size_t)z*zC + ix] = val; }
        else {
          short* o = (short*)Cout + (size_t)z*zC;
          o[ix] = (z==3) ? f2bf(val/(1.f+expf(-val))) : f2bf(val);
        }
      }
    }
  }
}

// ---------------- WKV pass A ----------------
__global__ __launch_bounds__(256) void wkv_chunk_kernel(
    const short* __restrict__ rb, const short* __restrict__ kb,
    const short* __restrict__ vb, const float* __restrict__ db,
    const float* __restrict__ wkv_state, const float* __restrict__ u,
    const int* __restrict__ sp,
    float* __restrict__ yb, short* __restrict__ rtb,
    float* __restrict__ Bc, float* __restrict__ Pc)
{
  int blk = blockIdx.x;
  int ch = blk >> 5;
  int h  = blk & 31;
  int tid = threadIdx.x;
  int a = tid & 3, j = tid >> 2;
  int w = tid >> 6, lane = tid & 63;
  __shared__ float sr[2][64], sk[2][64], suk[2][64], sv[2][64], sd[2][64];
  __shared__ float sp_[64];
  float u_reg = (w==1) ? u[h*64 + lane] : 0.f;
  if(tid < 64) sp_[tid] = 1.f;
  float S[16];
  #pragma unroll
  for(int ii=0;ii<16;ii++) S[ii]=0.f;
  int sp0=sp[0], sp1=sp[1], sp2=sp[2], sp3=sp[3];
  int tbase = ch*CHUNK;
  {
    size_t gb = (size_t)tbase*CC + h*64;
    if(w==0)      sr[0][lane] = bf2f(rb[gb+lane]);
    else if(w==1){ float kv_=bf2f(kb[gb+lane]); sk[0][lane]=kv_; suk[0][lane]=u_reg*kv_; }
    else if(w==2) sv[0][lane] = bf2f(vb[gb+lane]);
    else          sd[0][lane] = db[gb+lane];
  }
  __syncthreads();
  for(int tl=0; tl<CHUNK; ++tl){
    int t = tbase + tl;
    int buf = tl & 1;
    if(tl+1 < CHUNK){
      size_t nb = (size_t)(t+1)*CC + h*64;
      int b2_ = buf^1;
      if(w==0)      sr[b2_][lane] = bf2f(rb[nb+lane]);
      else if(w==1){ float kv_=bf2f(kb[nb+lane]); sk[b2_][lane]=kv_; suk[b2_][lane]=u_reg*kv_; }
      else if(w==2) sv[b2_][lane] = bf2f(vb[nb+lane]);
      else          sd[b2_][lane] = db[nb+lane];
    }
    size_t base = (size_t)t*CC + h*64;
    bool is_start = (sp0==t)|(sp1==t)|(sp2==t)|(sp3==t);
    if(is_start){
      int sid = (sp0<=t)+(sp1<=t)+(sp2<=t)+(sp3<=t) - 1;
      sid = sid<0?0:(sid>3?3:sid);
      const float* wsrc = wkv_state + (((size_t)sid*NH + h)*HSZ + a*16)*HSZ + j;
      #pragma unroll
      for(int ii=0;ii<16;ii++) S[ii] = wsrc[(size_t)ii*HSZ];
      if(tid < 64) sp_[tid] = 0.f;
    }
    float vj = sv[buf][j];
    float yp = 0.f, bp = 0.f;
    #pragma unroll
    for(int ii=0;ii<16;ii++){
      int i = a*16 + ii;
      float ri = sr[buf][i];
      yp += ri * S[ii];
      bp += ri * suk[buf][i];
    }
    yp += __shfl_xor(yp, 1); yp += __shfl_xor(yp, 2);
    bp += __shfl_xor(bp, 1); bp += __shfl_xor(bp, 2);
    if(a == 0) yb[base + j] = yp + bp*vj;
    if(tid < 64){
      rtb[base + tid] = f2bf(sr[buf][tid] * sp_[tid]);
      sp_[tid] *= sd[buf][tid];
    }
    #pragma unroll
    for(int ii=0;ii<16;ii++){
      int i = a*16 + ii;
      S[ii] = sd[buf][i]*S[ii] + sk[buf][i]*vj;
    }
    __syncthreads();
  }
  size_t cb = ((size_t)ch*NH + h)*HSZ*HSZ;
  #pragma unroll
  for(int ii=0;ii<16;ii++) Bc[cb + (size_t)(a*16+ii)*HSZ + j] = S[ii];
  if(tid < 64) Pc[((size_t)ch*NH + h)*HSZ + tid] = sp_[tid];
}

// ---------------- WKV pass B ----------------
__global__ __launch_bounds__(256) void wkv_combine_kernel(
    float* __restrict__ BS, const float* __restrict__ Pc)
{
  int idx = blockIdx.x*256 + threadIdx.x;
  int hi = idx >> 6;
  float s = 0.f;
  for(int cc=0; cc<NCHUNK; ++cc){
    size_t ix = (size_t)cc*(NH*HSZ*HSZ) + idx;
    float b = BS[ix];
    BS[ix] = s;
    s = Pc[cc*(NH*HSZ) + hi]*s + b;
  }
}

// ---------------- WKV pass C ----------------
__global__ __launch_bounds__(256) void wkv_corr_kernel(
    const short* __restrict__ rtb, const float* __restrict__ Sin, float* __restrict__ yb)
{
  int blk = blockIdx.x;
  int ch = blk >> 5, h = blk & 31;
  __shared__ float Ssm[64][64];
  __shared__ float Rsm[32][65];
  int tid = threadIdx.x;
  const float* Sp = Sin + (size_t)(ch*NH + h)*HSZ*HSZ;
  #pragma unroll
  for(int q=0;q<16;q++) ((float*)Ssm)[q*256+tid] = Sp[q*256+tid];
  #pragma unroll
  for(int q=0;q<8;q++){
    int ix = q*256 + tid;
    int tl = ix>>6, i = ix&63;
    Rsm[tl][i] = bf2f(rtb[(size_t)(ch*CHUNK+tl)*CC + h*64 + i]);
  }
  __syncthreads();
  int tl = tid >> 3;
  int jq = tid & 7;
  float acc[8];
  #pragma unroll
  for(int jj=0;jj<8;jj++) acc[jj]=0.f;
  for(int i=0;i<64;i++){
    float rv = Rsm[tl][i];
    #pragma unroll
    for(int jj=0;jj<8;jj++) acc[jj] += rv * Ssm[i][jq*8+jj];
  }
  #pragma unroll
  for(int jj=0;jj<8;jj++)
    yb[(size_t)(ch*CHUNK+tl)*CC + h*64 + jq*8+jj] += acc[jj];
}

// ---------------- GroupNorm(H groups) * g -> bf16 ----------------
__global__ __launch_bounds__(256) void gn_mul_kernel(
    const float* __restrict__ yb, const short* __restrict__ gb,
    const float* __restrict__ gam, const float* __restrict__ bet,
    short* __restrict__ yg)
{
  int t = blockIdx.x, tid = threadIdx.x;
  int w = tid >> 6, lane = tid & 63;
  for(int q=0;q<8;q++){
    int h = q*4 + w;
    int cc = h*64 + lane;
    float val = yb[(size_t)t*CC + cc];
    float s = val, ss = val*val;
    #pragma unroll
    for(int off=1;off<64;off<<=1){ s += __shfl_xor(s,off); ss += __shfl_xor(ss,off); }
    float mu = s*(1.f/64.f);
    float var = ss*(1.f/64.f) - mu*mu;
    float rstd = rsqrtf(var + 6.4e-4f);
    float o = (val-mu)*rstd*gam[cc] + bet[cc];
    yg[(size_t)t*CC + cc] = f2bf(o * bf2f(gb[(size_t)t*CC + cc]));
  }
}

// ---------------- final: out += sigmoid(s0+s1)*(kv0+kv1+kv2+kv3) ----------------
__global__ __launch_bounds__(256) void final_kernel(
    const float* __restrict__ s0, const float* __restrict__ s1,
    const float* __restrict__ kv0, const float* __restrict__ kv1,
    const float* __restrict__ kv2, const float* __restrict__ kv3,
    float* __restrict__ out)
{
  size_t i = ((size_t)blockIdx.x*256 + threadIdx.x)*8;
  #pragma unroll
  for(int j=0;j<8;j++){
    float sv = s0[i+j] + s1[i+j];
    float sig = 1.f/(1.f + expf(-sv));
    out[i+j] = out[i+j] + sig*(kv0[i+j] + kv1[i+j] + kv2[i+j] + kv3[i+j]);
  }
}

extern "C" void kernel_launch(void* const* d_in, const int* in_sizes, int n_in,
                              void* d_out, int out_size, void* d_ws, size_t ws_size,
                              hipStream_t stream)
{
  (void)in_sizes; (void)n_in; (void)out_size;
  const float* x         = (const float*)d_in[0];
  const int*   sp        = (const int*)d_in[1];
  const float* att_state = (const float*)d_in[2];
  const float* wkv_state = (const float*)d_in[3];
  const float* ffn_state = (const float*)d_in[4];
  const float* ln1_g=(const float*)d_in[5],  *ln1_b=(const float*)d_in[6];
  const float* ln2_g=(const float*)d_in[7],  *ln2_b=(const float*)d_in[8];
  const float* maa_x=(const float*)d_in[9],  *maa_w=(const float*)d_in[10], *maa_k=(const float*)d_in[11];
  const float* maa_v=(const float*)d_in[12], *maa_r=(const float*)d_in[13], *maa_g=(const float*)d_in[14];
  const float* tm_w1=(const float*)d_in[15], *tm_w2=(const float*)d_in[16];
  const float* td=(const float*)d_in[17],    *td_w1=(const float*)d_in[18], *td_w2=(const float*)d_in[19];
  const float* u = (const float*)d_in[20];
  const float* Wr=(const float*)d_in[21], *Wk=(const float*)d_in[22], *Wv=(const float*)d_in[23];
  const float* Wg=(const float*)d_in[24], *Wo=(const float*)d_in[25];
  const float* lnx_g=(const float*)d_in[26], *lnx_b=(const float*)d_in[27];
  const float* cm_k=(const float*)d_in[28],  *cm_r=(const float*)d_in[29];
  const float* Wck=(const float*)d_in[30], *Wcv=(const float*)d_in[31], *Wcr=(const float*)d_in[32];

  char* ws = (char*)d_ws;
  const size_t SLOT  = (size_t)TT*CC*4;
  const size_t BSLOT = (size_t)TT*CC*2;
  const size_t WT_SZ = (size_t)4*CC*CC*2;
  const size_t NEED  = 6*SLOT + 10*BSLOT + WT_SZ + (4u<<20);
  if(ws_size < NEED) return;

  float* xa   = (float*)(ws + 0*SLOT);
  float* xxb  = (float*)(ws + 1*SLOT);
  float* zw   = (float*)(ws + 2*SLOT);
  float* decb = (float*)(ws + 3*SLOT);
  float* yb   = (float*)(ws + 4*SLOT);
  float* S5   = (float*)(ws + 5*SLOT);
  float* BS   = xa;
  float* xxxPart = zw;
  float* h1Part  = yb;
  short* bA   = (short*)(ws + 6*SLOT);
  short* bO   = (short*)(ws + 6*SLOT + 4*BSLOT);
  short* b1 = bO + 0*(TT*CC);
  short* b2 = bO + 1*(TT*CC);
  short* b3 = bO + 2*(TT*CC);
  short* b4 = bO + 3*(TT*CC);
  short* b5 = bO + 4*(TT*CC);
  short* b6 = bO + 5*(TT*CC);
  short* WT = (short*)(ws + 6*SLOT + 10*BSLOT);
  char*  aux = (char*)WT + WT_SZ;
  float* xxxb = (float*)(aux);
  float* h1b  = (float*)(aux + (2u<<20));
  float* Pc   = (float*)(aux + (5u<<19));
  float* xmid = (float*)d_out;

  dim3 B256(256), B512(512);
  const int NTC8 = TT*CC/8/256;

  // ---- Tmix front ----
  ln_kernel<<<TT, B256, 0, stream>>>(x, ln1_g, ln1_b, xa, 1e-5f);
  shift1_kernel<<<TT, B256, 0, stream>>>(xa, att_state, sp, xxb);
  zprep_kernel<<<NTC8, B256, 0, stream>>>(xa, xxb, maa_x, bA);
  transpose_f2bf_kernel<<<dim3(4, CC/64), B256, 0, stream>>>(tm_w1, WT, CC, 160);
  gemm_bt_kernel<5><<<dim3(2, TT/128, 8), B256, 0, stream>>>(bA, WT, xxxPart, TT, 256, CC, 256,
      256, 256, (long)TT*256);
  tanh_reduce_kernel<256,160><<<TT, B256, 0, stream>>>(xxxPart, xxxb);
  mix5_kernel<<<NTC8, B256, 0, stream>>>(xxxb, tm_w2, xa, xxb,
      maa_w, maa_k, maa_v, maa_r, maa_g,
      b5, bA + 1*(TT*CC), bA + 2*(TT*CC), bA, bA + 3*(TT*CC));
  transpose_f2bf_kernel<<<dim3(2, CC/64), B256, 0, stream>>>(td_w1, WT, CC, 64);
  gemm_bt_kernel<5><<<dim3(1, TT/128, 8), B256, 0, stream>>>(b5, WT, h1Part, TT, 128, CC, 256,
      256, 256, (long)TT*128);
  tanh_reduce_kernel<128,64><<<TT/2, B256, 0, stream>>>(h1Part, h1b);
  dec_kernel<<<NTC8, B256, 0, stream>>>(h1b, td_w2, td, decb);

  // ---- r,k,v,g projections: batched 256^2 8-phase GEMM (256 blocks) ----
  WPtr4 w4; w4.w[0]=Wr; w4.w[1]=Wk; w4.w[2]=Wv; w4.w[3]=Wg;
  transpose4_f2bf_kernel<<<dim3(CC/64, CC/64, 4), B256, 0, stream>>>(w4, WT);
  gemm256_kernel<6><<<dim3(CC/256, TT/256, 4), B512, 0, stream>>>(bA, WT, b1, TT, CC, CC, CC,
      (long)TT*CC, (long)CC*CC, (long)TT*CC);

  // ---- WKV chunked scan ----
  wkv_chunk_kernel<<<NCHUNK*NH, B256, 0, stream>>>(b1, b2, b3, decb, wkv_state, u, sp,
                                                   yb, b5, BS, Pc);
  wkv_combine_kernel<<<NH*HSZ*HSZ/256, B256, 0, stream>>>(BS, Pc);
  wkv_corr_kernel<<<NCHUNK*NH, B256, 0, stream>>>(b5, BS, yb);
  gn_mul_kernel<<<TT, B256, 0, stream>>>(yb, b4, lnx_g, lnx_b, b6);

  // ---- output projection (128^2 split-K=2) + fused residual+LN2 ----
  transpose_f2bf_kernel<<<dim3(CC/64, CC/64), B256, 0, stream>>>(Wo, WT, CC, CC);
  gemm_bt_kernel<5><<<dim3(CC/128, TT/128, 2), B256, 0, stream>>>(b6, WT, yb, TT, CC, CC, 1024,
      1024, 1024, (long)TT*CC);
  ln2_fused_kernel<<<TT, B256, 0, stream>>>(yb, S5, x, ln2_g, ln2_b, xmid, zw, 1e-5f);

  // ---- CMix ----
  shift2_kernel<<<TT, B256, 0, stream>>>(zw, ffn_state, sp, cm_k, cm_r, bA, bA + 1*(TT*CC));
  transpose_f2bf_kernel<<<dim3(FFND/64, CC/64), B256, 0, stream>>>(Wck, WT, CC, FFND);
  gemm256_kernel<3><<<dim3(FFND/256, TT/256, 1), B512, 0, stream>>>(bA, WT, b1, TT, FFND, CC, CC,
      0, 0, 0);
  transpose_f2bf_kernel<<<dim3(CC/64, FFND/64), B256, 0, stream>>>(Wcv, WT, FFND, CC);
  gemm256_kernel<5><<<dim3(CC/256, TT/256, 4), B512, 0, stream>>>(b1, WT, zw, TT, CC, FFND, 1792,
      1792, 1792, (long)TT*CC);
  transpose_f2bf_kernel<<<dim3(CC/64, CC/64), B256, 0, stream>>>(Wcr, WT, CC, CC);
  gemm_bt_kernel<5><<<dim3(CC/128, TT/128, 2), B256, 0, stream>>>(bA + 1*(TT*CC), WT, xa, TT, CC, CC, 1024,
      1024, 1024, (long)TT*CC);
  final_kernel<<<NTC8, B256, 0, stream>>>(xa, xxb, zw, decb, yb, S5, xmid);
}

// Round 12
// 698.997 us; speedup vs baseline: 1.2330x; 1.0056x over previous
//
#include <hip/hip_runtime.h>
#include <stdint.h>

// RWKV6 block: B=1, T=2048, C=2048, H=32, HS=64, FFN=7168, NS=4
// Workspace: 6*16M (f32) + 4*8M (bA) + 6*8M (bO) + 32M (WT) + 4M aux = 212 MiB.

#define TT 2048
#define CC 2048
#define NH 32
#define HSZ 64
#define FFND 7168
#define CHUNK 32
#define NCHUNK 64

typedef __attribute__((ext_vector_type(8))) short short8;
typedef __attribute__((ext_vector_type(4))) float f32x4;

__device__ __forceinline__ float bf2f(short s){
  return __uint_as_float(((uint32_t)(uint16_t)s) << 16);
}
__device__ __forceinline__ short f2bf(float f){
  uint32_t u = __float_as_uint(f);
  u = u + 0x7fffu + ((u >> 16) & 1u);
  return (short)(u >> 16);
}

// ---------------- fused front: LN1(t) + LN1(t-1) + shift + z-prep ----------------
// Per block t: recomputes LN of row t-1 (bit-identical to row-t path) so the
// token-shift needs no separate xa pass. Emits xa (f32), xx (f32), z (bf16).
__global__ __launch_bounds__(256) void front_kernel(
    const float* __restrict__ x, const float* __restrict__ st,
    const int* __restrict__ sp, const float* __restrict__ gam,
    const float* __restrict__ bet, const float* __restrict__ maa,
    float* __restrict__ xa, float* __restrict__ xxb, short* __restrict__ z)
{
  int t = blockIdx.x, tid = threadIdx.x;
  const float* row = x + (size_t)t*CC;
  float4 a0 = *(const float4*)(row + tid*8);
  float4 a1 = *(const float4*)(row + tid*8 + 4);
  bool hp = (t > 0);
  float4 p0 = make_float4(0.f,0.f,0.f,0.f), p1 = p0;
  if(hp){
    const float* prow = x + (size_t)(t-1)*CC;
    p0 = *(const float4*)(prow + tid*8);
    p1 = *(const float4*)(prow + tid*8 + 4);
  }
  float sa  = a0.x+a0.y+a0.z+a0.w + a1.x+a1.y+a1.z+a1.w;
  float ssa = a0.x*a0.x+a0.y*a0.y+a0.z*a0.z+a0.w*a0.w
            + a1.x*a1.x+a1.y*a1.y+a1.z*a1.z+a1.w*a1.w;
  float sq  = p0.x+p0.y+p0.z+p0.w + p1.x+p1.y+p1.z+p1.w;
  float ssq = p0.x*p0.x+p0.y*p0.y+p0.z*p0.z+p0.w*p0.w
            + p1.x*p1.x+p1.y*p1.y+p1.z*p1.z+p1.w*p1.w;
  #pragma unroll
  for(int off=1; off<64; off<<=1){
    sa += __shfl_xor(sa,off); ssa += __shfl_xor(ssa,off);
    sq += __shfl_xor(sq,off); ssq += __shfl_xor(ssq,off);
  }
  __shared__ float sm[16];
  int w = tid>>6;
  if((tid&63)==0){ sm[w]=sa; sm[4+w]=ssa; sm[8+w]=sq; sm[12+w]=ssq; }
  __syncthreads();
  sa = sm[0]+sm[1]+sm[2]+sm[3];    ssa = sm[4]+sm[5]+sm[6]+sm[7];
  sq = sm[8]+sm[9]+sm[10]+sm[11];  ssq = sm[12]+sm[13]+sm[14]+sm[15];
  float mean_a = sa*(1.f/CC);
  float rstd_a = rsqrtf(ssa*(1.f/CC) - mean_a*mean_a + 1e-5f);
  float mean_q = sq*(1.f/CC);
  float rstd_q = rsqrtf(ssq*(1.f/CC) - mean_q*mean_q + 1e-5f);
  int sp0=sp[0], sp1=sp[1], sp2=sp[2], sp3=sp[3];
  bool is_start = (sp0==t)|(sp1==t)|(sp2==t)|(sp3==t);
  int sid = (sp0<=t)+(sp1<=t)+(sp2<=t)+(sp3<=t) - 1;
  sid = sid<0?0:(sid>3?3:sid);
  int c = tid*8;
  size_t base = (size_t)t*CC + c;
  float av[8] = {a0.x,a0.y,a0.z,a0.w,a1.x,a1.y,a1.z,a1.w};
  float pv[8] = {p0.x,p0.y,p0.z,p0.w,p1.x,p1.y,p1.z,p1.w};
  #pragma unroll
  for(int j=0;j<8;j++){
    float g = gam[c+j], b = bet[c+j];
    float lnt = (av[j]-mean_a)*rstd_a*g + b;
    float sh;
    if(is_start)      sh = st[(size_t)sid*CC + c + j];
    else if(hp)       sh = (pv[j]-mean_q)*rstd_q*g + b;
    else              sh = 0.f;
    float xx = sh - lnt;
    xa[base+j]  = lnt;
    xxb[base+j] = xx;
    z[base+j]   = f2bf(lnt + xx*maa[c+j]);
  }
}

// ---------------- fused: xmid = p0+p1+x ; zw = LN(xmid) ----------------
__global__ __launch_bounds__(256) void ln2_fused_kernel(
    const float* __restrict__ p0, const float* __restrict__ p1,
    const float* __restrict__ xres, const float* __restrict__ gam,
    const float* __restrict__ bet, float* __restrict__ xsum,
    float* __restrict__ lnout, float eps)
{
  int t = blockIdx.x, tid = threadIdx.x;
  size_t base = (size_t)t*CC + tid*8;
  float vv[8];
  float s = 0.f, ss = 0.f;
  #pragma unroll
  for(int j=0;j<8;j++){
    float v = p0[base+j] + p1[base+j] + xres[base+j];
    vv[j] = v; s += v; ss += v*v;
    xsum[base+j] = v;
  }
  #pragma unroll
  for(int off=1; off<64; off<<=1){ s += __shfl_xor(s,off); ss += __shfl_xor(ss,off); }
  __shared__ float sm[8];
  int w = tid>>6;
  if((tid&63)==0){ sm[w]=s; sm[4+w]=ss; }
  __syncthreads();
  s = sm[0]+sm[1]+sm[2]+sm[3]; ss = sm[4]+sm[5]+sm[6]+sm[7];
  float mean = s * (1.f/CC);
  float var  = ss * (1.f/CC) - mean*mean;
  float rstd = rsqrtf(var + eps);
  int c = tid*8;
  #pragma unroll
  for(int j=0;j<8;j++) lnout[base+j] = (vv[j]-mean)*rstd*gam[c+j] + bet[c+j];
}

// ---------------- token shift (ffn): xk2/xr2 fused, bf16 out ----------------
__global__ __launch_bounds__(256) void shift2_kernel(
    const float* __restrict__ xf, const float* __restrict__ st,
    const int* __restrict__ sp, const float* __restrict__ cmk,
    const float* __restrict__ cmr, short* __restrict__ xk2, short* __restrict__ xr2)
{
  int t = blockIdx.x, tid = threadIdx.x;
  int sp0=sp[0], sp1=sp[1], sp2=sp[2], sp3=sp[3];
  bool is_start = (sp0==t)|(sp1==t)|(sp2==t)|(sp3==t);
  int sid = (sp0<=t)+(sp1<=t)+(sp2<=t)+(sp3<=t) - 1;
  sid = sid<0?0:(sid>3?3:sid);
  int c = tid*8;
  const float* src = is_start ? (st + (size_t)sid*CC + c)
                   : (t>0 ? xf + (size_t)(t-1)*CC + c : nullptr);
  const float* cur = xf + (size_t)t*CC + c;
  size_t ix = (size_t)t*CC + c;
  #pragma unroll
  for(int jj=0;jj<8;jj++){
    float xfv = cur[jj];
    float sh = src ? src[jj] : 0.f;
    float d = sh - xfv;
    xk2[ix+jj] = f2bf(xfv + d*cmk[c+jj]);
    xr2[ix+jj] = f2bf(xfv + d*cmr[c+jj]);
  }
}

// ---------------- fused 5-way maa mix -> bf16 outputs ----------------
// t0/c derived from blockIdx only => xxxb index is wave-uniform => SMEM loads.
__global__ __launch_bounds__(256) void mix5_kernel(
    const float* __restrict__ xxxb, const float* __restrict__ w2,
    const float* __restrict__ xa, const float* __restrict__ xxv,
    const float* __restrict__ mw, const float* __restrict__ mk,
    const float* __restrict__ mv, const float* __restrict__ mr,
    const float* __restrict__ mg,
    short* __restrict__ ow, short* __restrict__ ok, short* __restrict__ ov,
    short* __restrict__ orr, short* __restrict__ og)
{
  int t0 = (blockIdx.x >> 3) * 8;                  // uniform (no tid)
  int c  = ((blockIdx.x & 7) << 8) + threadIdx.x;  // 0..2047
  float acc[5][8];
  #pragma unroll
  for(int s=0;s<5;s++)
    #pragma unroll
    for(int tt=0;tt<8;tt++) acc[s][tt]=0.f;
  #pragma unroll
  for(int s=0;s<5;s++){
    for(int e=0;e<32;e++){
      float wv = w2[(size_t)(s*32+e)*CC + c];
      #pragma unroll
      for(int tt=0;tt<8;tt++)
        acc[s][tt] += xxxb[(size_t)(t0+tt)*160 + s*32 + e] * wv;
    }
  }
  float vmw=mw[c], vmk=mk[c], vmv=mv[c], vmr=mr[c], vmg=mg[c];
  #pragma unroll
  for(int tt=0;tt<8;tt++){
    size_t ix = (size_t)(t0+tt)*CC + c;
    float av = xa[ix], xv = xxv[ix];
    ow[ix]  = f2bf(av + xv*(vmw + acc[0][tt]));
    ok[ix]  = f2bf(av + xv*(vmk + acc[1][tt]));
    ov[ix]  = f2bf(av + xv*(vmv + acc[2][tt]));
    orr[ix] = f2bf(av + xv*(vmr + acc[3][tt]));
    og[ix]  = f2bf(av + xv*(vmg + acc[4][tt]));
  }
}

// ---------------- dec = exp(-exp(td + h1 @ td_w2)) (f32) ----------------
__global__ __launch_bounds__(256) void dec_kernel(
    const float* __restrict__ h1b, const float* __restrict__ tw2,
    const float* __restrict__ td, float* __restrict__ out)
{
  int t0 = (blockIdx.x >> 3) * 8;
  int c  = ((blockIdx.x & 7) << 8) + threadIdx.x;
  float acc[8] = {0,0,0,0,0,0,0,0};
  for(int e=0;e<64;e++){
    float wv = tw2[(size_t)e*CC + c];
    #pragma unroll
    for(int tt=0;tt<8;tt++) acc[tt] += h1b[(size_t)(t0+tt)*64 + e]*wv;
  }
  float tdc = td[c];
  #pragma unroll
  for(int tt=0;tt<8;tt++)
    out[(size_t)(t0+tt)*CC + c] = expf(-expf(tdc + acc[tt]));
}

// ---------------- tanh split-K reduce ----------------
template<int N, int NK>
__global__ __launch_bounds__(256) void tanh_reduce_kernel(
    const float* __restrict__ part, float* __restrict__ out)
{
  int idx = blockIdx.x*256 + threadIdx.x;
  int col = idx & (N-1);
  int row = idx >> (N==256 ? 8 : 7);
  float s = 0.f;
  #pragma unroll
  for(int z=0;z<8;z++) s += part[(size_t)z*TT*N + idx];
  if(col < NK) out[(size_t)row*NK + col] = tanhf(s);
}

// ---------------- W[K,N] f32 -> Wt[NPAD,K] bf16 ----------------
__global__ __launch_bounds__(256) void transpose_f2bf_kernel(
    const float* __restrict__ W, short* __restrict__ Wt, int K, int N)
{
  __shared__ float tile[64][65];
  int n0 = blockIdx.x*64, k0 = blockIdx.y*64;
  int tid = threadIdx.x;
  #pragma unroll
  for(int q=0;q<16;q++){
    int ix = q*256 + tid;
    int r = ix >> 6, cc2 = ix & 63;
    tile[r][cc2] = (n0 + cc2 < N) ? W[(size_t)(k0+r)*N + n0 + cc2] : 0.f;
  }
  __syncthreads();
  #pragma unroll
  for(int q=0;q<16;q++){
    int ix = q*256 + tid;
    int r = ix >> 6, cc2 = ix & 63;
    Wt[(size_t)(n0+r)*K + k0 + cc2] = f2bf(tile[cc2][r]);
  }
}

struct WPtr4 { const float* w[4]; };
__global__ __launch_bounds__(256) void transpose4_f2bf_kernel(
    WPtr4 ws4, short* __restrict__ Wt)
{
  __shared__ float tile[64][65];
  int z = blockIdx.z;
  const float* W = ws4.w[z];
  short* dst = Wt + (size_t)z*CC*CC;
  int n0 = blockIdx.x*64, k0 = blockIdx.y*64;
  int tid = threadIdx.x;
  #pragma unroll
  for(int q=0;q<16;q++){
    int ix = q*256 + tid;
    int r = ix >> 6, cc2 = ix & 63;
    tile[r][cc2] = W[(size_t)(k0+r)*CC + n0 + cc2];
  }
  __syncthreads();
  #pragma unroll
  for(int q=0;q<16;q++){
    int ix = q*256 + tid;
    int r = ix >> 6, cc2 = ix & 63;
    dst[(size_t)(n0+r)*CC + k0 + cc2] = f2bf(tile[cc2][r]);
  }
}

__device__ __forceinline__ void load_lds16(const void* g, void* l){
  __builtin_amdgcn_global_load_lds(
      (const __attribute__((address_space(1))) uint32_t*)g,
      (__attribute__((address_space(3))) uint32_t*)l, 16, 0, 0);
}

// ---------------- 128^2 MFMA GEMM (m97-structure + swizzle) ----------------
// EPI: 0 bf16; 3 relu^2 bf16; 5 f32 partial slab; 6 rkvg batch
template<int EPI>
__global__ __launch_bounds__(256) void gemm_bt_kernel(
    const short* __restrict__ A, const short* __restrict__ Bt,
    void* __restrict__ Cout, int M, int N, int Kstride, int Klen,
    long zA, long zB, long zC)
{
  __shared__ __align__(16) short As[128*64];
  __shared__ __align__(16) short Bs[128*64];
  int z = blockIdx.z;
  const short* A0 = A + (size_t)z*zA;
  const short* B0 = Bt + (size_t)z*zB;
  int tid = threadIdx.x;
  int w = tid >> 6, lane = tid & 63;
  int l16 = lane & 15, lhi = lane >> 4;
  int wr = w >> 1, wc = w & 1;
  int gx = gridDim.x;
  int nwg = gx*gridDim.y;
  int lin = blockIdx.y*gx + blockIdx.x;
  int wg = (lin & 7)*(nwg >> 3) + (lin >> 3);
  int bn = wg % gx, bm = wg / gx;
  const short* Ab = A0 + (size_t)bm*128*Kstride;
  const short* Bb = B0 + (size_t)bn*128*Kstride;
  int srow = w*8 + (lane>>3);
  int scol = lane & 7;
  f32x4 acc[4][4] = {};
  for(int kt=0; kt<Klen; kt+=64){
    __syncthreads();
    #pragma unroll
    for(int q=0;q<4;q++){
      int row = q*32 + srow;
      int c8 = scol ^ (row & 7);
      int ldsoff = (q*256 + w*64)*8;
      load_lds16(Ab + (size_t)row*Kstride + kt + c8*8, As + ldsoff);
      load_lds16(Bb + (size_t)row*Kstride + kt + c8*8, Bs + ldsoff);
    }
    __syncthreads();
    #pragma unroll
    for(int kk=0;kk<2;kk++){
      short8 af[4], bf[4];
      #pragma unroll
      for(int m=0;m<4;m++){
        int row = wr*64 + m*16 + l16;
        int slot = (kk*4 + lhi) ^ (row & 7);
        af[m] = *(const short8*)(As + row*64 + slot*8);
      }
      #pragma unroll
      for(int n=0;n<4;n++){
        int row = wc*64 + n*16 + l16;
        int slot = (kk*4 + lhi) ^ (row & 7);
        bf[n] = *(const short8*)(Bs + row*64 + slot*8);
      }
      #pragma unroll
      for(int m=0;m<4;m++){
        #pragma unroll
        for(int n=0;n<4;n++)
          acc[m][n] = __builtin_amdgcn_mfma_f32_16x16x32_bf16(af[m], bf[n], acc[m][n], 0, 0, 0);
      }
    }
  }
  int m0 = bm*128 + wr*64;
  int n0 = bn*128 + wc*64;
  #pragma unroll
  for(int m=0;m<4;m++){
    #pragma unroll
    for(int n=0;n<4;n++){
      #pragma unroll
      for(int jj=0;jj<4;jj++){
        int row = m0 + m*16 + lhi*4 + jj;
        int col = n0 + n*16 + l16;
        size_t ix = (size_t)row*N + col;
        float val = acc[m][n][jj];
        if constexpr (EPI==0){ ((short*)Cout)[(size_t)z*zC + ix] = f2bf(val); }
        else if constexpr (EPI==3){ float rv = fmaxf(val, 0.f); ((short*)Cout)[ix] = f2bf(rv*rv); }
        else if constexpr (EPI==5){ ((float*)Cout)[(size_t)z*zC + ix] = val; }
        else {
          short* o = (short*)Cout + (size_t)z*zC;
          o[ix] = (z==3) ? f2bf(val/(1.f+expf(-val))) : f2bf(val);
        }
      }
    }
  }
}

// ---------------- 256^2 MFMA GEMM, fine 8-phase counted-vmcnt schedule ------
template<int EPI>
__global__ __launch_bounds__(512, 1) void gemm256_kernel(
    const short* __restrict__ A, const short* __restrict__ Bt,
    void* __restrict__ Cout, int M, int N, int Kstride, int Klen,
    long zA, long zB, long zC)
{
  __shared__ __align__(16) short As[2][256*64];
  __shared__ __align__(16) short Bs[2][256*64];
  int z = blockIdx.z;
  const short* A0 = A + (size_t)z*zA;
  const short* B0 = Bt + (size_t)z*zB;
  int tid = threadIdx.x;
  int w = tid >> 6, lane = tid & 63;
  int l16 = lane & 15, lhi = lane >> 4;
  int wr = w >> 2, wc = w & 3;
  int gx = gridDim.x;
  int nwg = gx*gridDim.y;
  int lin = blockIdx.y*gx + blockIdx.x;
  int wg = (lin & 7)*(nwg >> 3) + (lin >> 3);
  int bn = wg % gx, bm = wg / gx;
  const short* Ab = A0 + (size_t)bm*256*Kstride;
  const short* Bb = B0 + (size_t)bn*256*Kstride;
  int srow_w = w*8 + (lane>>3);
  int scol = lane & 7;
  f32x4 acc[8][4] = {};

  auto STG = [&](const short* src, short* dst, int half, int kt){
    #pragma unroll
    for(int q=0;q<2;q++){
      int row = half*128 + q*64 + srow_w;
      int c8 = scol ^ (row & 7);
      load_lds16(src + (size_t)row*Kstride + kt + c8*8,
                 dst + (half*128 + q*64 + w*8)*64);
    }
  };
  auto DSA = [&](const short* Ac, int p, short8 afr[2][2]){
    #pragma unroll
    for(int mm=0;mm<2;mm++)
      #pragma unroll
      for(int kk=0;kk<2;kk++){
        int row = wr*128 + (p*2+mm)*16 + l16;
        int slot = (kk*4 + lhi) ^ (row & 7);
        afr[mm][kk] = *(const short8*)(Ac + row*64 + slot*8);
      }
  };
  auto DSB = [&](const short* Bc, short8 bfr[4][2]){
    #pragma unroll
    for(int n=0;n<4;n++)
      #pragma unroll
      for(int kk=0;kk<2;kk++){
        int row = wc*64 + n*16 + l16;
        int slot = (kk*4 + lhi) ^ (row & 7);
        bfr[n][kk] = *(const short8*)(Bc + row*64 + slot*8);
      }
  };
  auto MM = [&](int p, short8 afr[2][2], short8 bfr[4][2]){
    __builtin_amdgcn_s_setprio(1);
    #pragma unroll
    for(int mm=0;mm<2;mm++)
      #pragma unroll
      for(int n=0;n<4;n++)
        #pragma unroll
        for(int kk=0;kk<2;kk++)
          acc[p*2+mm][n] = __builtin_amdgcn_mfma_f32_16x16x32_bf16(
              afr[mm][kk], bfr[n][kk], acc[p*2+mm][n], 0, 0, 0);
    __builtin_amdgcn_s_setprio(0);
  };
  #define PH_SYNC() do{ __builtin_amdgcn_s_barrier(); \
      asm volatile("s_waitcnt lgkmcnt(0)" ::: "memory"); \
      __builtin_amdgcn_sched_barrier(0); }while(0)
  #define PH_END() do{ __builtin_amdgcn_s_barrier(); \
      __builtin_amdgcn_sched_barrier(0); }while(0)

  int NT = Klen >> 6;
  int niter = NT >> 1;
  STG(Ab, &As[0][0], 0, 0); STG(Ab, &As[0][0], 1, 0);
  STG(Bb, &Bs[0][0], 0, 0); STG(Bb, &Bs[0][0], 1, 0);
  STG(Bb, &Bs[1][0], 0, 64); STG(Bb, &Bs[1][0], 1, 64);
  asm volatile("s_waitcnt vmcnt(4)" ::: "memory");
  __builtin_amdgcn_s_barrier();
  __builtin_amdgcn_sched_barrier(0);

  for(int i=0;i<niter;++i){
    int kt_o  = (2*i+1) << 6;
    int kt_e2 = (2*i+2) << 6;
    int kt_o2 = (2*i+3) << 6;
    bool st = (i+1 < niter);
    short8 bfr[4][2], afr[2][2];
    DSB(&Bs[0][0], bfr);
    DSA(&As[0][0], 0, afr);
    STG(Ab, &As[1][0], 0, kt_o);
    PH_SYNC(); MM(0, afr, bfr); PH_END();
    DSA(&As[0][0], 1, afr);
    STG(Ab, &As[1][0], 1, kt_o);
    PH_SYNC(); MM(1, afr, bfr); PH_END();
    DSA(&As[0][0], 2, afr);
    if(st) STG(Bb, &Bs[0][0], 0, kt_e2);
    PH_SYNC(); MM(2, afr, bfr); PH_END();
    DSA(&As[0][0], 3, afr);
    if(st){ STG(Bb, &Bs[0][0], 1, kt_e2);
            asm volatile("s_waitcnt vmcnt(4)" ::: "memory"); }
    else  { asm volatile("s_waitcnt vmcnt(0)" ::: "memory"); }
    PH_SYNC(); MM(3, afr, bfr); PH_END();
    DSB(&Bs[1][0], bfr);
    DSA(&As[1][0], 0, afr);
    if(st) STG(Ab, &As[0][0], 0, kt_e2);
    PH_SYNC(); MM(0, afr, bfr); PH_END();
    DSA(&As[1][0], 1, afr);
    if(st) STG(Ab, &As[0][0], 1, kt_e2);
    PH_SYNC(); MM(1, afr, bfr); PH_END();
    DSA(&As[1][0], 2, afr);
    if(st) STG(Bb, &Bs[1][0], 0, kt_o2);
    PH_SYNC(); MM(2, afr, bfr); PH_END();
    DSA(&As[1][0], 3, afr);
    if(st){ STG(Bb, &Bs[1][0], 1, kt_o2);
            asm volatile("s_waitcnt vmcnt(4)" ::: "memory"); }
    else  { asm volatile("s_waitcnt vmcnt(0)" ::: "memory"); }
    PH_SYNC(); MM(3, afr, bfr); PH_END();
  }
  #undef PH_SYNC
  #undef PH_END

  int m0 = bm*256 + wr*128;
  int n0 = bn*256 + wc*64;
  #pragma unroll
  for(int m=0;m<8;m++){
    #pragma unroll
    for(int n=0;n<4;n++){
      #pragma unroll
      for(int jj=0;jj<4;jj++){
        int row = m0 + m*16 + lhi*4 + jj;
        int col = n0 + n*16 + l16;
        size_t ix = (size_t)row*N + col;
        float val = acc[m][n][jj];
        if constexpr (EPI==3){ float rv = fmaxf(val, 0.f); ((short*)Cout)[ix] = f2bf(rv*rv); }
        else if constexpr (EPI==5){ ((float*)Cout)[(size_t)z*zC + ix] = val; }
        else {
          short* o = (short*)Cout + (size_t)z*zC;
          o[ix] = (z==3) ? f2bf(val/(1.f+expf(-val))) : f2bf(val);
        }
      }
    }
  }
}

// ---------------- WKV pass A ----------------
__global__ __launch_bounds__(256) void wkv_chunk_kernel(
    const short* __restrict__ rb, const short* __restrict__ kb,
    const short* __restrict__ vb, const float* __restrict__ db,
    const float* __restrict__ wkv_state, const float* __restrict__ u,
    const int* __restrict__ sp,
    float* __restrict__ yb, short* __restrict__ rtb,
    float* __restrict__ Bc, float* __restrict__ Pc)
{
  int blk = blockIdx.x;
  int ch = blk >> 5;
  int h  = blk & 31;
  int tid = threadIdx.x;
  int a = tid & 3, j = tid >> 2;
  int w = tid >> 6, lane = tid & 63;
  __shared__ float sr[2][64], sk[2][64], suk[2][64], sv[2][64], sd[2][64];
  __shared__ float sp_[64];
  float u_reg = (w==1) ? u[h*64 + lane] : 0.f;
  if(tid < 64) sp_[tid] = 1.f;
  float S[16];
  #pragma unroll
  for(int ii=0;ii<16;ii++) S[ii]=0.f;
  int sp0=sp[0], sp1=sp[1], sp2=sp[2], sp3=sp[3];
  int tbase = ch*CHUNK;
  {
    size_t gb = (size_t)tbase*CC + h*64;
    if(w==0)      sr[0][lane] = bf2f(rb[gb+lane]);
    else if(w==1){ float kv_=bf2f(kb[gb+lane]); sk[0][lane]=kv_; suk[0][lane]=u_reg*kv_; }
    else if(w==2) sv[0][lane] = bf2f(vb[gb+lane]);
    else          sd[0][lane] = db[gb+lane];
  }
  __syncthreads();
  for(int tl=0; tl<CHUNK; ++tl){
    int t = tbase + tl;
    int buf = tl & 1;
    if(tl+1 < CHUNK){
      size_t nb = (size_t)(t+1)*CC + h*64;
      int b2_ = buf^1;
      if(w==0)      sr[b2_][lane] = bf2f(rb[nb+lane]);
      else if(w==1){ float kv_=bf2f(kb[nb+lane]); sk[b2_][lane]=kv_; suk[b2_][lane]=u_reg*kv_; }
      else if(w==2) sv[b2_][lane] = bf2f(vb[nb+lane]);
      else          sd[b2_][lane] = db[nb+lane];
    }
    size_t base = (size_t)t*CC + h*64;
    bool is_start = (sp0==t)|(sp1==t)|(sp2==t)|(sp3==t);
    if(is_start){
      int sid = (sp0<=t)+(sp1<=t)+(sp2<=t)+(sp3<=t) - 1;
      sid = sid<0?0:(sid>3?3:sid);
      const float* wsrc = wkv_state + (((size_t)sid*NH + h)*HSZ + a*16)*HSZ + j;
      #pragma unroll
      for(int ii=0;ii<16;ii++) S[ii] = wsrc[(size_t)ii*HSZ];
      if(tid < 64) sp_[tid] = 0.f;
    }
    float vj = sv[buf][j];
    float yp = 0.f, bp = 0.f;
    #pragma unroll
    for(int ii=0;ii<16;ii++){
      int i = a*16 + ii;
      float ri = sr[buf][i];
      yp += ri * S[ii];
      bp += ri * suk[buf][i];
    }
    yp += __shfl_xor(yp, 1); yp += __shfl_xor(yp, 2);
    bp += __shfl_xor(bp, 1); bp += __shfl_xor(bp, 2);
    if(a == 0) yb[base + j] = yp + bp*vj;
    if(tid < 64){
      rtb[base + tid] = f2bf(sr[buf][tid] * sp_[tid]);
      sp_[tid] *= sd[buf][tid];
    }
    #pragma unroll
    for(int ii=0;ii<16;ii++){
      int i = a*16 + ii;
      S[ii] = sd[buf][i]*S[ii] + sk[buf][i]*vj;
    }
    __syncthreads();
  }
  size_t cb = ((size_t)ch*NH + h)*HSZ*HSZ;
  #pragma unroll
  for(int ii=0;ii<16;ii++) Bc[cb + (size_t)(a*16+ii)*HSZ + j] = S[ii];
  if(tid < 64) Pc[((size_t)ch*NH + h)*HSZ + tid] = sp_[tid];
}

// ---------------- WKV pass B ----------------
__global__ __launch_bounds__(256) void wkv_combine_kernel(
    float* __restrict__ BS, const float* __restrict__ Pc)
{
  int idx = blockIdx.x*256 + threadIdx.x;
  int hi = idx >> 6;
  float s = 0.f;
  for(int cc=0; cc<NCHUNK; ++cc){
    size_t ix = (size_t)cc*(NH*HSZ*HSZ) + idx;
    float b = BS[ix];
    BS[ix] = s;
    s = Pc[cc*(NH*HSZ) + hi]*s + b;
  }
}

// ---------------- WKV pass C + fused GroupNorm*g -> bf16 ----------------
// Each (chunk,head) block covers complete GN groups (64-wide head slices):
// finish y = yb + r~@Sin, then 8-lane group stats, normalize, * g, store bf16.
__global__ __launch_bounds__(256) void wkv_corr_gn_kernel(
    const short* __restrict__ rtb, const float* __restrict__ Sin,
    const float* __restrict__ yb, const short* __restrict__ gb,
    const float* __restrict__ gam, const float* __restrict__ bet,
    short* __restrict__ yg)
{
  int blk = blockIdx.x;
  int ch = blk >> 5, h = blk & 31;
  __shared__ float Ssm[64][64];
  __shared__ float Rsm[32][65];
  int tid = threadIdx.x;
  const float* Sp = Sin + (size_t)(ch*NH + h)*HSZ*HSZ;
  #pragma unroll
  for(int q=0;q<16;q++) ((float*)Ssm)[q*256+tid] = Sp[q*256+tid];
  #pragma unroll
  for(int q=0;q<8;q++){
    int ix = q*256 + tid;
    int tl = ix>>6, i = ix&63;
    Rsm[tl][i] = bf2f(rtb[(size_t)(ch*CHUNK+tl)*CC + h*64 + i]);
  }
  __syncthreads();
  int tl = tid >> 3;   // row 0..31 (8 lanes per row)
  int jq = tid & 7;
  float acc[8];
  #pragma unroll
  for(int jj=0;jj<8;jj++) acc[jj]=0.f;
  for(int i=0;i<64;i++){
    float rv = Rsm[tl][i];
    #pragma unroll
    for(int jj=0;jj<8;jj++) acc[jj] += rv * Ssm[i][jq*8+jj];
  }
  int t = ch*CHUNK + tl;
  float val[8];
  float s = 0.f, ss = 0.f;
  #pragma unroll
  for(int jj=0;jj<8;jj++){
    float v = yb[(size_t)t*CC + h*64 + jq*8+jj] + acc[jj];
    val[jj] = v; s += v; ss += v*v;
  }
  // row-wide (64-col) stats across the 8 lanes of this row
  #pragma unroll
  for(int off=1; off<8; off<<=1){ s += __shfl_xor(s,off); ss += __shfl_xor(ss,off); }
  float mu = s*(1.f/64.f);
  float var = ss*(1.f/64.f) - mu*mu;
  float rstd = rsqrtf(var + 6.4e-4f);   // eps = 1e-5 * 8^2
  #pragma unroll
  for(int jj=0;jj<8;jj++){
    int cc = h*64 + jq*8+jj;
    float o = (val[jj]-mu)*rstd*gam[cc] + bet[cc];
    yg[(size_t)t*CC + cc] = f2bf(o * bf2f(gb[(size_t)t*CC + cc]));
  }
}

// ---------------- final: out += sigmoid(s0+s1)*(kv0+kv1+kv2+kv3) ----------------
__global__ __launch_bounds__(256) void final_kernel(
    const float* __restrict__ s0, const float* __restrict__ s1,
    const float* __restrict__ kv0, const float* __restrict__ kv1,
    const float* __restrict__ kv2, const float* __restrict__ kv3,
    float* __restrict__ out)
{
  size_t i = ((size_t)blockIdx.x*256 + threadIdx.x)*8;
  #pragma unroll
  for(int j=0;j<8;j++){
    float sv = s0[i+j] + s1[i+j];
    float sig = 1.f/(1.f + expf(-sv));
    out[i+j] = out[i+j] + sig*(kv0[i+j] + kv1[i+j] + kv2[i+j] + kv3[i+j]);
  }
}

extern "C" void kernel_launch(void* const* d_in, const int* in_sizes, int n_in,
                              void* d_out, int out_size, void* d_ws, size_t ws_size,
                              hipStream_t stream)
{
  (void)in_sizes; (void)n_in; (void)out_size;
  const float* x         = (const float*)d_in[0];
  const int*   sp        = (const int*)d_in[1];
  const float* att_state = (const float*)d_in[2];
  const float* wkv_state = (const float*)d_in[3];
  const float* ffn_state = (const float*)d_in[4];
  const float* ln1_g=(const float*)d_in[5],  *ln1_b=(const float*)d_in[6];
  const float* ln2_g=(const float*)d_in[7],  *ln2_b=(const float*)d_in[8];
  const float* maa_x=(const float*)d_in[9],  *maa_w=(const float*)d_in[10], *maa_k=(const float*)d_in[11];
  const float* maa_v=(const float*)d_in[12], *maa_r=(const float*)d_in[13], *maa_g=(const float*)d_in[14];
  const float* tm_w1=(const float*)d_in[15], *tm_w2=(const float*)d_in[16];
  const float* td=(const float*)d_in[17],    *td_w1=(const float*)d_in[18], *td_w2=(const float*)d_in[19];
  const float* u = (const float*)d_in[20];
  const float* Wr=(const float*)d_in[21], *Wk=(const float*)d_in[22], *Wv=(const float*)d_in[23];
  const float* Wg=(const float*)d_in[24], *Wo=(const float*)d_in[25];
  const float* lnx_g=(const float*)d_in[26], *lnx_b=(const float*)d_in[27];
  const float* cm_k=(const float*)d_in[28],  *cm_r=(const float*)d_in[29];
  const float* Wck=(const float*)d_in[30], *Wcv=(const float*)d_in[31], *Wcr=(const float*)d_in[32];

  char* ws = (char*)d_ws;
  const size_t SLOT  = (size_t)TT*CC*4;
  const size_t BSLOT = (size_t)TT*CC*2;
  const size_t WT_SZ = (size_t)4*CC*CC*2;
  const size_t NEED  = 6*SLOT + 10*BSLOT + WT_SZ + (4u<<20);
  if(ws_size < NEED) return;

  float* xa   = (float*)(ws + 0*SLOT);
  float* xxb  = (float*)(ws + 1*SLOT);
  float* zw   = (float*)(ws + 2*SLOT);
  float* decb = (float*)(ws + 3*SLOT);
  float* yb   = (float*)(ws + 4*SLOT);
  float* S5   = (float*)(ws + 5*SLOT);
  float* BS   = xa;
  float* xxxPart = zw;
  float* h1Part  = yb;
  short* bA   = (short*)(ws + 6*SLOT);
  short* bO   = (short*)(ws + 6*SLOT + 4*BSLOT);
  short* b1 = bO + 0*(TT*CC);
  short* b2 = bO + 1*(TT*CC);
  short* b3 = bO + 2*(TT*CC);
  short* b4 = bO + 3*(TT*CC);
  short* b5 = bO + 4*(TT*CC);
  short* b6 = bO + 5*(TT*CC);
  short* WT = (short*)(ws + 6*SLOT + 10*BSLOT);
  char*  aux = (char*)WT + WT_SZ;
  float* xxxb = (float*)(aux);
  float* h1b  = (float*)(aux + (2u<<20));
  float* Pc   = (float*)(aux + (5u<<19));
  float* xmid = (float*)d_out;

  dim3 B256(256), B512(512);
  const int NTC8 = TT*CC/8/256;

  // ---- Tmix front (fused LN1 + shift + z-prep) ----
  front_kernel<<<TT, B256, 0, stream>>>(x, att_state, sp, ln1_g, ln1_b, maa_x,
                                        xa, xxb, bA);
  transpose_f2bf_kernel<<<dim3(4, CC/64), B256, 0, stream>>>(tm_w1, WT, CC, 160);
  gemm_bt_kernel<5><<<dim3(2, TT/128, 8), B256, 0, stream>>>(bA, WT, xxxPart, TT, 256, CC, 256,
      256, 256, (long)TT*256);
  tanh_reduce_kernel<256,160><<<TT, B256, 0, stream>>>(xxxPart, xxxb);
  mix5_kernel<<<NTC8, B256, 0, stream>>>(xxxb, tm_w2, xa, xxb,
      maa_w, maa_k, maa_v, maa_r, maa_g,
      b5, bA + 1*(TT*CC), bA + 2*(TT*CC), bA, bA + 3*(TT*CC));
  transpose_f2bf_kernel<<<dim3(2, CC/64), B256, 0, stream>>>(td_w1, WT, CC, 64);
  gemm_bt_kernel<5><<<dim3(1, TT/128, 8), B256, 0, stream>>>(b5, WT, h1Part, TT, 128, CC, 256,
      256, 256, (long)TT*128);
  tanh_reduce_kernel<128,64><<<TT/2, B256, 0, stream>>>(h1Part, h1b);
  dec_kernel<<<NTC8, B256, 0, stream>>>(h1b, td_w2, td, decb);

  // ---- r,k,v,g projections: batched 256^2 8-phase GEMM (256 blocks) ----
  WPtr4 w4; w4.w[0]=Wr; w4.w[1]=Wk; w4.w[2]=Wv; w4.w[3]=Wg;
  transpose4_f2bf_kernel<<<dim3(CC/64, CC/64, 4), B256, 0, stream>>>(w4, WT);
  gemm256_kernel<6><<<dim3(CC/256, TT/256, 4), B512, 0, stream>>>(bA, WT, b1, TT, CC, CC, CC,
      (long)TT*CC, (long)CC*CC, (long)TT*CC);

  // ---- WKV chunked scan (corr+GN fused) ----
  wkv_chunk_kernel<<<NCHUNK*NH, B256, 0, stream>>>(b1, b2, b3, decb, wkv_state, u, sp,
                                                   yb, b5, BS, Pc);
  wkv_combine_kernel<<<NH*HSZ*HSZ/256, B256, 0, stream>>>(BS, Pc);
  wkv_corr_gn_kernel<<<NCHUNK*NH, B256, 0, stream>>>(b5, BS, yb, b4, lnx_g, lnx_b, b6);

  // ---- output projection (128^2 split-K=2) + fused residual+LN2 ----
  transpose_f2bf_kernel<<<dim3(CC/64, CC/64), B256, 0, stream>>>(Wo, WT, CC, CC);
  gemm_bt_kernel<5><<<dim3(CC/128, TT/128, 2), B256, 0, stream>>>(b6, WT, yb, TT, CC, CC, 1024,
      1024, 1024, (long)TT*CC);
  ln2_fused_kernel<<<TT, B256, 0, stream>>>(yb, S5, x, ln2_g, ln2_b, xmid, zw, 1e-5f);

  // ---- CMix ----
  shift2_kernel<<<TT, B256, 0, stream>>>(zw, ffn_state, sp, cm_k, cm_r, bA, bA + 1*(TT*CC));
  transpose_f2bf_kernel<<<dim3(FFND/64, CC/64), B256, 0, stream>>>(Wck, WT, CC, FFND);
  gemm256_kernel<3><<<dim3(FFND/256, TT/256, 1), B512, 0, stream>>>(bA, WT, b1, TT, FFND, CC, CC,
      0, 0, 0);
  transpose_f2bf_kernel<<<dim3(CC/64, FFND/64), B256, 0, stream>>>(Wcv, WT, FFND, CC);
  gemm256_kernel<5><<<dim3(CC/256, TT/256, 4), B512, 0, stream>>>(b1, WT, zw, TT, CC, FFND, 1792,
      1792, 1792, (long)TT*CC);
  transpose_f2bf_kernel<<<dim3(CC/64, CC/64), B256, 0, stream>>>(Wcr, WT, CC, CC);
  gemm_bt_kernel<5><<<dim3(CC/128, TT/128, 2), B256, 0, stream>>>(bA + 1*(TT*CC), WT, xa, TT, CC, CC, 1024,
      1024, 1024, (long)TT*CC);
  final_kernel<<<NTC8, B256, 0, stream>>>(xa, xxb, zw, decb, yb, S5, xmid);
}

// Round 13
// 689.900 us; speedup vs baseline: 1.2492x; 1.0132x over previous
//
#include <hip/hip_runtime.h>
#include <stdint.h>

// RWKV6 block: B=1, T=2048, C=2048, H=32, HS=64, FFN=7168, NS=4
// Workspace: 6*16M (f32) + 4*8M (bA) + 6*8M (bO) + 32M (WT) + 4M aux = 212 MiB.

#define TT 2048
#define CC 2048
#define NH 32
#define HSZ 64
#define FFND 7168
#define CHUNK 32
#define NCHUNK 64

typedef __attribute__((ext_vector_type(8))) short short8;
typedef __attribute__((ext_vector_type(4))) float f32x4;

__device__ __forceinline__ float bf2f(short s){
  return __uint_as_float(((uint32_t)(uint16_t)s) << 16);
}
__device__ __forceinline__ short f2bf(float f){
  uint32_t u = __float_as_uint(f);
  u = u + 0x7fffu + ((u >> 16) & 1u);
  return (short)(u >> 16);
}

// ---------------- fused front: LN1(t) + LN1(t-1) + shift + z-prep ----------------
__global__ __launch_bounds__(256) void front_kernel(
    const float* __restrict__ x, const float* __restrict__ st,
    const int* __restrict__ sp, const float* __restrict__ gam,
    const float* __restrict__ bet, const float* __restrict__ maa,
    float* __restrict__ xa, float* __restrict__ xxb, short* __restrict__ z)
{
  int t = blockIdx.x, tid = threadIdx.x;
  const float* row = x + (size_t)t*CC;
  float4 a0 = *(const float4*)(row + tid*8);
  float4 a1 = *(const float4*)(row + tid*8 + 4);
  bool hp = (t > 0);
  float4 p0 = make_float4(0.f,0.f,0.f,0.f), p1 = p0;
  if(hp){
    const float* prow = x + (size_t)(t-1)*CC;
    p0 = *(const float4*)(prow + tid*8);
    p1 = *(const float4*)(prow + tid*8 + 4);
  }
  float sa  = a0.x+a0.y+a0.z+a0.w + a1.x+a1.y+a1.z+a1.w;
  float ssa = a0.x*a0.x+a0.y*a0.y+a0.z*a0.z+a0.w*a0.w
            + a1.x*a1.x+a1.y*a1.y+a1.z*a1.z+a1.w*a1.w;
  float sq  = p0.x+p0.y+p0.z+p0.w + p1.x+p1.y+p1.z+p1.w;
  float ssq = p0.x*p0.x+p0.y*p0.y+p0.z*p0.z+p0.w*p0.w
            + p1.x*p1.x+p1.y*p1.y+p1.z*p1.z+p1.w*p1.w;
  #pragma unroll
  for(int off=1; off<64; off<<=1){
    sa += __shfl_xor(sa,off); ssa += __shfl_xor(ssa,off);
    sq += __shfl_xor(sq,off); ssq += __shfl_xor(ssq,off);
  }
  __shared__ float sm[16];
  int w = tid>>6;
  if((tid&63)==0){ sm[w]=sa; sm[4+w]=ssa; sm[8+w]=sq; sm[12+w]=ssq; }
  __syncthreads();
  sa = sm[0]+sm[1]+sm[2]+sm[3];    ssa = sm[4]+sm[5]+sm[6]+sm[7];
  sq = sm[8]+sm[9]+sm[10]+sm[11];  ssq = sm[12]+sm[13]+sm[14]+sm[15];
  float mean_a = sa*(1.f/CC);
  float rstd_a = rsqrtf(ssa*(1.f/CC) - mean_a*mean_a + 1e-5f);
  float mean_q = sq*(1.f/CC);
  float rstd_q = rsqrtf(ssq*(1.f/CC) - mean_q*mean_q + 1e-5f);
  int sp0=sp[0], sp1=sp[1], sp2=sp[2], sp3=sp[3];
  bool is_start = (sp0==t)|(sp1==t)|(sp2==t)|(sp3==t);
  int sid = (sp0<=t)+(sp1<=t)+(sp2<=t)+(sp3<=t) - 1;
  sid = sid<0?0:(sid>3?3:sid);
  int c = tid*8;
  size_t base = (size_t)t*CC + c;
  float av[8] = {a0.x,a0.y,a0.z,a0.w,a1.x,a1.y,a1.z,a1.w};
  float pv[8] = {p0.x,p0.y,p0.z,p0.w,p1.x,p1.y,p1.z,p1.w};
  #pragma unroll
  for(int j=0;j<8;j++){
    float g = gam[c+j], b = bet[c+j];
    float lnt = (av[j]-mean_a)*rstd_a*g + b;
    float sh;
    if(is_start)      sh = st[(size_t)sid*CC + c + j];
    else if(hp)       sh = (pv[j]-mean_q)*rstd_q*g + b;
    else              sh = 0.f;
    float xx = sh - lnt;
    xa[base+j]  = lnt;
    xxb[base+j] = xx;
    z[base+j]   = f2bf(lnt + xx*maa[c+j]);
  }
}

// ---------------- fused: xmid = p0+p1+x ; zw = LN(xmid) ----------------
__global__ __launch_bounds__(256) void ln2_fused_kernel(
    const float* __restrict__ p0, const float* __restrict__ p1,
    const float* __restrict__ xres, const float* __restrict__ gam,
    const float* __restrict__ bet, float* __restrict__ xsum,
    float* __restrict__ lnout, float eps)
{
  int t = blockIdx.x, tid = threadIdx.x;
  size_t base = (size_t)t*CC + tid*8;
  float vv[8];
  float s = 0.f, ss = 0.f;
  #pragma unroll
  for(int j=0;j<8;j++){
    float v = p0[base+j] + p1[base+j] + xres[base+j];
    vv[j] = v; s += v; ss += v*v;
    xsum[base+j] = v;
  }
  #pragma unroll
  for(int off=1; off<64; off<<=1){ s += __shfl_xor(s,off); ss += __shfl_xor(ss,off); }
  __shared__ float sm[8];
  int w = tid>>6;
  if((tid&63)==0){ sm[w]=s; sm[4+w]=ss; }
  __syncthreads();
  s = sm[0]+sm[1]+sm[2]+sm[3]; ss = sm[4]+sm[5]+sm[6]+sm[7];
  float mean = s * (1.f/CC);
  float var  = ss * (1.f/CC) - mean*mean;
  float rstd = rsqrtf(var + eps);
  int c = tid*8;
  #pragma unroll
  for(int j=0;j<8;j++) lnout[base+j] = (vv[j]-mean)*rstd*gam[c+j] + bet[c+j];
}

// ---------------- token shift (ffn): xk2/xr2 fused, bf16 out ----------------
__global__ __launch_bounds__(256) void shift2_kernel(
    const float* __restrict__ xf, const float* __restrict__ st,
    const int* __restrict__ sp, const float* __restrict__ cmk,
    const float* __restrict__ cmr, short* __restrict__ xk2, short* __restrict__ xr2)
{
  int t = blockIdx.x, tid = threadIdx.x;
  int sp0=sp[0], sp1=sp[1], sp2=sp[2], sp3=sp[3];
  bool is_start = (sp0==t)|(sp1==t)|(sp2==t)|(sp3==t);
  int sid = (sp0<=t)+(sp1<=t)+(sp2<=t)+(sp3<=t) - 1;
  sid = sid<0?0:(sid>3?3:sid);
  int c = tid*8;
  const float* src = is_start ? (st + (size_t)sid*CC + c)
                   : (t>0 ? xf + (size_t)(t-1)*CC + c : nullptr);
  const float* cur = xf + (size_t)t*CC + c;
  size_t ix = (size_t)t*CC + c;
  #pragma unroll
  for(int jj=0;jj<8;jj++){
    float xfv = cur[jj];
    float sh = src ? src[jj] : 0.f;
    float d = sh - xfv;
    xk2[ix+jj] = f2bf(xfv + d*cmk[c+jj]);
    xr2[ix+jj] = f2bf(xfv + d*cmr[c+jj]);
  }
}

// ---------------- fused 5-way maa mix -> bf16 outputs ----------------
__global__ __launch_bounds__(256) void mix5_kernel(
    const float* __restrict__ xxxb, const float* __restrict__ w2,
    const float* __restrict__ xa, const float* __restrict__ xxv,
    const float* __restrict__ mw, const float* __restrict__ mk,
    const float* __restrict__ mv, const float* __restrict__ mr,
    const float* __restrict__ mg,
    short* __restrict__ ow, short* __restrict__ ok, short* __restrict__ ov,
    short* __restrict__ orr, short* __restrict__ og)
{
  int t0 = (blockIdx.x >> 3) * 8;                  // uniform (no tid)
  int c  = ((blockIdx.x & 7) << 8) + threadIdx.x;  // 0..2047
  float acc[5][8];
  #pragma unroll
  for(int s=0;s<5;s++)
    #pragma unroll
    for(int tt=0;tt<8;tt++) acc[s][tt]=0.f;
  #pragma unroll
  for(int s=0;s<5;s++){
    for(int e=0;e<32;e++){
      float wv = w2[(size_t)(s*32+e)*CC + c];
      #pragma unroll
      for(int tt=0;tt<8;tt++)
        acc[s][tt] += xxxb[(size_t)(t0+tt)*160 + s*32 + e] * wv;
    }
  }
  float vmw=mw[c], vmk=mk[c], vmv=mv[c], vmr=mr[c], vmg=mg[c];
  #pragma unroll
  for(int tt=0;tt<8;tt++){
    size_t ix = (size_t)(t0+tt)*CC + c;
    float av = xa[ix], xv = xxv[ix];
    ow[ix]  = f2bf(av + xv*(vmw + acc[0][tt]));
    ok[ix]  = f2bf(av + xv*(vmk + acc[1][tt]));
    ov[ix]  = f2bf(av + xv*(vmv + acc[2][tt]));
    orr[ix] = f2bf(av + xv*(vmr + acc[3][tt]));
    og[ix]  = f2bf(av + xv*(vmg + acc[4][tt]));
  }
}

// ---------------- dec = exp(-exp(td + h1 @ td_w2)) (f32) ----------------
__global__ __launch_bounds__(256) void dec_kernel(
    const float* __restrict__ h1b, const float* __restrict__ tw2,
    const float* __restrict__ td, float* __restrict__ out)
{
  int t0 = (blockIdx.x >> 3) * 8;
  int c  = ((blockIdx.x & 7) << 8) + threadIdx.x;
  float acc[8] = {0,0,0,0,0,0,0,0};
  for(int e=0;e<64;e++){
    float wv = tw2[(size_t)e*CC + c];
    #pragma unroll
    for(int tt=0;tt<8;tt++) acc[tt] += h1b[(size_t)(t0+tt)*64 + e]*wv;
  }
  float tdc = td[c];
  #pragma unroll
  for(int tt=0;tt<8;tt++)
    out[(size_t)(t0+tt)*CC + c] = expf(-expf(tdc + acc[tt]));
}

// ---------------- tanh split-K reduce ----------------
template<int N, int NK>
__global__ __launch_bounds__(256) void tanh_reduce_kernel(
    const float* __restrict__ part, float* __restrict__ out)
{
  int idx = blockIdx.x*256 + threadIdx.x;
  int col = idx & (N-1);
  int row = idx >> (N==256 ? 8 : 7);
  float s = 0.f;
  #pragma unroll
  for(int z=0;z<8;z++) s += part[(size_t)z*TT*N + idx];
  if(col < NK) out[(size_t)row*NK + col] = tanhf(s);
}

// ---------------- W[K,N] f32 -> Wt[NPAD,K] bf16 ----------------
__global__ __launch_bounds__(256) void transpose_f2bf_kernel(
    const float* __restrict__ W, short* __restrict__ Wt, int K, int N)
{
  __shared__ float tile[64][65];
  int n0 = blockIdx.x*64, k0 = blockIdx.y*64;
  int tid = threadIdx.x;
  #pragma unroll
  for(int q=0;q<16;q++){
    int ix = q*256 + tid;
    int r = ix >> 6, cc2 = ix & 63;
    tile[r][cc2] = (n0 + cc2 < N) ? W[(size_t)(k0+r)*N + n0 + cc2] : 0.f;
  }
  __syncthreads();
  #pragma unroll
  for(int q=0;q<16;q++){
    int ix = q*256 + tid;
    int r = ix >> 6, cc2 = ix & 63;
    Wt[(size_t)(n0+r)*K + k0 + cc2] = f2bf(tile[cc2][r]);
  }
}

struct WPtr4 { const float* w[4]; };
__global__ __launch_bounds__(256) void transpose4_f2bf_kernel(
    WPtr4 ws4, short* __restrict__ Wt)
{
  __shared__ float tile[64][65];
  int z = blockIdx.z;
  const float* W = ws4.w[z];
  short* dst = Wt + (size_t)z*CC*CC;
  int n0 = blockIdx.x*64, k0 = blockIdx.y*64;
  int tid = threadIdx.x;
  #pragma unroll
  for(int q=0;q<16;q++){
    int ix = q*256 + tid;
    int r = ix >> 6, cc2 = ix & 63;
    tile[r][cc2] = W[(size_t)(k0+r)*CC + n0 + cc2];
  }
  __syncthreads();
  #pragma unroll
  for(int q=0;q<16;q++){
    int ix = q*256 + tid;
    int r = ix >> 6, cc2 = ix & 63;
    dst[(size_t)(n0+r)*CC + k0 + cc2] = f2bf(tile[cc2][r]);
  }
}

__device__ __forceinline__ void load_lds16(const void* g, void* l){
  __builtin_amdgcn_global_load_lds(
      (const __attribute__((address_space(1))) uint32_t*)g,
      (__attribute__((address_space(3))) uint32_t*)l, 16, 0, 0);
}

// ---------------- 128^2 MFMA GEMM (m97-structure + swizzle) ----------------
// EPI: 0 bf16; 3 relu^2 bf16; 5 f32 partial slab; 6 rkvg batch
template<int EPI>
__global__ __launch_bounds__(256) void gemm_bt_kernel(
    const short* __restrict__ A, const short* __restrict__ Bt,
    void* __restrict__ Cout, int M, int N, int Kstride, int Klen,
    long zA, long zB, long zC)
{
  __shared__ __align__(16) short As[128*64];
  __shared__ __align__(16) short Bs[128*64];
  int z = blockIdx.z;
  const short* A0 = A + (size_t)z*zA;
  const short* B0 = Bt + (size_t)z*zB;
  int tid = threadIdx.x;
  int w = tid >> 6, lane = tid & 63;
  int l16 = lane & 15, lhi = lane >> 4;
  int wr = w >> 1, wc = w & 1;
  int gx = gridDim.x;
  int nwg = gx*gridDim.y;
  int lin = blockIdx.y*gx + blockIdx.x;
  int wg = (lin & 7)*(nwg >> 3) + (lin >> 3);
  int bn = wg % gx, bm = wg / gx;
  const short* Ab = A0 + (size_t)bm*128*Kstride;
  const short* Bb = B0 + (size_t)bn*128*Kstride;
  int srow = w*8 + (lane>>3);
  int scol = lane & 7;
  f32x4 acc[4][4] = {};
  for(int kt=0; kt<Klen; kt+=64){
    __syncthreads();
    #pragma unroll
    for(int q=0;q<4;q++){
      int row = q*32 + srow;
      int c8 = scol ^ (row & 7);
      int ldsoff = (q*256 + w*64)*8;
      load_lds16(Ab + (size_t)row*Kstride + kt + c8*8, As + ldsoff);
      load_lds16(Bb + (size_t)row*Kstride + kt + c8*8, Bs + ldsoff);
    }
    __syncthreads();
    #pragma unroll
    for(int kk=0;kk<2;kk++){
      short8 af[4], bf[4];
      #pragma unroll
      for(int m=0;m<4;m++){
        int row = wr*64 + m*16 + l16;
        int slot = (kk*4 + lhi) ^ (row & 7);
        af[m] = *(const short8*)(As + row*64 + slot*8);
      }
      #pragma unroll
      for(int n=0;n<4;n++){
        int row = wc*64 + n*16 + l16;
        int slot = (kk*4 + lhi) ^ (row & 7);
        bf[n] = *(const short8*)(Bs + row*64 + slot*8);
      }
      #pragma unroll
      for(int m=0;m<4;m++){
        #pragma unroll
        for(int n=0;n<4;n++)
          acc[m][n] = __builtin_amdgcn_mfma_f32_16x16x32_bf16(af[m], bf[n], acc[m][n], 0, 0, 0);
      }
    }
  }
  int m0 = bm*128 + wr*64;
  int n0 = bn*128 + wc*64;
  #pragma unroll
  for(int m=0;m<4;m++){
    #pragma unroll
    for(int n=0;n<4;n++){
      #pragma unroll
      for(int jj=0;jj<4;jj++){
        int row = m0 + m*16 + lhi*4 + jj;
        int col = n0 + n*16 + l16;
        size_t ix = (size_t)row*N + col;
        float val = acc[m][n][jj];
        if constexpr (EPI==0){ ((short*)Cout)[(size_t)z*zC + ix] = f2bf(val); }
        else if constexpr (EPI==3){ float rv = fmaxf(val, 0.f); ((short*)Cout)[ix] = f2bf(rv*rv); }
        else if constexpr (EPI==5){ ((float*)Cout)[(size_t)z*zC + ix] = val; }
        else {
          short* o = (short*)Cout + (size_t)z*zC;
          o[ix] = (z==3) ? f2bf(val/(1.f+expf(-val))) : f2bf(val);
        }
      }
    }
  }
}

// ---------------- 256^2 MFMA GEMM, 8-phase, thinned barriers ---------------
// Hazard ledger (buffers A0,A1,B0,B1; stages P1:A1h0 P2:A1h1 P3:B0h0'
// P4:B0h1' P5:A0h0' P6:A0h1' P7:B1h0' P8:B1h1'; LDS reads P1:{B0,A0q0}
// P2:A0q1 P3:A0q2 P4:A0q3 P5:{B1,A1q0} P6:A1q1 P7:A1q2 P8:A1q3):
//  - barriers only at end of P2 (B0 read->write), P4 (A0), P6 (B1), P8 (A1).
//  - vmcnt(4) at P4 retires {prevP7,prevP8,P1,P2} => B1+A1 ready for P5.
//    vmcnt(4) at P8 retires {P3,P4,P5,P6} => B0+A0 ready for next P1.
//  - per-phase lgkmcnt(0) is own-wave only (no barrier needed).
template<int EPI>
__global__ __launch_bounds__(512, 1) void gemm256_kernel(
    const short* __restrict__ A, const short* __restrict__ Bt,
    void* __restrict__ Cout, int M, int N, int Kstride, int Klen,
    long zA, long zB, long zC)
{
  __shared__ __align__(16) short As[2][256*64];
  __shared__ __align__(16) short Bs[2][256*64];
  int z = blockIdx.z;
  const short* A0p = A + (size_t)z*zA;
  const short* B0p = Bt + (size_t)z*zB;
  int tid = threadIdx.x;
  int w = tid >> 6, lane = tid & 63;
  int l16 = lane & 15, lhi = lane >> 4;
  int wr = w >> 2, wc = w & 3;
  int gx = gridDim.x;
  int nwg = gx*gridDim.y;
  int lin = blockIdx.y*gx + blockIdx.x;
  int wg = (lin & 7)*(nwg >> 3) + (lin >> 3);
  int bn = wg % gx, bm = wg / gx;
  const short* Ab = A0p + (size_t)bm*256*Kstride;
  const short* Bb = B0p + (size_t)bn*256*Kstride;
  int srow_w = w*8 + (lane>>3);
  int scol = lane & 7;
  f32x4 acc[8][4] = {};

  auto STG = [&](const short* src, short* dst, int half, int kt){
    #pragma unroll
    for(int q=0;q<2;q++){
      int row = half*128 + q*64 + srow_w;
      int c8 = scol ^ (row & 7);
      load_lds16(src + (size_t)row*Kstride + kt + c8*8,
                 dst + (half*128 + q*64 + w*8)*64);
    }
  };
  auto DSA = [&](const short* Ac, int p, short8 afr[2][2]){
    #pragma unroll
    for(int mm=0;mm<2;mm++)
      #pragma unroll
      for(int kk=0;kk<2;kk++){
        int row = wr*128 + (p*2+mm)*16 + l16;
        int slot = (kk*4 + lhi) ^ (row & 7);
        afr[mm][kk] = *(const short8*)(Ac + row*64 + slot*8);
      }
  };
  auto DSB = [&](const short* Bc, short8 bfr[4][2]){
    #pragma unroll
    for(int n=0;n<4;n++)
      #pragma unroll
      for(int kk=0;kk<2;kk++){
        int row = wc*64 + n*16 + l16;
        int slot = (kk*4 + lhi) ^ (row & 7);
        bfr[n][kk] = *(const short8*)(Bc + row*64 + slot*8);
      }
  };
  auto MM = [&](int p, short8 afr[2][2], short8 bfr[4][2]){
    __builtin_amdgcn_s_setprio(1);
    #pragma unroll
    for(int mm=0;mm<2;mm++)
      #pragma unroll
      for(int n=0;n<4;n++)
        #pragma unroll
        for(int kk=0;kk<2;kk++)
          acc[p*2+mm][n] = __builtin_amdgcn_mfma_f32_16x16x32_bf16(
              afr[mm][kk], bfr[n][kk], acc[p*2+mm][n], 0, 0, 0);
    __builtin_amdgcn_s_setprio(0);
  };
  #define LG0()  do{ asm volatile("s_waitcnt lgkmcnt(0)" ::: "memory"); \
      __builtin_amdgcn_sched_barrier(0); }while(0)
  #define BARX() do{ __builtin_amdgcn_s_barrier(); \
      __builtin_amdgcn_sched_barrier(0); }while(0)

  int NT = Klen >> 6;
  int niter = NT >> 1;
  // prologue: A0,B0 full + B1 full; retire first 8 (A0,B0)
  STG(Ab, &As[0][0], 0, 0); STG(Ab, &As[0][0], 1, 0);
  STG(Bb, &Bs[0][0], 0, 0); STG(Bb, &Bs[0][0], 1, 0);
  STG(Bb, &Bs[1][0], 0, 64); STG(Bb, &Bs[1][0], 1, 64);
  asm volatile("s_waitcnt vmcnt(4)" ::: "memory");
  BARX();

  for(int i=0;i<niter;++i){
    int kt_o  = (2*i+1) << 6;
    int kt_e2 = (2*i+2) << 6;
    int kt_o2 = (2*i+3) << 6;
    bool st = (i+1 < niter);
    short8 bfr[4][2], afr[2][2];
    // P1
    DSB(&Bs[0][0], bfr);
    DSA(&As[0][0], 0, afr);
    STG(Ab, &As[1][0], 0, kt_o);
    LG0(); MM(0, afr, bfr);
    // P2
    DSA(&As[0][0], 1, afr);
    STG(Ab, &As[1][0], 1, kt_o);
    LG0(); MM(1, afr, bfr);
    BARX();                          // B0 reads done -> P3 may stage B0
    // P3
    DSA(&As[0][0], 2, afr);
    if(st) STG(Bb, &Bs[0][0], 0, kt_e2);
    LG0(); MM(2, afr, bfr);
    // P4
    DSA(&As[0][0], 3, afr);
    if(st){ STG(Bb, &Bs[0][0], 1, kt_e2);
            asm volatile("s_waitcnt vmcnt(4)" ::: "memory"); }
    else  { asm volatile("s_waitcnt vmcnt(0)" ::: "memory"); }
    LG0(); MM(3, afr, bfr);
    BARX();                          // A0 reads done; A1/B1 stages published
    // P5
    DSB(&Bs[1][0], bfr);
    DSA(&As[1][0], 0, afr);
    if(st) STG(Ab, &As[0][0], 0, kt_e2);
    LG0(); MM(0, afr, bfr);
    // P6
    DSA(&As[1][0], 1, afr);
    if(st) STG(Ab, &As[0][0], 1, kt_e2);
    LG0(); MM(1, afr, bfr);
    BARX();                          // B1 reads done -> P7 may stage B1
    // P7
    DSA(&As[1][0], 2, afr);
    if(st) STG(Bb, &Bs[1][0], 0, kt_o2);
    LG0(); MM(2, afr, bfr);
    // P8
    DSA(&As[1][0], 3, afr);
    if(st){ STG(Bb, &Bs[1][0], 1, kt_o2);
            asm volatile("s_waitcnt vmcnt(4)" ::: "memory"); }
    else  { asm volatile("s_waitcnt vmcnt(0)" ::: "memory"); }
    LG0(); MM(3, afr, bfr);
    BARX();                          // A1 reads done; A0/B0 stages published
  }
  #undef LG0
  #undef BARX

  int m0 = bm*256 + wr*128;
  int n0 = bn*256 + wc*64;
  #pragma unroll
  for(int m=0;m<8;m++){
    #pragma unroll
    for(int n=0;n<4;n++){
      #pragma unroll
      for(int jj=0;jj<4;jj++){
        int row = m0 + m*16 + lhi*4 + jj;
        int col = n0 + n*16 + l16;
        size_t ix = (size_t)row*N + col;
        float val = acc[m][n][jj];
        if constexpr (EPI==3){ float rv = fmaxf(val, 0.f); ((short*)Cout)[ix] = f2bf(rv*rv); }
        else if constexpr (EPI==5){ ((float*)Cout)[(size_t)z*zC + ix] = val; }
        else {
          short* o = (short*)Cout + (size_t)z*zC;
          o[ix] = (z==3) ? f2bf(val/(1.f+expf(-val))) : f2bf(val);
        }
      }
    }
  }
}

// ---------------- WKV pass A ----------------
__global__ __launch_bounds__(256) void wkv_chunk_kernel(
    const short* __restrict__ rb, const short* __restrict__ kb,
    const short* __restrict__ vb, const float* __restrict__ db,
    const float* __restrict__ wkv_state, const float* __restrict__ u,
    const int* __restrict__ sp,
    float* __restrict__ yb, short* __restrict__ rtb,
    float* __restrict__ Bc, float* __restrict__ Pc)
{
  int blk = blockIdx.x;
  int ch = blk >> 5;
  int h  = blk & 31;
  int tid = threadIdx.x;
  int a = tid & 3, j = tid >> 2;
  int w = tid >> 6, lane = tid & 63;
  __shared__ float sr[2][64], sk[2][64], suk[2][64], sv[2][64], sd[2][64];
  __shared__ float sp_[64];
  float u_reg = (w==1) ? u[h*64 + lane] : 0.f;
  if(tid < 64) sp_[tid] = 1.f;
  float S[16];
  #pragma unroll
  for(int ii=0;ii<16;ii++) S[ii]=0.f;
  int sp0=sp[0], sp1=sp[1], sp2=sp[2], sp3=sp[3];
  int tbase = ch*CHUNK;
  {
    size_t gb = (size_t)tbase*CC + h*64;
    if(w==0)      sr[0][lane] = bf2f(rb[gb+lane]);
    else if(w==1){ float kv_=bf2f(kb[gb+lane]); sk[0][lane]=kv_; suk[0][lane]=u_reg*kv_; }
    else if(w==2) sv[0][lane] = bf2f(vb[gb+lane]);
    else          sd[0][lane] = db[gb+lane];
  }
  __syncthreads();
  for(int tl=0; tl<CHUNK; ++tl){
    int t = tbase + tl;
    int buf = tl & 1;
    if(tl+1 < CHUNK){
      size_t nb = (size_t)(t+1)*CC + h*64;
      int b2_ = buf^1;
      if(w==0)      sr[b2_][lane] = bf2f(rb[nb+lane]);
      else if(w==1){ float kv_=bf2f(kb[nb+lane]); sk[b2_][lane]=kv_; suk[b2_][lane]=u_reg*kv_; }
      else if(w==2) sv[b2_][lane] = bf2f(vb[nb+lane]);
      else          sd[b2_][lane] = db[nb+lane];
    }
    size_t base = (size_t)t*CC + h*64;
    bool is_start = (sp0==t)|(sp1==t)|(sp2==t)|(sp3==t);
    if(is_start){
      int sid = (sp0<=t)+(sp1<=t)+(sp2<=t)+(sp3<=t) - 1;
      sid = sid<0?0:(sid>3?3:sid);
      const float* wsrc = wkv_state + (((size_t)sid*NH + h)*HSZ + a*16)*HSZ + j;
      #pragma unroll
      for(int ii=0;ii<16;ii++) S[ii] = wsrc[(size_t)ii*HSZ];
      if(tid < 64) sp_[tid] = 0.f;
    }
    float vj = sv[buf][j];
    float yp = 0.f, bp = 0.f;
    #pragma unroll
    for(int ii=0;ii<16;ii++){
      int i = a*16 + ii;
      float ri = sr[buf][i];
      yp += ri * S[ii];
      bp += ri * suk[buf][i];
    }
    yp += __shfl_xor(yp, 1); yp += __shfl_xor(yp, 2);
    bp += __shfl_xor(bp, 1); bp += __shfl_xor(bp, 2);
    if(a == 0) yb[base + j] = yp + bp*vj;
    if(tid < 64){
      rtb[base + tid] = f2bf(sr[buf][tid] * sp_[tid]);
      sp_[tid] *= sd[buf][tid];
    }
    #pragma unroll
    for(int ii=0;ii<16;ii++){
      int i = a*16 + ii;
      S[ii] = sd[buf][i]*S[ii] + sk[buf][i]*vj;
    }
    __syncthreads();
  }
  size_t cb = ((size_t)ch*NH + h)*HSZ*HSZ;
  #pragma unroll
  for(int ii=0;ii<16;ii++) Bc[cb + (size_t)(a*16+ii)*HSZ + j] = S[ii];
  if(tid < 64) Pc[((size_t)ch*NH + h)*HSZ + tid] = sp_[tid];
}

// ---------------- WKV pass B ----------------
__global__ __launch_bounds__(256) void wkv_combine_kernel(
    float* __restrict__ BS, const float* __restrict__ Pc)
{
  int idx = blockIdx.x*256 + threadIdx.x;
  int hi = idx >> 6;
  float s = 0.f;
  for(int cc=0; cc<NCHUNK; ++cc){
    size_t ix = (size_t)cc*(NH*HSZ*HSZ) + idx;
    float b = BS[ix];
    BS[ix] = s;
    s = Pc[cc*(NH*HSZ) + hi]*s + b;
  }
}

// ---------------- WKV pass C + fused GroupNorm*g -> bf16 ----------------
__global__ __launch_bounds__(256) void wkv_corr_gn_kernel(
    const short* __restrict__ rtb, const float* __restrict__ Sin,
    const float* __restrict__ yb, const short* __restrict__ gb,
    const float* __restrict__ gam, const float* __restrict__ bet,
    short* __restrict__ yg)
{
  int blk = blockIdx.x;
  int ch = blk >> 5, h = blk & 31;
  __shared__ float Ssm[64][64];
  __shared__ float Rsm[32][65];
  int tid = threadIdx.x;
  const float* Sp = Sin + (size_t)(ch*NH + h)*HSZ*HSZ;
  #pragma unroll
  for(int q=0;q<16;q++) ((float*)Ssm)[q*256+tid] = Sp[q*256+tid];
  #pragma unroll
  for(int q=0;q<8;q++){
    int ix = q*256 + tid;
    int tl = ix>>6, i = ix&63;
    Rsm[tl][i] = bf2f(rtb[(size_t)(ch*CHUNK+tl)*CC + h*64 + i]);
  }
  __syncthreads();
  int tl = tid >> 3;   // row 0..31 (8 lanes per row)
  int jq = tid & 7;
  float acc[8];
  #pragma unroll
  for(int jj=0;jj<8;jj++) acc[jj]=0.f;
  for(int i=0;i<64;i++){
    float rv = Rsm[tl][i];
    #pragma unroll
    for(int jj=0;jj<8;jj++) acc[jj] += rv * Ssm[i][jq*8+jj];
  }
  int t = ch*CHUNK + tl;
  float val[8];
  float s = 0.f, ss = 0.f;
  #pragma unroll
  for(int jj=0;jj<8;jj++){
    float v = yb[(size_t)t*CC + h*64 + jq*8+jj] + acc[jj];
    val[jj] = v; s += v; ss += v*v;
  }
  #pragma unroll
  for(int off=1; off<8; off<<=1){ s += __shfl_xor(s,off); ss += __shfl_xor(ss,off); }
  float mu = s*(1.f/64.f);
  float var = ss*(1.f/64.f) - mu*mu;
  float rstd = rsqrtf(var + 6.4e-4f);   // eps = 1e-5 * 8^2
  #pragma unroll
  for(int jj=0;jj<8;jj++){
    int cc = h*64 + jq*8+jj;
    float o = (val[jj]-mu)*rstd*gam[cc] + bet[cc];
    yg[(size_t)t*CC + cc] = f2bf(o * bf2f(gb[(size_t)t*CC + cc]));
  }
}

// ---------------- final: out += sigmoid(s0+s1)*(kv0+kv1+kv2+kv3) ----------------
__global__ __launch_bounds__(256) void final_kernel(
    const float* __restrict__ s0, const float* __restrict__ s1,
    const float* __restrict__ kv0, const float* __restrict__ kv1,
    const float* __restrict__ kv2, const float* __restrict__ kv3,
    float* __restrict__ out)
{
  size_t i = ((size_t)blockIdx.x*256 + threadIdx.x)*8;
  #pragma unroll
  for(int j=0;j<8;j++){
    float sv = s0[i+j] + s1[i+j];
    float sig = 1.f/(1.f + expf(-sv));
    out[i+j] = out[i+j] + sig*(kv0[i+j] + kv1[i+j] + kv2[i+j] + kv3[i+j]);
  }
}

extern "C" void kernel_launch(void* const* d_in, const int* in_sizes, int n_in,
                              void* d_out, int out_size, void* d_ws, size_t ws_size,
                              hipStream_t stream)
{
  (void)in_sizes; (void)n_in; (void)out_size;
  const float* x         = (const float*)d_in[0];
  const int*   sp        = (const int*)d_in[1];
  const float* att_state = (const float*)d_in[2];
  const float* wkv_state = (const float*)d_in[3];
  const float* ffn_state = (const float*)d_in[4];
  const float* ln1_g=(const float*)d_in[5],  *ln1_b=(const float*)d_in[6];
  const float* ln2_g=(const float*)d_in[7],  *ln2_b=(const float*)d_in[8];
  const float* maa_x=(const float*)d_in[9],  *maa_w=(const float*)d_in[10], *maa_k=(const float*)d_in[11];
  const float* maa_v=(const float*)d_in[12], *maa_r=(const float*)d_in[13], *maa_g=(const float*)d_in[14];
  const float* tm_w1=(const float*)d_in[15], *tm_w2=(const float*)d_in[16];
  const float* td=(const float*)d_in[17],    *td_w1=(const float*)d_in[18], *td_w2=(const float*)d_in[19];
  const float* u = (const float*)d_in[20];
  const float* Wr=(const float*)d_in[21], *Wk=(const float*)d_in[22], *Wv=(const float*)d_in[23];
  const float* Wg=(const float*)d_in[24], *Wo=(const float*)d_in[25];
  const float* lnx_g=(const float*)d_in[26], *lnx_b=(const float*)d_in[27];
  const float* cm_k=(const float*)d_in[28],  *cm_r=(const float*)d_in[29];
  const float* Wck=(const float*)d_in[30], *Wcv=(const float*)d_in[31], *Wcr=(const float*)d_in[32];

  char* ws = (char*)d_ws;
  const size_t SLOT  = (size_t)TT*CC*4;
  const size_t BSLOT = (size_t)TT*CC*2;
  const size_t WT_SZ = (size_t)4*CC*CC*2;
  const size_t NEED  = 6*SLOT + 10*BSLOT + WT_SZ + (4u<<20);
  if(ws_size < NEED) return;

  float* xa   = (float*)(ws + 0*SLOT);
  float* xxb  = (float*)(ws + 1*SLOT);
  float* zw   = (float*)(ws + 2*SLOT);
  float* decb = (float*)(ws + 3*SLOT);
  float* yb   = (float*)(ws + 4*SLOT);
  float* S5   = (float*)(ws + 5*SLOT);
  float* BS   = xa;
  float* xxxPart = zw;
  float* h1Part  = yb;
  short* bA   = (short*)(ws + 6*SLOT);
  short* bO   = (short*)(ws + 6*SLOT + 4*BSLOT);
  short* b1 = bO + 0*(TT*CC);
  short* b2 = bO + 1*(TT*CC);
  short* b3 = bO + 2*(TT*CC);
  short* b4 = bO + 3*(TT*CC);
  short* b5 = bO + 4*(TT*CC);
  short* b6 = bO + 5*(TT*CC);
  short* WT = (short*)(ws + 6*SLOT + 10*BSLOT);
  char*  aux = (char*)WT + WT_SZ;
  float* xxxb = (float*)(aux);
  float* h1b  = (float*)(aux + (2u<<20));
  float* Pc   = (float*)(aux + (5u<<19));
  float* xmid = (float*)d_out;

  dim3 B256(256), B512(512);
  const int NTC8 = TT*CC/8/256;

  // ---- Tmix front (fused LN1 + shift + z-prep) ----
  front_kernel<<<TT, B256, 0, stream>>>(x, att_state, sp, ln1_g, ln1_b, maa_x,
                                        xa, xxb, bA);
  transpose_f2bf_kernel<<<dim3(4, CC/64), B256, 0, stream>>>(tm_w1, WT, CC, 160);
  gemm_bt_kernel<5><<<dim3(2, TT/128, 8), B256, 0, stream>>>(bA, WT, xxxPart, TT, 256, CC, 256,
      256, 256, (long)TT*256);
  tanh_reduce_kernel<256,160><<<TT, B256, 0, stream>>>(xxxPart, xxxb);
  mix5_kernel<<<NTC8, B256, 0, stream>>>(xxxb, tm_w2, xa, xxb,
      maa_w, maa_k, maa_v, maa_r, maa_g,
      b5, bA + 1*(TT*CC), bA + 2*(TT*CC), bA, bA + 3*(TT*CC));
  transpose_f2bf_kernel<<<dim3(2, CC/64), B256, 0, stream>>>(td_w1, WT, CC, 64);
  gemm_bt_kernel<5><<<dim3(1, TT/128, 8), B256, 0, stream>>>(b5, WT, h1Part, TT, 128, CC, 256,
      256, 256, (long)TT*128);
  tanh_reduce_kernel<128,64><<<TT/2, B256, 0, stream>>>(h1Part, h1b);
  dec_kernel<<<NTC8, B256, 0, stream>>>(h1b, td_w2, td, decb);

  // ---- r,k,v,g projections: batched 256^2 8-phase GEMM (256 blocks) ----
  WPtr4 w4; w4.w[0]=Wr; w4.w[1]=Wk; w4.w[2]=Wv; w4.w[3]=Wg;
  transpose4_f2bf_kernel<<<dim3(CC/64, CC/64, 4), B256, 0, stream>>>(w4, WT);
  gemm256_kernel<6><<<dim3(CC/256, TT/256, 4), B512, 0, stream>>>(bA, WT, b1, TT, CC, CC, CC,
      (long)TT*CC, (long)CC*CC, (long)TT*CC);

  // ---- WKV chunked scan (corr+GN fused) ----
  wkv_chunk_kernel<<<NCHUNK*NH, B256, 0, stream>>>(b1, b2, b3, decb, wkv_state, u, sp,
                                                   yb, b5, BS, Pc);
  wkv_combine_kernel<<<NH*HSZ*HSZ/256, B256, 0, stream>>>(BS, Pc);
  wkv_corr_gn_kernel<<<NCHUNK*NH, B256, 0, stream>>>(b5, BS, yb, b4, lnx_g, lnx_b, b6);

  // ---- output projection (128^2 split-K=2) + fused residual+LN2 ----
  transpose_f2bf_kernel<<<dim3(CC/64, CC/64), B256, 0, stream>>>(Wo, WT, CC, CC);
  gemm_bt_kernel<5><<<dim3(CC/128, TT/128, 2), B256, 0, stream>>>(b6, WT, yb, TT, CC, CC, 1024,
      1024, 1024, (long)TT*CC);
  ln2_fused_kernel<<<TT, B256, 0, stream>>>(yb, S5, x, ln2_g, ln2_b, xmid, zw, 1e-5f);

  // ---- CMix ----
  shift2_kernel<<<TT, B256, 0, stream>>>(zw, ffn_state, sp, cm_k, cm_r, bA, bA + 1*(TT*CC));
  transpose_f2bf_kernel<<<dim3(FFND/64, CC/64), B256, 0, stream>>>(Wck, WT, CC, FFND);
  gemm256_kernel<3><<<dim3(FFND/256, TT/256, 1), B512, 0, stream>>>(bA, WT, b1, TT, FFND, CC, CC,
      0, 0, 0);
  transpose_f2bf_kernel<<<dim3(CC/64, FFND/64), B256, 0, stream>>>(Wcv, WT, FFND, CC);
  gemm256_kernel<5><<<dim3(CC/256, TT/256, 4), B512, 0, stream>>>(b1, WT, zw, TT, CC, FFND, 1792,
      1792, 1792, (long)TT*CC);
  transpose_f2bf_kernel<<<dim3(CC/64, CC/64), B256, 0, stream>>>(Wcr, WT, CC, CC);
  gemm_bt_kernel<5><<<dim3(CC/128, TT/128, 2), B256, 0, stream>>>(bA + 1*(TT*CC), WT, xa, TT, CC, CC, 1024,
      1024, 1024, (long)TT*CC);
  final_kernel<<<NTC8, B256, 0, stream>>>(xa, xxb, zw, decb, yb, S5, xmid);
}

// Round 14
// 686.692 us; speedup vs baseline: 1.2551x; 1.0047x over previous
//
#include <hip/hip_runtime.h>
#include <stdint.h>

// RWKV6 block: B=1, T=2048, C=2048, H=32, HS=64, FFN=7168, NS=4
// Workspace: 6*16M (f32) + 4*8M (bA) + 6*8M (bO) + 32M (WT) + 4M aux = 212 MiB.

#define TT 2048
#define CC 2048
#define NH 32
#define HSZ 64
#define FFND 7168
#define CHUNK 32
#define NCHUNK 64

typedef __attribute__((ext_vector_type(8))) short short8;
typedef __attribute__((ext_vector_type(4))) float f32x4;

__device__ __forceinline__ float bf2f(short s){
  return __uint_as_float(((uint32_t)(uint16_t)s) << 16);
}
__device__ __forceinline__ short f2bf(float f){
  uint32_t u = __float_as_uint(f);
  u = u + 0x7fffu + ((u >> 16) & 1u);
  return (short)(u >> 16);
}

// ---------------- fused front: LN1(t) + LN1(t-1) + shift + z-prep ----------------
__global__ __launch_bounds__(256) void front_kernel(
    const float* __restrict__ x, const float* __restrict__ st,
    const int* __restrict__ sp, const float* __restrict__ gam,
    const float* __restrict__ bet, const float* __restrict__ maa,
    float* __restrict__ xa, float* __restrict__ xxb, short* __restrict__ z)
{
  int t = blockIdx.x, tid = threadIdx.x;
  const float* row = x + (size_t)t*CC;
  float4 a0 = *(const float4*)(row + tid*8);
  float4 a1 = *(const float4*)(row + tid*8 + 4);
  bool hp = (t > 0);
  float4 p0 = make_float4(0.f,0.f,0.f,0.f), p1 = p0;
  if(hp){
    const float* prow = x + (size_t)(t-1)*CC;
    p0 = *(const float4*)(prow + tid*8);
    p1 = *(const float4*)(prow + tid*8 + 4);
  }
  float sa  = a0.x+a0.y+a0.z+a0.w + a1.x+a1.y+a1.z+a1.w;
  float ssa = a0.x*a0.x+a0.y*a0.y+a0.z*a0.z+a0.w*a0.w
            + a1.x*a1.x+a1.y*a1.y+a1.z*a1.z+a1.w*a1.w;
  float sq  = p0.x+p0.y+p0.z+p0.w + p1.x+p1.y+p1.z+p1.w;
  float ssq = p0.x*p0.x+p0.y*p0.y+p0.z*p0.z+p0.w*p0.w
            + p1.x*p1.x+p1.y*p1.y+p1.z*p1.z+p1.w*p1.w;
  #pragma unroll
  for(int off=1; off<64; off<<=1){
    sa += __shfl_xor(sa,off); ssa += __shfl_xor(ssa,off);
    sq += __shfl_xor(sq,off); ssq += __shfl_xor(ssq,off);
  }
  __shared__ float sm[16];
  int w = tid>>6;
  if((tid&63)==0){ sm[w]=sa; sm[4+w]=ssa; sm[8+w]=sq; sm[12+w]=ssq; }
  __syncthreads();
  sa = sm[0]+sm[1]+sm[2]+sm[3];    ssa = sm[4]+sm[5]+sm[6]+sm[7];
  sq = sm[8]+sm[9]+sm[10]+sm[11];  ssq = sm[12]+sm[13]+sm[14]+sm[15];
  float mean_a = sa*(1.f/CC);
  float rstd_a = rsqrtf(ssa*(1.f/CC) - mean_a*mean_a + 1e-5f);
  float mean_q = sq*(1.f/CC);
  float rstd_q = rsqrtf(ssq*(1.f/CC) - mean_q*mean_q + 1e-5f);
  int sp0=sp[0], sp1=sp[1], sp2=sp[2], sp3=sp[3];
  bool is_start = (sp0==t)|(sp1==t)|(sp2==t)|(sp3==t);
  int sid = (sp0<=t)+(sp1<=t)+(sp2<=t)+(sp3<=t) - 1;
  sid = sid<0?0:(sid>3?3:sid);
  int c = tid*8;
  size_t base = (size_t)t*CC + c;
  float av[8] = {a0.x,a0.y,a0.z,a0.w,a1.x,a1.y,a1.z,a1.w};
  float pv[8] = {p0.x,p0.y,p0.z,p0.w,p1.x,p1.y,p1.z,p1.w};
  #pragma unroll
  for(int j=0;j<8;j++){
    float g = gam[c+j], b = bet[c+j];
    float lnt = (av[j]-mean_a)*rstd_a*g + b;
    float sh;
    if(is_start)      sh = st[(size_t)sid*CC + c + j];
    else if(hp)       sh = (pv[j]-mean_q)*rstd_q*g + b;
    else              sh = 0.f;
    float xx = sh - lnt;
    xa[base+j]  = lnt;
    xxb[base+j] = xx;
    z[base+j]   = f2bf(lnt + xx*maa[c+j]);
  }
}

// ---------------- fused: xmid = p0+p1+x ; zw = LN(xmid) ----------------
__global__ __launch_bounds__(256) void ln2_fused_kernel(
    const float* __restrict__ p0, const float* __restrict__ p1,
    const float* __restrict__ xres, const float* __restrict__ gam,
    const float* __restrict__ bet, float* __restrict__ xsum,
    float* __restrict__ lnout, float eps)
{
  int t = blockIdx.x, tid = threadIdx.x;
  size_t base = (size_t)t*CC + tid*8;
  float vv[8];
  float s = 0.f, ss = 0.f;
  #pragma unroll
  for(int j=0;j<8;j++){
    float v = p0[base+j] + p1[base+j] + xres[base+j];
    vv[j] = v; s += v; ss += v*v;
    xsum[base+j] = v;
  }
  #pragma unroll
  for(int off=1; off<64; off<<=1){ s += __shfl_xor(s,off); ss += __shfl_xor(ss,off); }
  __shared__ float sm[8];
  int w = tid>>6;
  if((tid&63)==0){ sm[w]=s; sm[4+w]=ss; }
  __syncthreads();
  s = sm[0]+sm[1]+sm[2]+sm[3]; ss = sm[4]+sm[5]+sm[6]+sm[7];
  float mean = s * (1.f/CC);
  float var  = ss * (1.f/CC) - mean*mean;
  float rstd = rsqrtf(var + eps);
  int c = tid*8;
  #pragma unroll
  for(int j=0;j<8;j++) lnout[base+j] = (vv[j]-mean)*rstd*gam[c+j] + bet[c+j];
}

// ---------------- token shift (ffn): xk2/xr2 fused, bf16 out ----------------
__global__ __launch_bounds__(256) void shift2_kernel(
    const float* __restrict__ xf, const float* __restrict__ st,
    const int* __restrict__ sp, const float* __restrict__ cmk,
    const float* __restrict__ cmr, short* __restrict__ xk2, short* __restrict__ xr2)
{
  int t = blockIdx.x, tid = threadIdx.x;
  int sp0=sp[0], sp1=sp[1], sp2=sp[2], sp3=sp[3];
  bool is_start = (sp0==t)|(sp1==t)|(sp2==t)|(sp3==t);
  int sid = (sp0<=t)+(sp1<=t)+(sp2<=t)+(sp3<=t) - 1;
  sid = sid<0?0:(sid>3?3:sid);
  int c = tid*8;
  const float* src = is_start ? (st + (size_t)sid*CC + c)
                   : (t>0 ? xf + (size_t)(t-1)*CC + c : nullptr);
  const float* cur = xf + (size_t)t*CC + c;
  size_t ix = (size_t)t*CC + c;
  #pragma unroll
  for(int jj=0;jj<8;jj++){
    float xfv = cur[jj];
    float sh = src ? src[jj] : 0.f;
    float d = sh - xfv;
    xk2[ix+jj] = f2bf(xfv + d*cmk[c+jj]);
    xr2[ix+jj] = f2bf(xfv + d*cmr[c+jj]);
  }
}

// ---------------- fused 5-way maa mix -> bf16 outputs ----------------
__global__ __launch_bounds__(256) void mix5_kernel(
    const float* __restrict__ xxxb, const float* __restrict__ w2,
    const float* __restrict__ xa, const float* __restrict__ xxv,
    const float* __restrict__ mw, const float* __restrict__ mk,
    const float* __restrict__ mv, const float* __restrict__ mr,
    const float* __restrict__ mg,
    short* __restrict__ ow, short* __restrict__ ok, short* __restrict__ ov,
    short* __restrict__ orr, short* __restrict__ og)
{
  int t0 = (blockIdx.x >> 3) * 8;                  // uniform (no tid)
  int c  = ((blockIdx.x & 7) << 8) + threadIdx.x;  // 0..2047
  float acc[5][8];
  #pragma unroll
  for(int s=0;s<5;s++)
    #pragma unroll
    for(int tt=0;tt<8;tt++) acc[s][tt]=0.f;
  #pragma unroll
  for(int s=0;s<5;s++){
    for(int e=0;e<32;e++){
      float wv = w2[(size_t)(s*32+e)*CC + c];
      #pragma unroll
      for(int tt=0;tt<8;tt++)
        acc[s][tt] += xxxb[(size_t)(t0+tt)*160 + s*32 + e] * wv;
    }
  }
  float vmw=mw[c], vmk=mk[c], vmv=mv[c], vmr=mr[c], vmg=mg[c];
  #pragma unroll
  for(int tt=0;tt<8;tt++){
    size_t ix = (size_t)(t0+tt)*CC + c;
    float av = xa[ix], xv = xxv[ix];
    ow[ix]  = f2bf(av + xv*(vmw + acc[0][tt]));
    ok[ix]  = f2bf(av + xv*(vmk + acc[1][tt]));
    ov[ix]  = f2bf(av + xv*(vmv + acc[2][tt]));
    orr[ix] = f2bf(av + xv*(vmr + acc[3][tt]));
    og[ix]  = f2bf(av + xv*(vmg + acc[4][tt]));
  }
}

// ---------------- dec = exp(-exp(td + h1 @ td_w2)) (f32) ----------------
__global__ __launch_bounds__(256) void dec_kernel(
    const float* __restrict__ h1b, const float* __restrict__ tw2,
    const float* __restrict__ td, float* __restrict__ out)
{
  int t0 = (blockIdx.x >> 3) * 8;
  int c  = ((blockIdx.x & 7) << 8) + threadIdx.x;
  float acc[8] = {0,0,0,0,0,0,0,0};
  for(int e=0;e<64;e++){
    float wv = tw2[(size_t)e*CC + c];
    #pragma unroll
    for(int tt=0;tt<8;tt++) acc[tt] += h1b[(size_t)(t0+tt)*64 + e]*wv;
  }
  float tdc = td[c];
  #pragma unroll
  for(int tt=0;tt<8;tt++)
    out[(size_t)(t0+tt)*CC + c] = expf(-expf(tdc + acc[tt]));
}

// ---------------- tanh split-K reduce ----------------
template<int N, int NK>
__global__ __launch_bounds__(256) void tanh_reduce_kernel(
    const float* __restrict__ part, float* __restrict__ out)
{
  int idx = blockIdx.x*256 + threadIdx.x;
  int col = idx & (N-1);
  int row = idx >> (N==256 ? 8 : 7);
  float s = 0.f;
  #pragma unroll
  for(int z=0;z<8;z++) s += part[(size_t)z*TT*N + idx];
  if(col < NK) out[(size_t)row*NK + col] = tanhf(s);
}

// ---------------- W[K,N] f32 -> Wt[NPAD,K] bf16 ----------------
__global__ __launch_bounds__(256) void transpose_f2bf_kernel(
    const float* __restrict__ W, short* __restrict__ Wt, int K, int N)
{
  __shared__ float tile[64][65];
  int n0 = blockIdx.x*64, k0 = blockIdx.y*64;
  int tid = threadIdx.x;
  #pragma unroll
  for(int q=0;q<16;q++){
    int ix = q*256 + tid;
    int r = ix >> 6, cc2 = ix & 63;
    tile[r][cc2] = (n0 + cc2 < N) ? W[(size_t)(k0+r)*N + n0 + cc2] : 0.f;
  }
  __syncthreads();
  #pragma unroll
  for(int q=0;q<16;q++){
    int ix = q*256 + tid;
    int r = ix >> 6, cc2 = ix & 63;
    Wt[(size_t)(n0+r)*K + k0 + cc2] = f2bf(tile[cc2][r]);
  }
}

struct WPtr4 { const float* w[4]; };
__global__ __launch_bounds__(256) void transpose4_f2bf_kernel(
    WPtr4 ws4, short* __restrict__ Wt)
{
  __shared__ float tile[64][65];
  int z = blockIdx.z;
  const float* W = ws4.w[z];
  short* dst = Wt + (size_t)z*CC*CC;
  int n0 = blockIdx.x*64, k0 = blockIdx.y*64;
  int tid = threadIdx.x;
  #pragma unroll
  for(int q=0;q<16;q++){
    int ix = q*256 + tid;
    int r = ix >> 6, cc2 = ix & 63;
    tile[r][cc2] = W[(size_t)(k0+r)*CC + n0 + cc2];
  }
  __syncthreads();
  #pragma unroll
  for(int q=0;q<16;q++){
    int ix = q*256 + tid;
    int r = ix >> 6, cc2 = ix & 63;
    dst[(size_t)(n0+r)*CC + k0 + cc2] = f2bf(tile[cc2][r]);
  }
}

__device__ __forceinline__ void load_lds16(const void* g, void* l){
  __builtin_amdgcn_global_load_lds(
      (const __attribute__((address_space(1))) uint32_t*)g,
      (__attribute__((address_space(3))) uint32_t*)l, 16, 0, 0);
}

// ---------------- 128^2 MFMA GEMM (m97-structure + swizzle) ----------------
// EPI: 0 bf16; 3 relu^2 bf16; 5 f32 partial slab; 6 rkvg batch
template<int EPI>
__global__ __launch_bounds__(256) void gemm_bt_kernel(
    const short* __restrict__ A, const short* __restrict__ Bt,
    void* __restrict__ Cout, int M, int N, int Kstride, int Klen,
    long zA, long zB, long zC)
{
  __shared__ __align__(16) short As[128*64];
  __shared__ __align__(16) short Bs[128*64];
  int z = blockIdx.z;
  const short* A0 = A + (size_t)z*zA;
  const short* B0 = Bt + (size_t)z*zB;
  int tid = threadIdx.x;
  int w = tid >> 6, lane = tid & 63;
  int l16 = lane & 15, lhi = lane >> 4;
  int wr = w >> 1, wc = w & 1;
  int gx = gridDim.x;
  int nwg = gx*gridDim.y;
  int lin = blockIdx.y*gx + blockIdx.x;
  int wg = (lin & 7)*(nwg >> 3) + (lin >> 3);
  int bn = wg % gx, bm = wg / gx;
  const short* Ab = A0 + (size_t)bm*128*Kstride;
  const short* Bb = B0 + (size_t)bn*128*Kstride;
  int srow = w*8 + (lane>>3);
  int scol = lane & 7;
  f32x4 acc[4][4] = {};
  for(int kt=0; kt<Klen; kt+=64){
    __syncthreads();
    #pragma unroll
    for(int q=0;q<4;q++){
      int row = q*32 + srow;
      int c8 = scol ^ (row & 7);
      int ldsoff = (q*256 + w*64)*8;
      load_lds16(Ab + (size_t)row*Kstride + kt + c8*8, As + ldsoff);
      load_lds16(Bb + (size_t)row*Kstride + kt + c8*8, Bs + ldsoff);
    }
    __syncthreads();
    #pragma unroll
    for(int kk=0;kk<2;kk++){
      short8 af[4], bf[4];
      #pragma unroll
      for(int m=0;m<4;m++){
        int row = wr*64 + m*16 + l16;
        int slot = (kk*4 + lhi) ^ (row & 7);
        af[m] = *(const short8*)(As + row*64 + slot*8);
      }
      #pragma unroll
      for(int n=0;n<4;n++){
        int row = wc*64 + n*16 + l16;
        int slot = (kk*4 + lhi) ^ (row & 7);
        bf[n] = *(const short8*)(Bs + row*64 + slot*8);
      }
      #pragma unroll
      for(int m=0;m<4;m++){
        #pragma unroll
        for(int n=0;n<4;n++)
          acc[m][n] = __builtin_amdgcn_mfma_f32_16x16x32_bf16(af[m], bf[n], acc[m][n], 0, 0, 0);
      }
    }
  }
  int m0 = bm*128 + wr*64;
  int n0 = bn*128 + wc*64;
  #pragma unroll
  for(int m=0;m<4;m++){
    #pragma unroll
    for(int n=0;n<4;n++){
      #pragma unroll
      for(int jj=0;jj<4;jj++){
        int row = m0 + m*16 + lhi*4 + jj;
        int col = n0 + n*16 + l16;
        size_t ix = (size_t)row*N + col;
        float val = acc[m][n][jj];
        if constexpr (EPI==0){ ((short*)Cout)[(size_t)z*zC + ix] = f2bf(val); }
        else if constexpr (EPI==3){ float rv = fmaxf(val, 0.f); ((short*)Cout)[ix] = f2bf(rv*rv); }
        else if constexpr (EPI==5){ ((float*)Cout)[(size_t)z*zC + ix] = val; }
        else {
          short* o = (short*)Cout + (size_t)z*zC;
          o[ix] = (z==3) ? f2bf(val/(1.f+expf(-val))) : f2bf(val);
        }
      }
    }
  }
}

// ---------------- 256^2 MFMA GEMM, 8-phase, thinned barriers ---------------
template<int EPI>
__global__ __launch_bounds__(512, 1) void gemm256_kernel(
    const short* __restrict__ A, const short* __restrict__ Bt,
    void* __restrict__ Cout, int M, int N, int Kstride, int Klen,
    long zA, long zB, long zC)
{
  __shared__ __align__(16) short As[2][256*64];
  __shared__ __align__(16) short Bs[2][256*64];
  int z = blockIdx.z;
  const short* A0p = A + (size_t)z*zA;
  const short* B0p = Bt + (size_t)z*zB;
  int tid = threadIdx.x;
  int w = tid >> 6, lane = tid & 63;
  int l16 = lane & 15, lhi = lane >> 4;
  int wr = w >> 2, wc = w & 3;
  int gx = gridDim.x;
  int nwg = gx*gridDim.y;
  int lin = blockIdx.y*gx + blockIdx.x;
  int wg = (lin & 7)*(nwg >> 3) + (lin >> 3);
  int bn = wg % gx, bm = wg / gx;
  const short* Ab = A0p + (size_t)bm*256*Kstride;
  const short* Bb = B0p + (size_t)bn*256*Kstride;
  int srow_w = w*8 + (lane>>3);
  int scol = lane & 7;
  f32x4 acc[8][4] = {};

  auto STG = [&](const short* src, short* dst, int half, int kt){
    #pragma unroll
    for(int q=0;q<2;q++){
      int row = half*128 + q*64 + srow_w;
      int c8 = scol ^ (row & 7);
      load_lds16(src + (size_t)row*Kstride + kt + c8*8,
                 dst + (half*128 + q*64 + w*8)*64);
    }
  };
  auto DSA = [&](const short* Ac, int p, short8 afr[2][2]){
    #pragma unroll
    for(int mm=0;mm<2;mm++)
      #pragma unroll
      for(int kk=0;kk<2;kk++){
        int row = wr*128 + (p*2+mm)*16 + l16;
        int slot = (kk*4 + lhi) ^ (row & 7);
        afr[mm][kk] = *(const short8*)(Ac + row*64 + slot*8);
      }
  };
  auto DSB = [&](const short* Bc, short8 bfr[4][2]){
    #pragma unroll
    for(int n=0;n<4;n++)
      #pragma unroll
      for(int kk=0;kk<2;kk++){
        int row = wc*64 + n*16 + l16;
        int slot = (kk*4 + lhi) ^ (row & 7);
        bfr[n][kk] = *(const short8*)(Bc + row*64 + slot*8);
      }
  };
  auto MM = [&](int p, short8 afr[2][2], short8 bfr[4][2]){
    __builtin_amdgcn_s_setprio(1);
    #pragma unroll
    for(int mm=0;mm<2;mm++)
      #pragma unroll
      for(int n=0;n<4;n++)
        #pragma unroll
        for(int kk=0;kk<2;kk++)
          acc[p*2+mm][n] = __builtin_amdgcn_mfma_f32_16x16x32_bf16(
              afr[mm][kk], bfr[n][kk], acc[p*2+mm][n], 0, 0, 0);
    __builtin_amdgcn_s_setprio(0);
  };
  #define LG0()  do{ asm volatile("s_waitcnt lgkmcnt(0)" ::: "memory"); \
      __builtin_amdgcn_sched_barrier(0); }while(0)
  #define BARX() do{ __builtin_amdgcn_s_barrier(); \
      __builtin_amdgcn_sched_barrier(0); }while(0)

  int NT = Klen >> 6;
  int niter = NT >> 1;
  STG(Ab, &As[0][0], 0, 0); STG(Ab, &As[0][0], 1, 0);
  STG(Bb, &Bs[0][0], 0, 0); STG(Bb, &Bs[0][0], 1, 0);
  STG(Bb, &Bs[1][0], 0, 64); STG(Bb, &Bs[1][0], 1, 64);
  asm volatile("s_waitcnt vmcnt(4)" ::: "memory");
  BARX();

  for(int i=0;i<niter;++i){
    int kt_o  = (2*i+1) << 6;
    int kt_e2 = (2*i+2) << 6;
    int kt_o2 = (2*i+3) << 6;
    bool st = (i+1 < niter);
    short8 bfr[4][2], afr[2][2];
    // P1
    DSB(&Bs[0][0], bfr);
    DSA(&As[0][0], 0, afr);
    STG(Ab, &As[1][0], 0, kt_o);
    LG0(); MM(0, afr, bfr);
    // P2
    DSA(&As[0][0], 1, afr);
    STG(Ab, &As[1][0], 1, kt_o);
    LG0(); MM(1, afr, bfr);
    BARX();
    // P3
    DSA(&As[0][0], 2, afr);
    if(st) STG(Bb, &Bs[0][0], 0, kt_e2);
    LG0(); MM(2, afr, bfr);
    // P4
    DSA(&As[0][0], 3, afr);
    if(st){ STG(Bb, &Bs[0][0], 1, kt_e2);
            asm volatile("s_waitcnt vmcnt(4)" ::: "memory"); }
    else  { asm volatile("s_waitcnt vmcnt(0)" ::: "memory"); }
    LG0(); MM(3, afr, bfr);
    BARX();
    // P5
    DSB(&Bs[1][0], bfr);
    DSA(&As[1][0], 0, afr);
    if(st) STG(Ab, &As[0][0], 0, kt_e2);
    LG0(); MM(0, afr, bfr);
    // P6
    DSA(&As[1][0], 1, afr);
    if(st) STG(Ab, &As[0][0], 1, kt_e2);
    LG0(); MM(1, afr, bfr);
    BARX();
    // P7
    DSA(&As[1][0], 2, afr);
    if(st) STG(Bb, &Bs[1][0], 0, kt_o2);
    LG0(); MM(2, afr, bfr);
    // P8
    DSA(&As[1][0], 3, afr);
    if(st){ STG(Bb, &Bs[1][0], 1, kt_o2);
            asm volatile("s_waitcnt vmcnt(4)" ::: "memory"); }
    else  { asm volatile("s_waitcnt vmcnt(0)" ::: "memory"); }
    LG0(); MM(3, afr, bfr);
    BARX();
  }
  #undef LG0
  #undef BARX

  int m0 = bm*256 + wr*128;
  int n0 = bn*256 + wc*64;
  #pragma unroll
  for(int m=0;m<8;m++){
    #pragma unroll
    for(int n=0;n<4;n++){
      #pragma unroll
      for(int jj=0;jj<4;jj++){
        int row = m0 + m*16 + lhi*4 + jj;
        int col = n0 + n*16 + l16;
        size_t ix = (size_t)row*N + col;
        float val = acc[m][n][jj];
        if constexpr (EPI==3){ float rv = fmaxf(val, 0.f); ((short*)Cout)[ix] = f2bf(rv*rv); }
        else if constexpr (EPI==5){ ((float*)Cout)[(size_t)z*zC + ix] = val; }
        else {
          short* o = (short*)Cout + (size_t)z*zC;
          o[ix] = (z==3) ? f2bf(val/(1.f+expf(-val))) : f2bf(val);
        }
      }
    }
  }
}

// ---------------- WKV pass A: barrier-free per-wave staging ----------------
// Wave w owns j in [w*16, w*16+16); lane: a = lane>>4 (i-group), jloc = lane&15.
// Per step: loads for t+1 issued first (regs, no wait); compute reads private
// LDS staged last iteration (own-wave lgkm dep); vmcnt-gated LDS writes after
// compute. Bonus term = wave-reduced scalar. Decay product p in wave-0 regs.
__global__ __launch_bounds__(256) void wkv_chunk_kernel(
    const short* __restrict__ rb, const short* __restrict__ kb,
    const short* __restrict__ vb, const float* __restrict__ db,
    const float* __restrict__ wkv_state, const float* __restrict__ u,
    const int* __restrict__ sp,
    float* __restrict__ yb, short* __restrict__ rtb,
    float* __restrict__ Bc, float* __restrict__ Pc)
{
  int blk = blockIdx.x;
  int ch = blk >> 5, h = blk & 31;
  int tid = threadIdx.x;
  int w = tid >> 6, lane = tid & 63;
  int a = lane >> 4, jloc = lane & 15;
  int j = w*16 + jloc;
  __shared__ __align__(16) float sr[4][2][64], sd[4][2][64], sk[4][2][64];
  float u_reg = u[h*64 + lane];
  float S[16];
  #pragma unroll
  for(int ii=0;ii<16;ii++) S[ii]=0.f;
  float p_reg = 1.f;
  int sp0=sp[0], sp1=sp[1], sp2=sp[2], sp3=sp[3];
  int tbase = ch*CHUNK;
  // prologue: stage step 0
  size_t gb0 = (size_t)tbase*CC + h*64 + lane;
  float r_c = bf2f(rb[gb0]);
  float k_c0 = bf2f(kb[gb0]);
  float v_c = bf2f(vb[gb0]);
  float d_c = db[gb0];
  sr[w][0][lane] = r_c; sd[w][0][lane] = d_c; sk[w][0][lane] = k_c0;
  float m0s = r_c * u_reg * k_c0;
  #pragma unroll
  for(int off=1; off<64; off<<=1) m0s += __shfl_xor(m0s, off);
  float bsum_c = m0s;

  for(int tl=0; tl<CHUNK; ++tl){
    int t = tbase + tl;
    int buf = tl & 1;
    bool more = (tl+1 < CHUNK);
    short r_n=0, k_n=0, v_n=0; float d_n=0.f;
    if(more){
      size_t nb = (size_t)(t+1)*CC + h*64 + lane;
      r_n = rb[nb]; k_n = kb[nb]; v_n = vb[nb]; d_n = db[nb];
    }
    size_t base = (size_t)t*CC + h*64;
    bool is_start = (sp0==t)|(sp1==t)|(sp2==t)|(sp3==t);
    if(is_start){
      int sid = (sp0<=t)+(sp1<=t)+(sp2<=t)+(sp3<=t) - 1;
      sid = sid<0?0:(sid>3?3:sid);
      const float* wsrc = wkv_state + (((size_t)sid*NH + h)*HSZ + a*16)*HSZ + j;
      #pragma unroll
      for(int ii=0;ii<16;ii++) S[ii] = wsrc[(size_t)ii*HSZ];
      p_reg = 0.f;
    }
    float vj = __shfl(v_c, j);
    const float4* rp = (const float4*)&sr[w][buf][a*16];
    const float4* dp = (const float4*)&sd[w][buf][a*16];
    const float4* kp = (const float4*)&sk[w][buf][a*16];
    float yp = 0.f;
    #pragma unroll
    for(int q=0;q<4;q++){
      float4 R = rp[q], D = dp[q], K = kp[q];
      yp += R.x*S[q*4+0] + R.y*S[q*4+1] + R.z*S[q*4+2] + R.w*S[q*4+3];
      S[q*4+0] = D.x*S[q*4+0] + K.x*vj;
      S[q*4+1] = D.y*S[q*4+1] + K.y*vj;
      S[q*4+2] = D.z*S[q*4+2] + K.z*vj;
      S[q*4+3] = D.w*S[q*4+3] + K.w*vj;
    }
    yp += __shfl_xor(yp, 16);
    yp += __shfl_xor(yp, 32);
    if(a == 0) yb[base + j] = yp + bsum_c * vj;
    if(w == 0){
      rtb[base + lane] = f2bf(r_c * p_reg);
      p_reg *= d_c;
    }
    if(more){
      float rf = bf2f(r_n), kf = bf2f(k_n), vf = bf2f(v_n);
      int nb2 = buf^1;
      sr[w][nb2][lane] = rf; sd[w][nb2][lane] = d_n; sk[w][nb2][lane] = kf;
      float mm = rf * u_reg * kf;
      #pragma unroll
      for(int off=1; off<64; off<<=1) mm += __shfl_xor(mm, off);
      bsum_c = mm;
      r_c = rf; d_c = d_n; v_c = vf;
    }
  }
  size_t cb = ((size_t)ch*NH + h)*HSZ*HSZ;
  #pragma unroll
  for(int ii=0;ii<16;ii++) Bc[cb + (size_t)(a*16+ii)*HSZ + j] = S[ii];
  if(w == 0) Pc[((size_t)ch*NH + h)*HSZ + lane] = p_reg;
}

// ---------------- WKV pass B ----------------
__global__ __launch_bounds__(256) void wkv_combine_kernel(
    float* __restrict__ BS, const float* __restrict__ Pc)
{
  int idx = blockIdx.x*256 + threadIdx.x;
  int hi = idx >> 6;
  float s = 0.f;
  for(int cc=0; cc<NCHUNK; ++cc){
    size_t ix = (size_t)cc*(NH*HSZ*HSZ) + idx;
    float b = BS[ix];
    BS[ix] = s;
    s = Pc[cc*(NH*HSZ) + hi]*s + b;
  }
}

// ---------------- WKV pass C + fused GroupNorm*g -> bf16 ----------------
__global__ __launch_bounds__(256) void wkv_corr_gn_kernel(
    const short* __restrict__ rtb, const float* __restrict__ Sin,
    const float* __restrict__ yb, const short* __restrict__ gb,
    const float* __restrict__ gam, const float* __restrict__ bet,
    short* __restrict__ yg)
{
  int blk = blockIdx.x;
  int ch = blk >> 5, h = blk & 31;
  __shared__ float Ssm[64][64];
  __shared__ float Rsm[32][65];
  int tid = threadIdx.x;
  const float* Sp = Sin + (size_t)(ch*NH + h)*HSZ*HSZ;
  #pragma unroll
  for(int q=0;q<16;q++) ((float*)Ssm)[q*256+tid] = Sp[q*256+tid];
  #pragma unroll
  for(int q=0;q<8;q++){
    int ix = q*256 + tid;
    int tl = ix>>6, i = ix&63;
    Rsm[tl][i] = bf2f(rtb[(size_t)(ch*CHUNK+tl)*CC + h*64 + i]);
  }
  __syncthreads();
  int tl = tid >> 3;   // row 0..31 (8 lanes per row)
  int jq = tid & 7;
  float acc[8];
  #pragma unroll
  for(int jj=0;jj<8;jj++) acc[jj]=0.f;
  for(int i=0;i<64;i++){
    float rv = Rsm[tl][i];
    #pragma unroll
    for(int jj=0;jj<8;jj++) acc[jj] += rv * Ssm[i][jq*8+jj];
  }
  int t = ch*CHUNK + tl;
  float val[8];
  float s = 0.f, ss = 0.f;
  #pragma unroll
  for(int jj=0;jj<8;jj++){
    float v = yb[(size_t)t*CC + h*64 + jq*8+jj] + acc[jj];
    val[jj] = v; s += v; ss += v*v;
  }
  #pragma unroll
  for(int off=1; off<8; off<<=1){ s += __shfl_xor(s,off); ss += __shfl_xor(ss,off); }
  float mu = s*(1.f/64.f);
  float var = ss*(1.f/64.f) - mu*mu;
  float rstd = rsqrtf(var + 6.4e-4f);   // eps = 1e-5 * 8^2
  #pragma unroll
  for(int jj=0;jj<8;jj++){
    int cc = h*64 + jq*8+jj;
    float o = (val[jj]-mu)*rstd*gam[cc] + bet[cc];
    yg[(size_t)t*CC + cc] = f2bf(o * bf2f(gb[(size_t)t*CC + cc]));
  }
}

// ---------------- final: out += sigmoid(s0+s1)*(kv0+kv1+kv2+kv3) ----------------
__global__ __launch_bounds__(256) void final_kernel(
    const float* __restrict__ s0, const float* __restrict__ s1,
    const float* __restrict__ kv0, const float* __restrict__ kv1,
    const float* __restrict__ kv2, const float* __restrict__ kv3,
    float* __restrict__ out)
{
  size_t i = ((size_t)blockIdx.x*256 + threadIdx.x)*8;
  #pragma unroll
  for(int j=0;j<8;j++){
    float sv = s0[i+j] + s1[i+j];
    float sig = 1.f/(1.f + expf(-sv));
    out[i+j] = out[i+j] + sig*(kv0[i+j] + kv1[i+j] + kv2[i+j] + kv3[i+j]);
  }
}

extern "C" void kernel_launch(void* const* d_in, const int* in_sizes, int n_in,
                              void* d_out, int out_size, void* d_ws, size_t ws_size,
                              hipStream_t stream)
{
  (void)in_sizes; (void)n_in; (void)out_size;
  const float* x         = (const float*)d_in[0];
  const int*   sp        = (const int*)d_in[1];
  const float* att_state = (const float*)d_in[2];
  const float* wkv_state = (const float*)d_in[3];
  const float* ffn_state = (const float*)d_in[4];
  const float* ln1_g=(const float*)d_in[5],  *ln1_b=(const float*)d_in[6];
  const float* ln2_g=(const float*)d_in[7],  *ln2_b=(const float*)d_in[8];
  const float* maa_x=(const float*)d_in[9],  *maa_w=(const float*)d_in[10], *maa_k=(const float*)d_in[11];
  const float* maa_v=(const float*)d_in[12], *maa_r=(const float*)d_in[13], *maa_g=(const float*)d_in[14];
  const float* tm_w1=(const float*)d_in[15], *tm_w2=(const float*)d_in[16];
  const float* td=(const float*)d_in[17],    *td_w1=(const float*)d_in[18], *td_w2=(const float*)d_in[19];
  const float* u = (const float*)d_in[20];
  const float* Wr=(const float*)d_in[21], *Wk=(const float*)d_in[22], *Wv=(const float*)d_in[23];
  const float* Wg=(const float*)d_in[24], *Wo=(const float*)d_in[25];
  const float* lnx_g=(const float*)d_in[26], *lnx_b=(const float*)d_in[27];
  const float* cm_k=(const float*)d_in[28],  *cm_r=(const float*)d_in[29];
  const float* Wck=(const float*)d_in[30], *Wcv=(const float*)d_in[31], *Wcr=(const float*)d_in[32];

  char* ws = (char*)d_ws;
  const size_t SLOT  = (size_t)TT*CC*4;
  const size_t BSLOT = (size_t)TT*CC*2;
  const size_t WT_SZ = (size_t)4*CC*CC*2;
  const size_t NEED  = 6*SLOT + 10*BSLOT + WT_SZ + (4u<<20);
  if(ws_size < NEED) return;

  float* xa   = (float*)(ws + 0*SLOT);
  float* xxb  = (float*)(ws + 1*SLOT);
  float* zw   = (float*)(ws + 2*SLOT);
  float* decb = (float*)(ws + 3*SLOT);
  float* yb   = (float*)(ws + 4*SLOT);
  float* S5   = (float*)(ws + 5*SLOT);
  float* BS   = xa;
  float* xxxPart = zw;
  float* h1Part  = yb;
  short* bA   = (short*)(ws + 6*SLOT);
  short* bO   = (short*)(ws + 6*SLOT + 4*BSLOT);
  short* b1 = bO + 0*(TT*CC);
  short* b2 = bO + 1*(TT*CC);
  short* b3 = bO + 2*(TT*CC);
  short* b4 = bO + 3*(TT*CC);
  short* b5 = bO + 4*(TT*CC);
  short* b6 = bO + 5*(TT*CC);
  short* WT = (short*)(ws + 6*SLOT + 10*BSLOT);
  char*  aux = (char*)WT + WT_SZ;
  float* xxxb = (float*)(aux);
  float* h1b  = (float*)(aux + (2u<<20));
  float* Pc   = (float*)(aux + (5u<<19));
  float* xmid = (float*)d_out;

  dim3 B256(256), B512(512);
  const int NTC8 = TT*CC/8/256;

  // ---- Tmix front (fused LN1 + shift + z-prep) ----
  front_kernel<<<TT, B256, 0, stream>>>(x, att_state, sp, ln1_g, ln1_b, maa_x,
                                        xa, xxb, bA);
  transpose_f2bf_kernel<<<dim3(4, CC/64), B256, 0, stream>>>(tm_w1, WT, CC, 160);
  gemm_bt_kernel<5><<<dim3(2, TT/128, 8), B256, 0, stream>>>(bA, WT, xxxPart, TT, 256, CC, 256,
      256, 256, (long)TT*256);
  tanh_reduce_kernel<256,160><<<TT, B256, 0, stream>>>(xxxPart, xxxb);
  mix5_kernel<<<NTC8, B256, 0, stream>>>(xxxb, tm_w2, xa, xxb,
      maa_w, maa_k, maa_v, maa_r, maa_g,
      b5, bA + 1*(TT*CC), bA + 2*(TT*CC), bA, bA + 3*(TT*CC));
  transpose_f2bf_kernel<<<dim3(2, CC/64), B256, 0, stream>>>(td_w1, WT, CC, 64);
  gemm_bt_kernel<5><<<dim3(1, TT/128, 8), B256, 0, stream>>>(b5, WT, h1Part, TT, 128, CC, 256,
      256, 256, (long)TT*128);
  tanh_reduce_kernel<128,64><<<TT/2, B256, 0, stream>>>(h1Part, h1b);
  dec_kernel<<<NTC8, B256, 0, stream>>>(h1b, td_w2, td, decb);

  // ---- r,k,v,g projections: batched 256^2 8-phase GEMM (256 blocks) ----
  WPtr4 w4; w4.w[0]=Wr; w4.w[1]=Wk; w4.w[2]=Wv; w4.w[3]=Wg;
  transpose4_f2bf_kernel<<<dim3(CC/64, CC/64, 4), B256, 0, stream>>>(w4, WT);
  gemm256_kernel<6><<<dim3(CC/256, TT/256, 4), B512, 0, stream>>>(bA, WT, b1, TT, CC, CC, CC,
      (long)TT*CC, (long)CC*CC, (long)TT*CC);

  // ---- WKV chunked scan (corr+GN fused) ----
  wkv_chunk_kernel<<<NCHUNK*NH, B256, 0, stream>>>(b1, b2, b3, decb, wkv_state, u, sp,
                                                   yb, b5, BS, Pc);
  wkv_combine_kernel<<<NH*HSZ*HSZ/256, B256, 0, stream>>>(BS, Pc);
  wkv_corr_gn_kernel<<<NCHUNK*NH, B256, 0, stream>>>(b5, BS, yb, b4, lnx_g, lnx_b, b6);

  // ---- output projection (128^2 split-K=2) + fused residual+LN2 ----
  transpose_f2bf_kernel<<<dim3(CC/64, CC/64), B256, 0, stream>>>(Wo, WT, CC, CC);
  gemm_bt_kernel<5><<<dim3(CC/128, TT/128, 2), B256, 0, stream>>>(b6, WT, yb, TT, CC, CC, 1024,
      1024, 1024, (long)TT*CC);
  ln2_fused_kernel<<<TT, B256, 0, stream>>>(yb, S5, x, ln2_g, ln2_b, xmid, zw, 1e-5f);

  // ---- CMix ----
  shift2_kernel<<<TT, B256, 0, stream>>>(zw, ffn_state, sp, cm_k, cm_r, bA, bA + 1*(TT*CC));
  transpose_f2bf_kernel<<<dim3(FFND/64, CC/64), B256, 0, stream>>>(Wck, WT, CC, FFND);
  gemm256_kernel<3><<<dim3(FFND/256, TT/256, 1), B512, 0, stream>>>(bA, WT, b1, TT, FFND, CC, CC,
      0, 0, 0);
  transpose_f2bf_kernel<<<dim3(CC/64, FFND/64), B256, 0, stream>>>(Wcv, WT, FFND, CC);
  gemm256_kernel<5><<<dim3(CC/256, TT/256, 4), B512, 0, stream>>>(b1, WT, zw, TT, CC, FFND, 1792,
      1792, 1792, (long)TT*CC);
  transpose_f2bf_kernel<<<dim3(CC/64, CC/64), B256, 0, stream>>>(Wcr, WT, CC, CC);
  gemm_bt_kernel<5><<<dim3(CC/128, TT/128, 2), B256, 0, stream>>>(bA + 1*(TT*CC), WT, xa, TT, CC, CC, 1024,
      1024, 1024, (long)TT*CC);
  final_kernel<<<NTC8, B256, 0, stream>>>(xa, xxb, zw, decb, yb, S5, xmid);
}

// Round 15
// 674.012 us; speedup vs baseline: 1.2787x; 1.0188x over previous
//
#include <hip/hip_runtime.h>
#include <stdint.h>

// RWKV6 block: B=1, T=2048, C=2048, H=32, HS=64, FFN=7168, NS=4
// Workspace: 6*16M (f32) + 4*8M (bA) + 6*8M (bO) + 32M (WT) + 4M aux = 212 MiB.

#define TT 2048
#define CC 2048
#define NH 32
#define HSZ 64
#define FFND 7168
#define CHUNK 32
#define NCHUNK 64

typedef __attribute__((ext_vector_type(8))) short short8;
typedef __attribute__((ext_vector_type(4))) float f32x4;

__device__ __forceinline__ float bf2f(short s){
  return __uint_as_float(((uint32_t)(uint16_t)s) << 16);
}
__device__ __forceinline__ short f2bf(float f){
  uint32_t u = __float_as_uint(f);
  u = u + 0x7fffu + ((u >> 16) & 1u);
  return (short)(u >> 16);
}

// ---------------- fused front: LN1(t) + LN1(t-1) + shift + z-prep ----------------
__global__ __launch_bounds__(256) void front_kernel(
    const float* __restrict__ x, const float* __restrict__ st,
    const int* __restrict__ sp, const float* __restrict__ gam,
    const float* __restrict__ bet, const float* __restrict__ maa,
    float* __restrict__ xa, float* __restrict__ xxb, short* __restrict__ z)
{
  int t = blockIdx.x, tid = threadIdx.x;
  const float* row = x + (size_t)t*CC;
  float4 a0 = *(const float4*)(row + tid*8);
  float4 a1 = *(const float4*)(row + tid*8 + 4);
  bool hp = (t > 0);
  float4 p0 = make_float4(0.f,0.f,0.f,0.f), p1 = p0;
  if(hp){
    const float* prow = x + (size_t)(t-1)*CC;
    p0 = *(const float4*)(prow + tid*8);
    p1 = *(const float4*)(prow + tid*8 + 4);
  }
  float sa  = a0.x+a0.y+a0.z+a0.w + a1.x+a1.y+a1.z+a1.w;
  float ssa = a0.x*a0.x+a0.y*a0.y+a0.z*a0.z+a0.w*a0.w
            + a1.x*a1.x+a1.y*a1.y+a1.z*a1.z+a1.w*a1.w;
  float sq  = p0.x+p0.y+p0.z+p0.w + p1.x+p1.y+p1.z+p1.w;
  float ssq = p0.x*p0.x+p0.y*p0.y+p0.z*p0.z+p0.w*p0.w
            + p1.x*p1.x+p1.y*p1.y+p1.z*p1.z+p1.w*p1.w;
  #pragma unroll
  for(int off=1; off<64; off<<=1){
    sa += __shfl_xor(sa,off); ssa += __shfl_xor(ssa,off);
    sq += __shfl_xor(sq,off); ssq += __shfl_xor(ssq,off);
  }
  __shared__ float sm[16];
  int w = tid>>6;
  if((tid&63)==0){ sm[w]=sa; sm[4+w]=ssa; sm[8+w]=sq; sm[12+w]=ssq; }
  __syncthreads();
  sa = sm[0]+sm[1]+sm[2]+sm[3];    ssa = sm[4]+sm[5]+sm[6]+sm[7];
  sq = sm[8]+sm[9]+sm[10]+sm[11];  ssq = sm[12]+sm[13]+sm[14]+sm[15];
  float mean_a = sa*(1.f/CC);
  float rstd_a = rsqrtf(ssa*(1.f/CC) - mean_a*mean_a + 1e-5f);
  float mean_q = sq*(1.f/CC);
  float rstd_q = rsqrtf(ssq*(1.f/CC) - mean_q*mean_q + 1e-5f);
  int sp0=sp[0], sp1=sp[1], sp2=sp[2], sp3=sp[3];
  bool is_start = (sp0==t)|(sp1==t)|(sp2==t)|(sp3==t);
  int sid = (sp0<=t)+(sp1<=t)+(sp2<=t)+(sp3<=t) - 1;
  sid = sid<0?0:(sid>3?3:sid);
  int c = tid*8;
  size_t base = (size_t)t*CC + c;
  float av[8] = {a0.x,a0.y,a0.z,a0.w,a1.x,a1.y,a1.z,a1.w};
  float pv[8] = {p0.x,p0.y,p0.z,p0.w,p1.x,p1.y,p1.z,p1.w};
  #pragma unroll
  for(int j=0;j<8;j++){
    float g = gam[c+j], b = bet[c+j];
    float lnt = (av[j]-mean_a)*rstd_a*g + b;
    float sh;
    if(is_start)      sh = st[(size_t)sid*CC + c + j];
    else if(hp)       sh = (pv[j]-mean_q)*rstd_q*g + b;
    else              sh = 0.f;
    float xx = sh - lnt;
    xa[base+j]  = lnt;
    xxb[base+j] = xx;
    z[base+j]   = f2bf(lnt + xx*maa[c+j]);
  }
}

// ---------------- fused: xmid = p0+p1+x ; zw = LN(xmid) ----------------
__global__ __launch_bounds__(256) void ln2_fused_kernel(
    const float* __restrict__ p0, const float* __restrict__ p1,
    const float* __restrict__ xres, const float* __restrict__ gam,
    const float* __restrict__ bet, float* __restrict__ xsum,
    float* __restrict__ lnout, float eps)
{
  int t = blockIdx.x, tid = threadIdx.x;
  size_t base = (size_t)t*CC + tid*8;
  float vv[8];
  float s = 0.f, ss = 0.f;
  #pragma unroll
  for(int j=0;j<8;j++){
    float v = p0[base+j] + p1[base+j] + xres[base+j];
    vv[j] = v; s += v; ss += v*v;
    xsum[base+j] = v;
  }
  #pragma unroll
  for(int off=1; off<64; off<<=1){ s += __shfl_xor(s,off); ss += __shfl_xor(ss,off); }
  __shared__ float sm[8];
  int w = tid>>6;
  if((tid&63)==0){ sm[w]=s; sm[4+w]=ss; }
  __syncthreads();
  s = sm[0]+sm[1]+sm[2]+sm[3]; ss = sm[4]+sm[5]+sm[6]+sm[7];
  float mean = s * (1.f/CC);
  float var  = ss * (1.f/CC) - mean*mean;
  float rstd = rsqrtf(var + eps);
  int c = tid*8;
  #pragma unroll
  for(int j=0;j<8;j++) lnout[base+j] = (vv[j]-mean)*rstd*gam[c+j] + bet[c+j];
}

// ---------------- token shift (ffn): xk2/xr2 fused, bf16 out ----------------
__global__ __launch_bounds__(256) void shift2_kernel(
    const float* __restrict__ xf, const float* __restrict__ st,
    const int* __restrict__ sp, const float* __restrict__ cmk,
    const float* __restrict__ cmr, short* __restrict__ xk2, short* __restrict__ xr2)
{
  int t = blockIdx.x, tid = threadIdx.x;
  int sp0=sp[0], sp1=sp[1], sp2=sp[2], sp3=sp[3];
  bool is_start = (sp0==t)|(sp1==t)|(sp2==t)|(sp3==t);
  int sid = (sp0<=t)+(sp1<=t)+(sp2<=t)+(sp3<=t) - 1;
  sid = sid<0?0:(sid>3?3:sid);
  int c = tid*8;
  const float* src = is_start ? (st + (size_t)sid*CC + c)
                   : (t>0 ? xf + (size_t)(t-1)*CC + c : nullptr);
  const float* cur = xf + (size_t)t*CC + c;
  size_t ix = (size_t)t*CC + c;
  #pragma unroll
  for(int jj=0;jj<8;jj++){
    float xfv = cur[jj];
    float sh = src ? src[jj] : 0.f;
    float d = sh - xfv;
    xk2[ix+jj] = f2bf(xfv + d*cmk[c+jj]);
    xr2[ix+jj] = f2bf(xfv + d*cmr[c+jj]);
  }
}

// ---------------- fused 5-way maa mix -> bf16 outputs ----------------
__global__ __launch_bounds__(256) void mix5_kernel(
    const float* __restrict__ xxxb, const float* __restrict__ w2,
    const float* __restrict__ xa, const float* __restrict__ xxv,
    const float* __restrict__ mw, const float* __restrict__ mk,
    const float* __restrict__ mv, const float* __restrict__ mr,
    const float* __restrict__ mg,
    short* __restrict__ ow, short* __restrict__ ok, short* __restrict__ ov,
    short* __restrict__ orr, short* __restrict__ og)
{
  int t0 = (blockIdx.x >> 3) * 8;                  // uniform (no tid)
  int c  = ((blockIdx.x & 7) << 8) + threadIdx.x;  // 0..2047
  float acc[5][8];
  #pragma unroll
  for(int s=0;s<5;s++)
    #pragma unroll
    for(int tt=0;tt<8;tt++) acc[s][tt]=0.f;
  #pragma unroll
  for(int s=0;s<5;s++){
    for(int e=0;e<32;e++){
      float wv = w2[(size_t)(s*32+e)*CC + c];
      #pragma unroll
      for(int tt=0;tt<8;tt++)
        acc[s][tt] += xxxb[(size_t)(t0+tt)*160 + s*32 + e] * wv;
    }
  }
  float vmw=mw[c], vmk=mk[c], vmv=mv[c], vmr=mr[c], vmg=mg[c];
  #pragma unroll
  for(int tt=0;tt<8;tt++){
    size_t ix = (size_t)(t0+tt)*CC + c;
    float av = xa[ix], xv = xxv[ix];
    ow[ix]  = f2bf(av + xv*(vmw + acc[0][tt]));
    ok[ix]  = f2bf(av + xv*(vmk + acc[1][tt]));
    ov[ix]  = f2bf(av + xv*(vmv + acc[2][tt]));
    orr[ix] = f2bf(av + xv*(vmr + acc[3][tt]));
    og[ix]  = f2bf(av + xv*(vmg + acc[4][tt]));
  }
}

// ---------------- dec = exp(-exp(td + h1 @ td_w2)) (f32) ----------------
__global__ __launch_bounds__(256) void dec_kernel(
    const float* __restrict__ h1b, const float* __restrict__ tw2,
    const float* __restrict__ td, float* __restrict__ out)
{
  int t0 = (blockIdx.x >> 3) * 8;
  int c  = ((blockIdx.x & 7) << 8) + threadIdx.x;
  float acc[8] = {0,0,0,0,0,0,0,0};
  for(int e=0;e<64;e++){
    float wv = tw2[(size_t)e*CC + c];
    #pragma unroll
    for(int tt=0;tt<8;tt++) acc[tt] += h1b[(size_t)(t0+tt)*64 + e]*wv;
  }
  float tdc = td[c];
  #pragma unroll
  for(int tt=0;tt<8;tt++)
    out[(size_t)(t0+tt)*CC + c] = expf(-expf(tdc + acc[tt]));
}

// ---------------- tanh split-K reduce ----------------
template<int N, int NK>
__global__ __launch_bounds__(256) void tanh_reduce_kernel(
    const float* __restrict__ part, float* __restrict__ out)
{
  int idx = blockIdx.x*256 + threadIdx.x;
  int col = idx & (N-1);
  int row = idx >> (N==256 ? 8 : 7);
  float s = 0.f;
  #pragma unroll
  for(int z=0;z<8;z++) s += part[(size_t)z*TT*N + idx];
  if(col < NK) out[(size_t)row*NK + col] = tanhf(s);
}

// ---------------- W[K,N] f32 -> Wt[NPAD,K] bf16 ----------------
__global__ __launch_bounds__(256) void transpose_f2bf_kernel(
    const float* __restrict__ W, short* __restrict__ Wt, int K, int N)
{
  __shared__ float tile[64][65];
  int n0 = blockIdx.x*64, k0 = blockIdx.y*64;
  int tid = threadIdx.x;
  #pragma unroll
  for(int q=0;q<16;q++){
    int ix = q*256 + tid;
    int r = ix >> 6, cc2 = ix & 63;
    tile[r][cc2] = (n0 + cc2 < N) ? W[(size_t)(k0+r)*N + n0 + cc2] : 0.f;
  }
  __syncthreads();
  #pragma unroll
  for(int q=0;q<16;q++){
    int ix = q*256 + tid;
    int r = ix >> 6, cc2 = ix & 63;
    Wt[(size_t)(n0+r)*K + k0 + cc2] = f2bf(tile[cc2][r]);
  }
}

struct WPtr4 { const float* w[4]; };
__global__ __launch_bounds__(256) void transpose4_f2bf_kernel(
    WPtr4 ws4, short* __restrict__ Wt)
{
  __shared__ float tile[64][65];
  int z = blockIdx.z;
  const float* W = ws4.w[z];
  short* dst = Wt + (size_t)z*CC*CC;
  int n0 = blockIdx.x*64, k0 = blockIdx.y*64;
  int tid = threadIdx.x;
  #pragma unroll
  for(int q=0;q<16;q++){
    int ix = q*256 + tid;
    int r = ix >> 6, cc2 = ix & 63;
    tile[r][cc2] = W[(size_t)(k0+r)*CC + n0 + cc2];
  }
  __syncthreads();
  #pragma unroll
  for(int q=0;q<16;q++){
    int ix = q*256 + tid;
    int r = ix >> 6, cc2 = ix & 63;
    dst[(size_t)(n0+r)*CC + k0 + cc2] = f2bf(tile[cc2][r]);
  }
}

__device__ __forceinline__ void load_lds16(const void* g, void* l){
  __builtin_amdgcn_global_load_lds(
      (const __attribute__((address_space(1))) uint32_t*)g,
      (__attribute__((address_space(3))) uint32_t*)l, 16, 0, 0);
}

// ---------------- 128^2 MFMA GEMM (m97-structure + swizzle) ----------------
// EPI: 0 bf16; 3 relu^2 bf16; 5 f32 partial slab; 6 rkvg batch
template<int EPI>
__global__ __launch_bounds__(256) void gemm_bt_kernel(
    const short* __restrict__ A, const short* __restrict__ Bt,
    void* __restrict__ Cout, int M, int N, int Kstride, int Klen,
    long zA, long zB, long zC)
{
  __shared__ __align__(16) short As[128*64];
  __shared__ __align__(16) short Bs[128*64];
  int z = blockIdx.z;
  const short* A0 = A + (size_t)z*zA;
  const short* B0 = Bt + (size_t)z*zB;
  int tid = threadIdx.x;
  int w = tid >> 6, lane = tid & 63;
  int l16 = lane & 15, lhi = lane >> 4;
  int wr = w >> 1, wc = w & 1;
  int gx = gridDim.x;
  int nwg = gx*gridDim.y;
  int lin = blockIdx.y*gx + blockIdx.x;
  int wg = (lin & 7)*(nwg >> 3) + (lin >> 3);
  int bn = wg % gx, bm = wg / gx;
  const short* Ab = A0 + (size_t)bm*128*Kstride;
  const short* Bb = B0 + (size_t)bn*128*Kstride;
  int srow = w*8 + (lane>>3);
  int scol = lane & 7;
  f32x4 acc[4][4] = {};
  for(int kt=0; kt<Klen; kt+=64){
    __syncthreads();
    #pragma unroll
    for(int q=0;q<4;q++){
      int row = q*32 + srow;
      int c8 = scol ^ (row & 7);
      int ldsoff = (q*256 + w*64)*8;
      load_lds16(Ab + (size_t)row*Kstride + kt + c8*8, As + ldsoff);
      load_lds16(Bb + (size_t)row*Kstride + kt + c8*8, Bs + ldsoff);
    }
    __syncthreads();
    #pragma unroll
    for(int kk=0;kk<2;kk++){
      short8 af[4], bf[4];
      #pragma unroll
      for(int m=0;m<4;m++){
        int row = wr*64 + m*16 + l16;
        int slot = (kk*4 + lhi) ^ (row & 7);
        af[m] = *(const short8*)(As + row*64 + slot*8);
      }
      #pragma unroll
      for(int n=0;n<4;n++){
        int row = wc*64 + n*16 + l16;
        int slot = (kk*4 + lhi) ^ (row & 7);
        bf[n] = *(const short8*)(Bs + row*64 + slot*8);
      }
      #pragma unroll
      for(int m=0;m<4;m++){
        #pragma unroll
        for(int n=0;n<4;n++)
          acc[m][n] = __builtin_amdgcn_mfma_f32_16x16x32_bf16(af[m], bf[n], acc[m][n], 0, 0, 0);
      }
    }
  }
  int m0 = bm*128 + wr*64;
  int n0 = bn*128 + wc*64;
  #pragma unroll
  for(int m=0;m<4;m++){
    #pragma unroll
    for(int n=0;n<4;n++){
      #pragma unroll
      for(int jj=0;jj<4;jj++){
        int row = m0 + m*16 + lhi*4 + jj;
        int col = n0 + n*16 + l16;
        size_t ix = (size_t)row*N + col;
        float val = acc[m][n][jj];
        if constexpr (EPI==0){ ((short*)Cout)[(size_t)z*zC + ix] = f2bf(val); }
        else if constexpr (EPI==3){ float rv = fmaxf(val, 0.f); ((short*)Cout)[ix] = f2bf(rv*rv); }
        else if constexpr (EPI==5){ ((float*)Cout)[(size_t)z*zC + ix] = val; }
        else {
          short* o = (short*)Cout + (size_t)z*zC;
          o[ix] = (z==3) ? f2bf(val/(1.f+expf(-val))) : f2bf(val);
        }
      }
    }
  }
}

// ---------------- 256^2 MFMA GEMM, 4-phase (32 MFMA/phase), thinned barriers -
// Calendar: Q1 reads {B0, A0 m0-3}, stages A1 full; Q2 reads A0 m4-7, stages
// B0', vmcnt(4) [retires A0'(prev),B1'(prev),A1 -> ready for Q3]; Q3 reads
// {B1, A1 m0-3}, stages A0'; Q4 reads A1 m4-7, stages B1', vmcnt(4)
// [retires B0',A0' for next Q1]. Barriers end Q1(B0 free), Q2(A0 free;
// publish A1,B1), Q3(B1 free), Q4(A1 free; publish B0',A0').
template<int EPI>
__global__ __launch_bounds__(512, 1) void gemm256_kernel(
    const short* __restrict__ A, const short* __restrict__ Bt,
    void* __restrict__ Cout, int M, int N, int Kstride, int Klen,
    long zA, long zB, long zC)
{
  __shared__ __align__(16) short As[2][256*64];
  __shared__ __align__(16) short Bs[2][256*64];
  int z = blockIdx.z;
  const short* A0p = A + (size_t)z*zA;
  const short* B0p = Bt + (size_t)z*zB;
  int tid = threadIdx.x;
  int w = tid >> 6, lane = tid & 63;
  int l16 = lane & 15, lhi = lane >> 4;
  int wr = w >> 2, wc = w & 3;
  int gx = gridDim.x;
  int nwg = gx*gridDim.y;
  int lin = blockIdx.y*gx + blockIdx.x;
  int wg = (lin & 7)*(nwg >> 3) + (lin >> 3);
  int bn = wg % gx, bm = wg / gx;
  const short* Ab = A0p + (size_t)bm*256*Kstride;
  const short* Bb = B0p + (size_t)bn*256*Kstride;
  int srow_w = w*8 + (lane>>3);
  int scol = lane & 7;
  f32x4 acc[8][4] = {};

  auto STGF = [&](const short* src, short* dst, int kt){  // full 256-row tile, 4 loads
    #pragma unroll
    for(int q=0;q<4;q++){
      int row = q*64 + srow_w;
      int c8 = scol ^ (row & 7);
      load_lds16(src + (size_t)row*Kstride + kt + c8*8,
                 dst + (q*64 + w*8)*64);
    }
  };
  auto DSA4 = [&](const short* Ac, int half, short8 afr[4][2]){
    #pragma unroll
    for(int mm=0;mm<4;mm++)
      #pragma unroll
      for(int kk=0;kk<2;kk++){
        int row = wr*128 + (half*4+mm)*16 + l16;
        int slot = (kk*4 + lhi) ^ (row & 7);
        afr[mm][kk] = *(const short8*)(Ac + row*64 + slot*8);
      }
  };
  auto DSB = [&](const short* Bc, short8 bfr[4][2]){
    #pragma unroll
    for(int n=0;n<4;n++)
      #pragma unroll
      for(int kk=0;kk<2;kk++){
        int row = wc*64 + n*16 + l16;
        int slot = (kk*4 + lhi) ^ (row & 7);
        bfr[n][kk] = *(const short8*)(Bc + row*64 + slot*8);
      }
  };
  auto MM4 = [&](int half, short8 afr[4][2], short8 bfr[4][2]){
    __builtin_amdgcn_s_setprio(1);
    #pragma unroll
    for(int mm=0;mm<4;mm++)
      #pragma unroll
      for(int n=0;n<4;n++)
        #pragma unroll
        for(int kk=0;kk<2;kk++)
          acc[half*4+mm][n] = __builtin_amdgcn_mfma_f32_16x16x32_bf16(
              afr[mm][kk], bfr[n][kk], acc[half*4+mm][n], 0, 0, 0);
    __builtin_amdgcn_s_setprio(0);
  };
  #define LG0()  do{ asm volatile("s_waitcnt lgkmcnt(0)" ::: "memory"); \
      __builtin_amdgcn_sched_barrier(0); }while(0)
  #define BARX() do{ __builtin_amdgcn_s_barrier(); \
      __builtin_amdgcn_sched_barrier(0); }while(0)

  int NT = Klen >> 6;
  int niter = NT >> 1;
  // prologue: A0,B0 full + B1 full; retire A0+B0 (8 of 12)
  STGF(Ab, &As[0][0], 0);
  STGF(Bb, &Bs[0][0], 0);
  STGF(Bb, &Bs[1][0], 64);
  asm volatile("s_waitcnt vmcnt(4)" ::: "memory");
  BARX();

  for(int i=0;i<niter;++i){
    int kt_o  = (2*i+1) << 6;
    int kt_e2 = (2*i+2) << 6;
    int kt_o2 = (2*i+3) << 6;
    bool st = (i+1 < niter);
    short8 bfr[4][2], afr[4][2];
    // Q1: reads B0 + A0 m0-3; stage A1 full
    DSB(&Bs[0][0], bfr);
    DSA4(&As[0][0], 0, afr);
    STGF(Ab, &As[1][0], kt_o);
    LG0(); MM4(0, afr, bfr);
    BARX();                      // B0 reads done
    // Q2: reads A0 m4-7; stage B0'
    DSA4(&As[0][0], 1, afr);
    if(st){ STGF(Bb, &Bs[0][0], kt_e2);
            asm volatile("s_waitcnt vmcnt(4)" ::: "memory"); }
    else  { asm volatile("s_waitcnt vmcnt(0)" ::: "memory"); }
    LG0(); MM4(1, afr, bfr);
    BARX();                      // A0 reads done; A1,B1 published
    // Q3: reads B1 + A1 m0-3; stage A0'
    DSB(&Bs[1][0], bfr);
    DSA4(&As[1][0], 0, afr);
    if(st) STGF(Ab, &As[0][0], kt_e2);
    LG0(); MM4(0, afr, bfr);
    BARX();                      // B1 reads done
    // Q4: reads A1 m4-7; stage B1'
    DSA4(&As[1][0], 1, afr);
    if(st){ STGF(Bb, &Bs[1][0], kt_o2);
            asm volatile("s_waitcnt vmcnt(4)" ::: "memory"); }
    else  { asm volatile("s_waitcnt vmcnt(0)" ::: "memory"); }
    LG0(); MM4(1, afr, bfr);
    BARX();                      // A1 reads done; B0',A0' published
  }
  #undef LG0
  #undef BARX

  int m0 = bm*256 + wr*128;
  int n0 = bn*256 + wc*64;
  #pragma unroll
  for(int m=0;m<8;m++){
    #pragma unroll
    for(int n=0;n<4;n++){
      #pragma unroll
      for(int jj=0;jj<4;jj++){
        int row = m0 + m*16 + lhi*4 + jj;
        int col = n0 + n*16 + l16;
        size_t ix = (size_t)row*N + col;
        float val = acc[m][n][jj];
        if constexpr (EPI==3){ float rv = fmaxf(val, 0.f); ((short*)Cout)[ix] = f2bf(rv*rv); }
        else if constexpr (EPI==5){ ((float*)Cout)[(size_t)z*zC + ix] = val; }
        else {
          short* o = (short*)Cout + (size_t)z*zC;
          o[ix] = (z==3) ? f2bf(val/(1.f+expf(-val))) : f2bf(val);
        }
      }
    }
  }
}

// ---------------- WKV pass A: barrier-free per-wave staging ----------------
__global__ __launch_bounds__(256) void wkv_chunk_kernel(
    const short* __restrict__ rb, const short* __restrict__ kb,
    const short* __restrict__ vb, const float* __restrict__ db,
    const float* __restrict__ wkv_state, const float* __restrict__ u,
    const int* __restrict__ sp,
    float* __restrict__ yb, short* __restrict__ rtb,
    float* __restrict__ Bc, float* __restrict__ Pc)
{
  int blk = blockIdx.x;
  int ch = blk >> 5, h = blk & 31;
  int tid = threadIdx.x;
  int w = tid >> 6, lane = tid & 63;
  int a = lane >> 4, jloc = lane & 15;
  int j = w*16 + jloc;
  __shared__ __align__(16) float sr[4][2][64], sd[4][2][64], sk[4][2][64];
  float u_reg = u[h*64 + lane];
  float S[16];
  #pragma unroll
  for(int ii=0;ii<16;ii++) S[ii]=0.f;
  float p_reg = 1.f;
  int sp0=sp[0], sp1=sp[1], sp2=sp[2], sp3=sp[3];
  int tbase = ch*CHUNK;
  size_t gb0 = (size_t)tbase*CC + h*64 + lane;
  float r_c = bf2f(rb[gb0]);
  float k_c0 = bf2f(kb[gb0]);
  float v_c = bf2f(vb[gb0]);
  float d_c = db[gb0];
  sr[w][0][lane] = r_c; sd[w][0][lane] = d_c; sk[w][0][lane] = k_c0;
  float m0s = r_c * u_reg * k_c0;
  #pragma unroll
  for(int off=1; off<64; off<<=1) m0s += __shfl_xor(m0s, off);
  float bsum_c = m0s;

  for(int tl=0; tl<CHUNK; ++tl){
    int t = tbase + tl;
    int buf = tl & 1;
    bool more = (tl+1 < CHUNK);
    short r_n=0, k_n=0, v_n=0; float d_n=0.f;
    if(more){
      size_t nb = (size_t)(t+1)*CC + h*64 + lane;
      r_n = rb[nb]; k_n = kb[nb]; v_n = vb[nb]; d_n = db[nb];
    }
    size_t base = (size_t)t*CC + h*64;
    bool is_start = (sp0==t)|(sp1==t)|(sp2==t)|(sp3==t);
    if(is_start){
      int sid = (sp0<=t)+(sp1<=t)+(sp2<=t)+(sp3<=t) - 1;
      sid = sid<0?0:(sid>3?3:sid);
      const float* wsrc = wkv_state + (((size_t)sid*NH + h)*HSZ + a*16)*HSZ + j;
      #pragma unroll
      for(int ii=0;ii<16;ii++) S[ii] = wsrc[(size_t)ii*HSZ];
      p_reg = 0.f;
    }
    float vj = __shfl(v_c, j);
    const float4* rp = (const float4*)&sr[w][buf][a*16];
    const float4* dp = (const float4*)&sd[w][buf][a*16];
    const float4* kp = (const float4*)&sk[w][buf][a*16];
    float yp = 0.f;
    #pragma unroll
    for(int q=0;q<4;q++){
      float4 R = rp[q], D = dp[q], K = kp[q];
      yp += R.x*S[q*4+0] + R.y*S[q*4+1] + R.z*S[q*4+2] + R.w*S[q*4+3];
      S[q*4+0] = D.x*S[q*4+0] + K.x*vj;
      S[q*4+1] = D.y*S[q*4+1] + K.y*vj;
      S[q*4+2] = D.z*S[q*4+2] + K.z*vj;
      S[q*4+3] = D.w*S[q*4+3] + K.w*vj;
    }
    yp += __shfl_xor(yp, 16);
    yp += __shfl_xor(yp, 32);
    if(a == 0) yb[base + j] = yp + bsum_c * vj;
    if(w == 0){
      rtb[base + lane] = f2bf(r_c * p_reg);
      p_reg *= d_c;
    }
    if(more){
      float rf = bf2f(r_n), kf = bf2f(k_n), vf = bf2f(v_n);
      int nb2 = buf^1;
      sr[w][nb2][lane] = rf; sd[w][nb2][lane] = d_n; sk[w][nb2][lane] = kf;
      float mm = rf * u_reg * kf;
      #pragma unroll
      for(int off=1; off<64; off<<=1) mm += __shfl_xor(mm, off);
      bsum_c = mm;
      r_c = rf; d_c = d_n; v_c = vf;
    }
  }
  size_t cb = ((size_t)ch*NH + h)*HSZ*HSZ;
  #pragma unroll
  for(int ii=0;ii<16;ii++) Bc[cb + (size_t)(a*16+ii)*HSZ + j] = S[ii];
  if(w == 0) Pc[((size_t)ch*NH + h)*HSZ + lane] = p_reg;
}

// ---------------- WKV pass B ----------------
__global__ __launch_bounds__(256) void wkv_combine_kernel(
    float* __restrict__ BS, const float* __restrict__ Pc)
{
  int idx = blockIdx.x*256 + threadIdx.x;
  int hi = idx >> 6;
  float s = 0.f;
  for(int cc=0; cc<NCHUNK; ++cc){
    size_t ix = (size_t)cc*(NH*HSZ*HSZ) + idx;
    float b = BS[ix];
    BS[ix] = s;
    s = Pc[cc*(NH*HSZ) + hi]*s + b;
  }
}

// ---------------- WKV pass C + fused GroupNorm*g -> bf16 ----------------
__global__ __launch_bounds__(256) void wkv_corr_gn_kernel(
    const short* __restrict__ rtb, const float* __restrict__ Sin,
    const float* __restrict__ yb, const short* __restrict__ gb,
    const float* __restrict__ gam, const float* __restrict__ bet,
    short* __restrict__ yg)
{
  int blk = blockIdx.x;
  int ch = blk >> 5, h = blk & 31;
  __shared__ float Ssm[64][64];
  __shared__ float Rsm[32][65];
  int tid = threadIdx.x;
  const float* Sp = Sin + (size_t)(ch*NH + h)*HSZ*HSZ;
  #pragma unroll
  for(int q=0;q<16;q++) ((float*)Ssm)[q*256+tid] = Sp[q*256+tid];
  #pragma unroll
  for(int q=0;q<8;q++){
    int ix = q*256 + tid;
    int tl = ix>>6, i = ix&63;
    Rsm[tl][i] = bf2f(rtb[(size_t)(ch*CHUNK+tl)*CC + h*64 + i]);
  }
  __syncthreads();
  int tl = tid >> 3;   // row 0..31 (8 lanes per row)
  int jq = tid & 7;
  float acc[8];
  #pragma unroll
  for(int jj=0;jj<8;jj++) acc[jj]=0.f;
  for(int i=0;i<64;i++){
    float rv = Rsm[tl][i];
    #pragma unroll
    for(int jj=0;jj<8;jj++) acc[jj] += rv * Ssm[i][jq*8+jj];
  }
  int t = ch*CHUNK + tl;
  float val[8];
  float s = 0.f, ss = 0.f;
  #pragma unroll
  for(int jj=0;jj<8;jj++){
    float v = yb[(size_t)t*CC + h*64 + jq*8+jj] + acc[jj];
    val[jj] = v; s += v; ss += v*v;
  }
  #pragma unroll
  for(int off=1; off<8; off<<=1){ s += __shfl_xor(s,off); ss += __shfl_xor(ss,off); }
  float mu = s*(1.f/64.f);
  float var = ss*(1.f/64.f) - mu*mu;
  float rstd = rsqrtf(var + 6.4e-4f);   // eps = 1e-5 * 8^2
  #pragma unroll
  for(int jj=0;jj<8;jj++){
    int cc = h*64 + jq*8+jj;
    float o = (val[jj]-mu)*rstd*gam[cc] + bet[cc];
    yg[(size_t)t*CC + cc] = f2bf(o * bf2f(gb[(size_t)t*CC + cc]));
  }
}

// ---------------- final: out += sigmoid(s0+s1)*(kv0+kv1+kv2+kv3) ----------------
__global__ __launch_bounds__(256) void final_kernel(
    const float* __restrict__ s0, const float* __restrict__ s1,
    const float* __restrict__ kv0, const float* __restrict__ kv1,
    const float* __restrict__ kv2, const float* __restrict__ kv3,
    float* __restrict__ out)
{
  size_t i = ((size_t)blockIdx.x*256 + threadIdx.x)*8;
  #pragma unroll
  for(int j=0;j<8;j++){
    float sv = s0[i+j] + s1[i+j];
    float sig = 1.f/(1.f + expf(-sv));
    out[i+j] = out[i+j] + sig*(kv0[i+j] + kv1[i+j] + kv2[i+j] + kv3[i+j]);
  }
}

extern "C" void kernel_launch(void* const* d_in, const int* in_sizes, int n_in,
                              void* d_out, int out_size, void* d_ws, size_t ws_size,
                              hipStream_t stream)
{
  (void)in_sizes; (void)n_in; (void)out_size;
  const float* x         = (const float*)d_in[0];
  const int*   sp        = (const int*)d_in[1];
  const float* att_state = (const float*)d_in[2];
  const float* wkv_state = (const float*)d_in[3];
  const float* ffn_state = (const float*)d_in[4];
  const float* ln1_g=(const float*)d_in[5],  *ln1_b=(const float*)d_in[6];
  const float* ln2_g=(const float*)d_in[7],  *ln2_b=(const float*)d_in[8];
  const float* maa_x=(const float*)d_in[9],  *maa_w=(const float*)d_in[10], *maa_k=(const float*)d_in[11];
  const float* maa_v=(const float*)d_in[12], *maa_r=(const float*)d_in[13], *maa_g=(const float*)d_in[14];
  const float* tm_w1=(const float*)d_in[15], *tm_w2=(const float*)d_in[16];
  const float* td=(const float*)d_in[17],    *td_w1=(const float*)d_in[18], *td_w2=(const float*)d_in[19];
  const float* u = (const float*)d_in[20];
  const float* Wr=(const float*)d_in[21], *Wk=(const float*)d_in[22], *Wv=(const float*)d_in[23];
  const float* Wg=(const float*)d_in[24], *Wo=(const float*)d_in[25];
  const float* lnx_g=(const float*)d_in[26], *lnx_b=(const float*)d_in[27];
  const float* cm_k=(const float*)d_in[28],  *cm_r=(const float*)d_in[29];
  const float* Wck=(const float*)d_in[30], *Wcv=(const float*)d_in[31], *Wcr=(const float*)d_in[32];

  char* ws = (char*)d_ws;
  const size_t SLOT  = (size_t)TT*CC*4;
  const size_t BSLOT = (size_t)TT*CC*2;
  const size_t WT_SZ = (size_t)4*CC*CC*2;
  const size_t NEED  = 6*SLOT + 10*BSLOT + WT_SZ + (4u<<20);
  if(ws_size < NEED) return;

  float* xa   = (float*)(ws + 0*SLOT);
  float* xxb  = (float*)(ws + 1*SLOT);
  float* zw   = (float*)(ws + 2*SLOT);
  float* decb = (float*)(ws + 3*SLOT);
  float* yb   = (float*)(ws + 4*SLOT);
  float* S5   = (float*)(ws + 5*SLOT);
  float* BS   = xa;
  float* xxxPart = zw;
  float* h1Part  = yb;
  short* bA   = (short*)(ws + 6*SLOT);
  short* bO   = (short*)(ws + 6*SLOT + 4*BSLOT);
  short* b1 = bO + 0*(TT*CC);
  short* b2 = bO + 1*(TT*CC);
  short* b3 = bO + 2*(TT*CC);
  short* b4 = bO + 3*(TT*CC);
  short* b5 = bO + 4*(TT*CC);
  short* b6 = bO + 5*(TT*CC);
  short* WT = (short*)(ws + 6*SLOT + 10*BSLOT);
  char*  aux = (char*)WT + WT_SZ;
  float* xxxb = (float*)(aux);
  float* h1b  = (float*)(aux + (2u<<20));
  float* Pc   = (float*)(aux + (5u<<19));
  float* xmid = (float*)d_out;

  dim3 B256(256), B512(512);
  const int NTC8 = TT*CC/8/256;

  // ---- Tmix front (fused LN1 + shift + z-prep) ----
  front_kernel<<<TT, B256, 0, stream>>>(x, att_state, sp, ln1_g, ln1_b, maa_x,
                                        xa, xxb, bA);
  transpose_f2bf_kernel<<<dim3(4, CC/64), B256, 0, stream>>>(tm_w1, WT, CC, 160);
  gemm_bt_kernel<5><<<dim3(2, TT/128, 8), B256, 0, stream>>>(bA, WT, xxxPart, TT, 256, CC, 256,
      256, 256, (long)TT*256);
  tanh_reduce_kernel<256,160><<<TT, B256, 0, stream>>>(xxxPart, xxxb);
  mix5_kernel<<<NTC8, B256, 0, stream>>>(xxxb, tm_w2, xa, xxb,
      maa_w, maa_k, maa_v, maa_r, maa_g,
      b5, bA + 1*(TT*CC), bA + 2*(TT*CC), bA, bA + 3*(TT*CC));
  transpose_f2bf_kernel<<<dim3(2, CC/64), B256, 0, stream>>>(td_w1, WT, CC, 64);
  gemm_bt_kernel<5><<<dim3(1, TT/128, 8), B256, 0, stream>>>(b5, WT, h1Part, TT, 128, CC, 256,
      256, 256, (long)TT*128);
  tanh_reduce_kernel<128,64><<<TT/2, B256, 0, stream>>>(h1Part, h1b);
  dec_kernel<<<NTC8, B256, 0, stream>>>(h1b, td_w2, td, decb);

  // ---- r,k,v,g projections: batched 256^2 4-phase GEMM (256 blocks) ----
  WPtr4 w4; w4.w[0]=Wr; w4.w[1]=Wk; w4.w[2]=Wv; w4.w[3]=Wg;
  transpose4_f2bf_kernel<<<dim3(CC/64, CC/64, 4), B256, 0, stream>>>(w4, WT);
  gemm256_kernel<6><<<dim3(CC/256, TT/256, 4), B512, 0, stream>>>(bA, WT, b1, TT, CC, CC, CC,
      (long)TT*CC, (long)CC*CC, (long)TT*CC);

  // ---- WKV chunked scan (corr+GN fused) ----
  wkv_chunk_kernel<<<NCHUNK*NH, B256, 0, stream>>>(b1, b2, b3, decb, wkv_state, u, sp,
                                                   yb, b5, BS, Pc);
  wkv_combine_kernel<<<NH*HSZ*HSZ/256, B256, 0, stream>>>(BS, Pc);
  wkv_corr_gn_kernel<<<NCHUNK*NH, B256, 0, stream>>>(b5, BS, yb, b4, lnx_g, lnx_b, b6);

  // ---- output projection (128^2 split-K=2) + fused residual+LN2 ----
  transpose_f2bf_kernel<<<dim3(CC/64, CC/64), B256, 0, stream>>>(Wo, WT, CC, CC);
  gemm_bt_kernel<5><<<dim3(CC/128, TT/128, 2), B256, 0, stream>>>(b6, WT, yb, TT, CC, CC, 1024,
      1024, 1024, (long)TT*CC);
  ln2_fused_kernel<<<TT, B256, 0, stream>>>(yb, S5, x, ln2_g, ln2_b, xmid, zw, 1e-5f);

  // ---- CMix ----
  shift2_kernel<<<TT, B256, 0, stream>>>(zw, ffn_state, sp, cm_k, cm_r, bA, bA + 1*(TT*CC));
  transpose_f2bf_kernel<<<dim3(FFND/64, CC/64), B256, 0, stream>>>(Wck, WT, CC, FFND);
  gemm256_kernel<3><<<dim3(FFND/256, TT/256, 1), B512, 0, stream>>>(bA, WT, b1, TT, FFND, CC, CC,
      0, 0, 0);
  transpose_f2bf_kernel<<<dim3(CC/64, FFND/64), B256, 0, stream>>>(Wcv, WT, FFND, CC);
  gemm256_kernel<5><<<dim3(CC/256, TT/256, 4), B512, 0, stream>>>(b1, WT, zw, TT, CC, FFND, 1792,
      1792, 1792, (long)TT*CC);
  transpose_f2bf_kernel<<<dim3(CC/64, CC/64), B256, 0, stream>>>(Wcr, WT, CC, CC);
  gemm_bt_kernel<5><<<dim3(CC/128, TT/128, 2), B256, 0, stream>>>(bA + 1*(TT*CC), WT, xa, TT, CC, CC, 1024,
      1024, 1024, (long)TT*CC);
  final_kernel<<<NTC8, B256, 0, stream>>>(xa, xxb, zw, decb, yb, S5, xmid);
}